// Round 10
// baseline (254.908 us; speedup 1.0000x reference)
//
#include <hip/hip_runtime.h>

#define TDIM 1024
#define DD   263
#define CC   526
#define NFREQ 513
#define PACK 1026
#define KTOP 102

// ---------------- ws layout (float offsets) ----------------
static const size_t WS_EX     = 0;          // 538624 f32
static const size_t WS_W1BF   = 538624;     // 320x288 bf16
static const size_t WS_W2BF   = 584704;
static const size_t WS_WEMT   = 630784;     // 576x288 bf16
static const size_t WS_MASKB  = 1615872;    // 2048x288 bf16
static const size_t WS_HBF    = 2154496;
static const size_t WS_PROJ   = 2693120;    // f32 2048x263
static const size_t WS_XTBF   = 3231744;    // 2x1024x288 bf16
static const size_t WS_CXP    = 3770368;    // f32 2*1026*263
static const size_t WS_EXTHL  = 4310044;    // 2x320x3072 bf16 = 983040 f (old Twid)
static const size_t WS_ITBF   = 5360668;    // 1024x1056 bf16
static const size_t WS_CXPT   = 5901340;    // 2x320x1056 bf16
static const size_t WS_TABC   = 6411292;    // 1024
static const size_t WS_TABS   = 6412316;    // 1024
static const size_t WS_SCORE  = 6413340;    // double[2048]
static const size_t WS_MAGM   = 6417436;    // double[1026]
static const size_t WS_MASKT  = 6419488;    // int[2048]
static const size_t WS_IDXT   = 6421536;    // int[204]
static const size_t WS_IDXF   = 6421740;    // int[204]
static const size_t WS_MASKF  = 6421944;    // int[1026]
static const size_t WS_XHL    = 6422972;    // 2048x1632 bf16 = 1671168 f
static const size_t WS_THL    = 8094140;    // 1088x3072 bf16 = 1671168 f
static const size_t WS_WHL    = 9765308;    // 320x1632 bf16 = 261120 f (ends 10026428)
static const size_t WS_TOTAL  = 10740380;   // floats

static const size_t OFF_OUTT = 0;
static const size_t OFF_IDXT = 1077248;
static const size_t OFF_OUTF = 1077452;
static const size_t OFF_IDXF = 2154700;

typedef __bf16 bf16x8_t __attribute__((ext_vector_type(8)));
typedef float  f32x4_t  __attribute__((ext_vector_type(4)));

__device__ __forceinline__ unsigned short f2bf(float f) {
    unsigned int u = __float_as_uint(f);
    unsigned int r = (u + 0x7fffu + ((u >> 16) & 1u)) >> 16;
    return (unsigned short)r;
}
__device__ __forceinline__ float bf2f(unsigned short h) {
    return __uint_as_float(((unsigned int)h) << 16);
}

__device__ __forceinline__ float pe_val(int t, int d) {
    const float sc = (float)(-9.210340371976184 / 263.0);  // -ln(10000)/D
    int j = d >> 1;
    float div = expf((float)(2 * j) * sc);
    float a = (float)t * div;
    return (d & 1) ? cosf(a) : sinf(a);
}

// ---------------- bf16 MFMA GEMM: C = A @ Bt^T (direct epilogue) ----------------
// A [>=M x SA] bf16, Bt [Npad x SA] bf16. Tile 64x64, 4 waves 2x2.
// EPI: 0 ->f32 (n<N only); 1 bias+gelu->bf16 (zero pads to NC); 2 bias+sigmoid->f32;
//      3 ->bf16 (zero pads to NC); 4 bias+pe->f32
template<int EPI>
__global__ __launch_bounds__(256) void gemm_mfma(const unsigned short* __restrict__ A,
                                                 const unsigned short* __restrict__ Bt,
                                                 const float* __restrict__ bias,
                                                 void* __restrict__ Cv,
                                                 int M, int N, int SA, int NC,
                                                 long sBt, long sC)
{
    __shared__ unsigned short As[2][64][40];
    __shared__ unsigned short Bs[2][64][40];
    const int tid  = threadIdx.x;
    const int row0 = blockIdx.x * 64, col0 = blockIdx.y * 64;
    Bt += (size_t)blockIdx.z * (size_t)sBt;
    const long co = (long)blockIdx.z * sC;
    const int wid = tid >> 6, lane = tid & 63;
    const int wr = wid >> 1, wc = wid & 1;
    const int srow = tid >> 2, skoff = (tid & 3) * 8;
    const int fl = lane & 15, fh = lane >> 4;
    f32x4_t acc[2][2];
#pragma unroll
    for (int i = 0; i < 2; i++)
#pragma unroll
        for (int j = 0; j < 2; j++) acc[i][j] = (f32x4_t){0.f, 0.f, 0.f, 0.f};

    bf16x8_t ra, rb;
    const int nk = SA / 32;
    const unsigned short* pa = A  + (size_t)(row0 + srow) * SA + skoff;
    const unsigned short* pb = Bt + (size_t)(col0 + srow) * SA + skoff;

    ra = *(const bf16x8_t*)(pa);
    rb = *(const bf16x8_t*)(pb);
    *(bf16x8_t*)(&As[0][srow][skoff]) = ra;
    *(bf16x8_t*)(&Bs[0][srow][skoff]) = rb;
    __syncthreads();
    for (int it = 0; it < nk; ++it) {
        const int cur = it & 1;
        if (it + 1 < nk) {
            ra = *(const bf16x8_t*)(pa + (size_t)(it + 1) * 32);
            rb = *(const bf16x8_t*)(pb + (size_t)(it + 1) * 32);
        }
        bf16x8_t fa0 = *(const bf16x8_t*)(&As[cur][wr * 32 + fl][fh * 8]);
        bf16x8_t fa1 = *(const bf16x8_t*)(&As[cur][wr * 32 + 16 + fl][fh * 8]);
        bf16x8_t fb0 = *(const bf16x8_t*)(&Bs[cur][wc * 32 + fl][fh * 8]);
        bf16x8_t fb1 = *(const bf16x8_t*)(&Bs[cur][wc * 32 + 16 + fl][fh * 8]);
        acc[0][0] = __builtin_amdgcn_mfma_f32_16x16x32_bf16(fa0, fb0, acc[0][0], 0, 0, 0);
        acc[0][1] = __builtin_amdgcn_mfma_f32_16x16x32_bf16(fa0, fb1, acc[0][1], 0, 0, 0);
        acc[1][0] = __builtin_amdgcn_mfma_f32_16x16x32_bf16(fa1, fb0, acc[1][0], 0, 0, 0);
        acc[1][1] = __builtin_amdgcn_mfma_f32_16x16x32_bf16(fa1, fb1, acc[1][1], 0, 0, 0);
        if (it + 1 < nk) {
            *(bf16x8_t*)(&As[cur ^ 1][srow][skoff]) = ra;
            *(bf16x8_t*)(&Bs[cur ^ 1][srow][skoff]) = rb;
            __syncthreads();
        }
    }

#pragma unroll
    for (int fi = 0; fi < 2; fi++)
#pragma unroll
        for (int fj = 0; fj < 2; fj++)
#pragma unroll
            for (int r = 0; r < 4; r++) {
                int m = row0 + wr * 32 + fi * 16 + fh * 4 + r;
                int n = col0 + wc * 32 + fj * 16 + fl;
                if (m >= M) continue;
                float v = acc[fi][fj][r];
                if (EPI == 0) {
                    if (n < N) ((float*)Cv)[co + (size_t)m * NC + n] = v;
                } else if (EPI == 1) {
                    if (n < NC) {
                        float o = 0.0f;
                        if (n < N) { o = v + bias[n]; o = 0.5f * o * (1.0f + erff(o * 0.70710678118654752f)); }
                        ((unsigned short*)Cv)[(size_t)m * NC + n] = f2bf(o);
                    }
                } else if (EPI == 2) {
                    if (n < N) {
                        v += bias[n];
                        ((float*)Cv)[(size_t)m * NC + n] = 1.0f / (1.0f + expf(-v));
                    }
                } else if (EPI == 3) {
                    if (n < NC) {
                        ((unsigned short*)Cv)[co + (size_t)m * NC + n] = (n < N) ? f2bf(v) : (unsigned short)0;
                    }
                } else {
                    if (n < N) {
                        v += bias[n] + pe_val(m & (TDIM - 1), n);
                        ((float*)Cv)[(size_t)m * NC + n] = v;
                    }
                }
            }
}

// ---------------- glue kernels ----------------
__global__ void zero_masks_k(int* maskt, int* maskf) {
    int i = blockIdx.x * 256 + threadIdx.x;
    if (i < 2 * TDIM) maskt[i] = 0;
    if (i < PACK) maskf[i] = 0;
}

__global__ void tab_k(float* tabc, float* tabs) {
    int i = blockIdx.x * 256 + threadIdx.x;
    if (i >= 1024) return;
    double ang = (double)i * (3.14159265358979323846 * 2.0 / 1024.0);
    tabc[i] = (float)cos(ang);
    tabs[i] = (float)sin(ang);
}

// split-bf16 Twid: [1088 rows x 3072], A-packing segs {hi, hi, lo}
__global__ void twid_hl_fill_k(const float* __restrict__ tabc, const float* __restrict__ tabs,
                               unsigned short* __restrict__ thl) {
    int row = blockIdx.x;   // 0..1087
    unsigned short* dst = thl + (size_t)row * 3072;
    for (int c = threadIdx.x; c < 3072; c += 256) {
        int seg = c >> 10, t = c & 1023;
        float v = 0.0f;
        if (row < PACK) v = (row < NFREQ) ? tabc[(row * t) & 1023] : -tabs[((row - NFREQ) * t) & 1023];
        unsigned short hi = f2bf(v);
        dst[c] = (seg < 2) ? hi : f2bf(v - bf2f(hi));
    }
}

// x [2048x526] f32 -> xhl [2048x1632] bf16, A-packing segs {hi, hi, lo}
__global__ void conv_x_hl_k(const float* __restrict__ x, unsigned short* __restrict__ xhl) {
    int r = blockIdx.x;   // 0..2047
    const float* src = x + (size_t)r * CC;
    unsigned short* dst = xhl + (size_t)r * 1632;
    for (int c = threadIdx.x; c < 1632; c += 256) {
        int seg = c / 544, cc = c - seg * 544;
        float v = (cc < CC) ? src[cc] : 0.0f;
        unsigned short hi = f2bf(v);
        dst[c] = (seg < 2) ? hi : f2bf(v - bf2f(hi));
    }
}

// W_emb [263x526] f32 -> whl [320x1632] bf16, B-packing segs {hi, lo, hi}
__global__ void conv_w_hl_k(const float* __restrict__ W, unsigned short* __restrict__ whl) {
    int n = blockIdx.x;   // 0..319
    unsigned short* dst = whl + (size_t)n * 1632;
    for (int c = threadIdx.x; c < 1632; c += 256) {
        int seg = c / 544, cc = c - seg * 544;
        float v = (n < DD && cc < CC) ? W[(size_t)n * CC + cc] : 0.0f;
        unsigned short hi = f2bf(v);
        dst[c] = (seg == 1) ? f2bf(v - bf2f(hi)) : hi;
    }
}

// ex [2][1024][263] f32 -> exthl [2][320][3072] bf16 (transposed), B-packing {hi, lo, hi}
__global__ void conv_exT_hl_k(const float* __restrict__ ex, unsigned short* __restrict__ exthl) {
    int b = blockIdx.x / 320, n = blockIdx.x % 320;
    unsigned short* dst = exthl + ((size_t)b * 320 + n) * 3072;
    const float* src = ex + (size_t)b * TDIM * DD + n;
    for (int c = threadIdx.x; c < 3072; c += 256) {
        int seg = c >> 10, t = c & 1023;
        float v = (n < DD) ? src[(size_t)t * DD] : 0.0f;
        unsigned short hi = f2bf(v);
        dst[c] = (seg == 1) ? f2bf(v - bf2f(hi)) : hi;
    }
}

__global__ void itwid_fill_bf_k(const float* __restrict__ tabc, const float* __restrict__ tabs,
                                unsigned short* __restrict__ IT) {
    int t = blockIdx.x;
    for (int col = threadIdx.x; col < 1056; col += 256) {
        float v = 0.0f;
        if (col < NFREQ) {
            int k = col;
            float w = (k == 0 || k == 512) ? 1.0f : 2.0f;
            v = (w * (1.0f / 1024.0f)) * tabc[(k * t) & 1023];
        } else if (col < PACK) {
            int k = col - NFREQ;
            v = (k == 0 || k == 512) ? 0.0f : (-2.0f / 1024.0f) * tabs[(k * t) & 1023];
        }
        IT[(size_t)t * 1056 + col] = f2bf(v);
    }
}

// fused weight conversions (writes ALL pad zeros)
__global__ void conv_weights_k(const float* __restrict__ W1t, const float* __restrict__ W2t,
                               const float* __restrict__ W_emb,
                               unsigned short* __restrict__ w1b, unsigned short* __restrict__ w2b,
                               unsigned short* __restrict__ wemT) {
    int r = blockIdx.x;   // 0..1215
    if (r < 640) {
        int rr = r & 319;
        const float* src = (r < 320) ? W1t : W2t;
        unsigned short* dst = (r < 320) ? w1b : w2b;
        for (int c = threadIdx.x; c < 288; c += 256) {
            float v = (rr < DD && c < DD) ? src[(size_t)rr * DD + c] : 0.0f;
            dst[(size_t)rr * 288 + c] = f2bf(v);
        }
    } else {
        int rr = r - 640;  // 0..575
        for (int c = threadIdx.x; c < 288; c += 256) {
            float v = (rr < CC && c < DD) ? W_emb[(size_t)c * CC + rr] : 0.0f;
            wemT[(size_t)rr * 288 + c] = f2bf(v);
        }
    }
}

__global__ __launch_bounds__(64) void sliding_score_k(const float* __restrict__ ex,
                                                      double* __restrict__ score)
{
    const int ib = blockIdx.x;
    const int t = ib & (TDIM - 1);
    const int t0 = max(0, t - 24);
    const int nt = t - t0 + 1;
    const float cnt = (float)nt;
    const int lane = threadIdx.x;
    const float* base = ex + ((size_t)(ib - t) + t0) * DD;
    double ms = 0.0, vs = 0.0;
    for (int d = lane; d < DD; d += 64) {
        float s1 = 0.0f, s2 = 0.0f;
        for (int r = 0; r < nt; r++) {
            float v = base[(size_t)r * DD + d];
            s1 += v;
            s2 += v * v;
        }
        float m1 = s1 / cnt;
        float var = s2 / cnt - m1 * m1;
        ms += (double)m1;
        vs += (double)var;
    }
#pragma unroll
    for (int off = 32; off; off >>= 1) { ms += __shfl_xor(ms, off); vs += __shfl_xor(vs, off); }
    if (lane == 0) score[ib] = vs / (ms + (double)1e-6f);
}

__global__ __launch_bounds__(512) void topk_sort_k(const double* __restrict__ score,
                                                   int n, int kcount,
                                                   float* __restrict__ out_f,
                                                   int* __restrict__ out_i,
                                                   int* __restrict__ mask)
{
    __shared__ double sv[1024];
    __shared__ int    si[1024];
    const int b = blockIdx.x, tid = threadIdx.x;
    const double* s = score + (size_t)b * n;
    for (int i = tid; i < 1024; i += 512) {
        sv[i] = (i < n) ? s[i] : -1.0e300;
        si[i] = i;
    }
    __syncthreads();
    for (int k = 2; k <= 1024; k <<= 1) {
        for (int j = k >> 1; j > 0; j >>= 1) {
            for (int t = tid; t < 1024; t += 512) {
                int l = t ^ j;
                if (l > t) {
                    double v0 = sv[t], v1 = sv[l];
                    int i0 = si[t], i1 = si[l];
                    bool g = (v0 > v1) || (v0 == v1 && i0 < i1);
                    bool wrong = ((t & k) == 0) ? !g : g;
                    if (wrong) {
                        sv[t] = v1; sv[l] = v0;
                        si[t] = i1; si[l] = i0;
                    }
                }
            }
            __syncthreads();
        }
    }
    for (int t = tid; t < kcount; t += 512) {
        int bi = si[t];
        out_f[(size_t)b * kcount + t] = (float)bi;
        out_i[b * kcount + t] = bi;
        mask[b * n + bi] = 1;
    }
}

__global__ void build_masked_k(const float* __restrict__ ex, const float* __restrict__ ttok,
                               const int* __restrict__ maskt, unsigned short* __restrict__ mb) {
    int bt = blockIdx.x;
    int d = threadIdx.x;
    if (d >= 288) return;
    float v = 0.0f;
    if (d < DD) v = maskt[bt] ? ttok[d] : ex[(size_t)bt * DD + d];
    mb[(size_t)bt * 288 + d] = f2bf(v);
}

__global__ void select_k(const int* __restrict__ maskt, const float* __restrict__ proj,
                         unsigned short* __restrict__ mb) {
    int bt = blockIdx.x;
    int d = threadIdx.x;
    if (d >= DD) return;
    if (!maskt[bt]) mb[(size_t)bt * 288 + d] = f2bf(proj[(size_t)bt * DD + d]);
}

__global__ void mag_k(const float* __restrict__ cxp, double* __restrict__ magm) {
    int ib = blockIdx.x;
    int b = ib / NFREQ, k = ib % NFREQ;
    int lane = threadIdx.x;
    const float* re = cxp + ((size_t)b * PACK + k) * DD;
    const float* im = cxp + ((size_t)b * PACK + NFREQ + k) * DD;
    double acc = 0.0;
    for (int d = lane; d < DD; d += 64) {
        float r = re[d], i = im[d];
        acc += (double)sqrtf(r * r + i * i);
    }
#pragma unroll
    for (int off = 32; off; off >>= 1) acc += __shfl_xor(acc, off);
    if (lane == 0) magm[ib] = acc / (double)DD;
}

__global__ void fmask_apply_k(float* __restrict__ cxp, const int* __restrict__ idxf,
                              const float* __restrict__ tokr, const float* __restrict__ toki) {
    int b = blockIdx.x / KTOP, j = blockIdx.x % KTOP;
    int d = threadIdx.x;
    if (d >= DD) return;
    int k = idxf[b * KTOP + j];
    float* base = cxp + (size_t)b * PACK * DD;
    base[(size_t)k * DD + d] = tokr[d];
    base[(size_t)(NFREQ + k) * DD + d] = toki[d];
}

// cxp f32 [2][1026][263] -> cxpT bf16 [2][320][1056] (full fill incl. pads)
__global__ void conv_cxpT_k(const float* __restrict__ cxp, unsigned short* __restrict__ cxpT) {
    int b = blockIdx.x / 320, n = blockIdx.x % 320;
    unsigned short* dst = cxpT + ((size_t)b * 320 + n) * 1056;
    const float* src = cxp + (size_t)b * PACK * DD + n;
    for (int c = threadIdx.x; c < 1056; c += 256) {
        float v = (n < DD && c < PACK) ? src[(size_t)c * DD] : 0.0f;
        dst[c] = f2bf(v);
    }
}

// ---------------- launch ----------------
extern "C" void kernel_launch(void* const* d_in, const int* in_sizes, int n_in,
                              void* d_out, int out_size, void* d_ws, size_t ws_size,
                              hipStream_t stream) {
    (void)in_sizes; (void)n_in; (void)out_size; (void)ws_size;
    const float* x      = (const float*)d_in[0];
    const float* W_emb  = (const float*)d_in[1];
    const float* b_emb  = (const float*)d_in[2];
    const float* ttok   = (const float*)d_in[3];
    const float* W1t    = (const float*)d_in[4];
    const float* b1t    = (const float*)d_in[5];
    const float* W2t    = (const float*)d_in[6];
    const float* b2t    = (const float*)d_in[7];
    const float* ftr    = (const float*)d_in[8];
    const float* fti    = (const float*)d_in[9];
    float* out = (float*)d_out;
    float* ws  = (float*)d_ws;

    float* ex     = ws + WS_EX;
    float* proj   = ws + WS_PROJ;
    float* cxp    = ws + WS_CXP;
    float* tabc   = ws + WS_TABC;
    float* tabs   = ws + WS_TABS;
    double* score = (double*)(ws + WS_SCORE);
    double* magm  = (double*)(ws + WS_MAGM);
    int* maskt    = (int*)(ws + WS_MASKT);
    int* idxt     = (int*)(ws + WS_IDXT);
    int* idxf     = (int*)(ws + WS_IDXF);
    int* maskf    = (int*)(ws + WS_MASKF);
    unsigned short* w1b   = (unsigned short*)(ws + WS_W1BF);
    unsigned short* w2b   = (unsigned short*)(ws + WS_W2BF);
    unsigned short* wemT  = (unsigned short*)(ws + WS_WEMT);
    unsigned short* maskb = (unsigned short*)(ws + WS_MASKB);
    unsigned short* hb    = (unsigned short*)(ws + WS_HBF);
    unsigned short* xtb   = (unsigned short*)(ws + WS_XTBF);
    unsigned short* itb   = (unsigned short*)(ws + WS_ITBF);
    unsigned short* cxpT  = (unsigned short*)(ws + WS_CXPT);
    unsigned short* xhl   = (unsigned short*)(ws + WS_XHL);
    unsigned short* thl   = (unsigned short*)(ws + WS_THL);
    unsigned short* whl   = (unsigned short*)(ws + WS_WHL);
    unsigned short* exthl = (unsigned short*)(ws + WS_EXTHL);

    // init + tables + operand conversions
    zero_masks_k<<<8, 256, 0, stream>>>(maskt, maskf);
    tab_k<<<4, 256, 0, stream>>>(tabc, tabs);
    twid_hl_fill_k<<<1088, 256, 0, stream>>>(tabc, tabs, thl);
    itwid_fill_bf_k<<<TDIM, 256, 0, stream>>>(tabc, tabs, itb);
    conv_weights_k<<<1216, 256, 0, stream>>>(W1t, W2t, W_emb, w1b, w2b, wemT);
    conv_x_hl_k<<<2048, 256, 0, stream>>>(x, xhl);
    conv_w_hl_k<<<320, 256, 0, stream>>>(W_emb, whl);

    // ex = x @ W_emb^T + b_emb + pe  (split-bf16 MFMA, K'=3*544)
    gemm_mfma<4><<<dim3(32, 5), 256, 0, stream>>>(xhl, whl, b_emb, ex,
                                                  2048, DD, 1632, DD, 0, 0);

    // temporal score -> topk
    sliding_score_k<<<2048, 64, 0, stream>>>(ex, score);
    topk_sort_k<<<2, 512, 0, stream>>>(score, TDIM, KTOP, out + OFF_IDXT, idxt, maskt);

    // masked -> h -> proj -> select -> out_t
    build_masked_k<<<2048, 320, 0, stream>>>(ex, ttok, maskt, maskb);
    gemm_mfma<1><<<dim3(32, 5), 256, 0, stream>>>(maskb, w1b, b1t, hb, 2048, DD, 288, 288, 0, 0);
    gemm_mfma<2><<<dim3(32, 5), 256, 0, stream>>>(hb, w2b, b2t, proj, 2048, DD, 288, DD, 0, 0);
    select_k<<<2048, 320, 0, stream>>>(maskt, proj, maskb);
    gemm_mfma<0><<<dim3(32, 9), 256, 0, stream>>>(maskb, wemT, nullptr, out + OFF_OUTT,
                                                  2048, CC, 288, CC, 0, 0);

    // forward DFT (split-bf16 MFMA, K'=3*1024): cxp[b] = Twid @ ex[b]
    conv_exT_hl_k<<<640, 256, 0, stream>>>(ex, exthl);
    gemm_mfma<0><<<dim3(17, 5, 2), 256, 0, stream>>>(thl, exthl, nullptr, cxp,
                                                     PACK, DD, 3072, DD,
                                                     (long)320 * 3072, (long)PACK * DD);
    mag_k<<<2 * NFREQ, 64, 0, stream>>>(cxp, magm);
    topk_sort_k<<<2, 512, 0, stream>>>(magm, NFREQ, KTOP, out + OFF_IDXF, idxf, maskf);
    fmask_apply_k<<<2 * KTOP, 320, 0, stream>>>(cxp, idxf, ftr, fti);
    conv_cxpT_k<<<640, 256, 0, stream>>>(cxp, cxpT);

    // inverse DFT (MFMA): xtb[b] = ITwid @ cxp[b]^T^T
    gemm_mfma<3><<<dim3(16, 5, 2), 256, 0, stream>>>(itb, cxpT, nullptr, xtb,
                                                     1024, DD, 1056, 288,
                                                     (long)320 * 1056, (long)1024 * 288);
    // out_f = xt @ W_emb
    gemm_mfma<0><<<dim3(32, 9), 256, 0, stream>>>(xtb, wemT, nullptr, out + OFF_OUTF,
                                                  2048, CC, 288, CC, 0, 0);
}

// Round 11
// 226.921 us; speedup vs baseline: 1.1233x; 1.1233x over previous
//
#include <hip/hip_runtime.h>

#define TDIM 1024
#define DD   263
#define CC   526
#define NFREQ 513
#define PACK 1026
#define KTOP 102

// ---------------- ws layout (float offsets) ----------------
static const size_t WS_EX     = 0;          // 538624 f32
static const size_t WS_W1BF   = 538624;     // 320x288 bf16
static const size_t WS_W2BF   = 584704;
static const size_t WS_WEMT   = 630784;     // 576x288 bf16
static const size_t WS_MASKB  = 1615872;    // 2048x288 bf16
static const size_t WS_HBF    = 2154496;
static const size_t WS_PROJ   = 2693120;    // f32 2048x263
static const size_t WS_XTBF   = 3231744;    // 2x1024x288 bf16
static const size_t WS_CXP    = 3770368;    // f32 2*1026*263
static const size_t WS_EXTHL  = 4310044;    // [640][3072] bf16 = 983040 f
static const size_t WS_ITBF   = 5360668;    // 1024x1056 bf16
static const size_t WS_CXPT   = 5901340;    // [640][1056] bf16
static const size_t WS_TABC   = 6411292;    // 1024
static const size_t WS_TABS   = 6412316;    // 1024
static const size_t WS_SCORE  = 6413340;    // double[2048]
static const size_t WS_MAGM   = 6417436;    // double[1026]
static const size_t WS_MASKT  = 6419488;    // int[2048]
static const size_t WS_IDXT   = 6421536;    // int[204]
static const size_t WS_IDXF   = 6421740;    // int[204]
static const size_t WS_MASKF  = 6421944;    // int[1026]
static const size_t WS_XHL    = 6422972;    // 2048x1632 bf16 = 1671168 f
static const size_t WS_THL    = 8094140;    // 1088x3072 bf16 = 1671168 f
static const size_t WS_WHL    = 9765308;    // 320x1632 bf16 = 261120 f
static const size_t WS_TOTAL  = 10740380;   // floats

static const size_t OFF_OUTT = 0;
static const size_t OFF_IDXT = 1077248;
static const size_t OFF_OUTF = 1077452;
static const size_t OFF_IDXF = 2154700;

typedef __bf16 bf16x8_t __attribute__((ext_vector_type(8)));
typedef float  f32x4_t  __attribute__((ext_vector_type(4)));

__device__ __forceinline__ unsigned short f2bf(float f) {
    unsigned int u = __float_as_uint(f);
    unsigned int r = (u + 0x7fffu + ((u >> 16) & 1u)) >> 16;
    return (unsigned short)r;
}
__device__ __forceinline__ float bf2f(unsigned short h) {
    return __uint_as_float(((unsigned int)h) << 16);
}

__device__ __forceinline__ float pe_val(int t, int d) {
    const float sc = (float)(-9.210340371976184 / 263.0);  // -ln(10000)/D
    int j = d >> 1;
    float div = expf((float)(2 * j) * sc);
    float a = (float)t * div;
    return (d & 1) ? cosf(a) : sinf(a);
}

// raw workgroup barrier: no implicit vmcnt(0) drain (prefetch stays in flight)
#define WG_FENCE()   asm volatile("" ::: "memory")
#define WG_BARRIER() { WG_FENCE(); __builtin_amdgcn_s_barrier(); WG_FENCE(); }

// ---------------- bf16 MFMA GEMM, reg-prefetch-queue + XCD swizzle ----------------
// C = A @ Bt^T. A [>=M x SA] bf16, Bt [64*gy x SA] bf16. Tile 64x64, 4 waves 2x2.
// Flat grid (gx*gy blocks), x-major XCD-bijective swizzle.
// EPI: 0 ->f32 [m*NC+n], n<N;  1 bias+gelu->bf16 pad to NC;  2 bias+sigmoid->f32;
//      4 bias+pe->f32;  5 DFT scatter ->cxp f32;  6 iDFT scatter ->xtb bf16
template<int EPI>
__global__ __launch_bounds__(256) void gemm_mfma(const unsigned short* __restrict__ A,
                                                 const unsigned short* __restrict__ Bt,
                                                 const float* __restrict__ bias,
                                                 void* __restrict__ Cv,
                                                 int M, int N, int SA, int NC, int gy)
{
    __shared__ unsigned short As[64][40];
    __shared__ unsigned short Bs[64][40];
    // XCD-bijective chunked swizzle (m204): consecutive logical ids share A-panel
    const int nwg = gridDim.x;
    const int hw = blockIdx.x;
    const int q = nwg >> 3, r = nwg & 7, xcd = hw & 7;
    const int logical = (xcd < r ? xcd * (q + 1) : r * (q + 1) + (xcd - r) * q) + (hw >> 3);
    const int row0 = (logical / gy) * 64, col0 = (logical % gy) * 64;

    const int tid  = threadIdx.x;
    const int wid = tid >> 6, lane = tid & 63;
    const int wr = wid >> 1, wc = wid & 1;
    const int srow = tid >> 2, skoff = (tid & 3) * 8;
    const int fl = lane & 15, fh = lane >> 4;
    f32x4_t acc[2][2];
#pragma unroll
    for (int i = 0; i < 2; i++)
#pragma unroll
        for (int j = 0; j < 2; j++) acc[i][j] = (f32x4_t){0.f, 0.f, 0.f, 0.f};

    const int nk = SA / 32;
    const unsigned short* pa = A  + (size_t)(row0 + srow) * SA + skoff;
    const unsigned short* pb = Bt + (size_t)(col0 + srow) * SA + skoff;

    bf16x8_t qa[4], qb[4];
#pragma unroll
    for (int j = 0; j < 4; ++j) {
        if (j < nk) {
            qa[j] = *(const bf16x8_t*)(pa + (size_t)j * 32);
            qb[j] = *(const bf16x8_t*)(pb + (size_t)j * 32);
        }
    }

    for (int itb = 0; itb < nk; itb += 4) {
#pragma unroll
        for (int j = 0; j < 4; ++j) {
            const int it = itb + j;
            if (it < nk) {
                if (it > 0) WG_BARRIER();            // all waves done reading LDS
                *(bf16x8_t*)(&As[srow][skoff]) = qa[j];   // compiler waits vmcnt for qa[j]
                *(bf16x8_t*)(&Bs[srow][skoff]) = qb[j];
                asm volatile("s_waitcnt lgkmcnt(0)" ::: "memory");
                WG_BARRIER();                         // all writes visible
                bf16x8_t fa0 = *(const bf16x8_t*)(&As[wr * 32 + fl][fh * 8]);
                bf16x8_t fa1 = *(const bf16x8_t*)(&As[wr * 32 + 16 + fl][fh * 8]);
                bf16x8_t fb0 = *(const bf16x8_t*)(&Bs[wc * 32 + fl][fh * 8]);
                bf16x8_t fb1 = *(const bf16x8_t*)(&Bs[wc * 32 + 16 + fl][fh * 8]);
                acc[0][0] = __builtin_amdgcn_mfma_f32_16x16x32_bf16(fa0, fb0, acc[0][0], 0, 0, 0);
                acc[0][1] = __builtin_amdgcn_mfma_f32_16x16x32_bf16(fa0, fb1, acc[0][1], 0, 0, 0);
                acc[1][0] = __builtin_amdgcn_mfma_f32_16x16x32_bf16(fa1, fb0, acc[1][0], 0, 0, 0);
                acc[1][1] = __builtin_amdgcn_mfma_f32_16x16x32_bf16(fa1, fb1, acc[1][1], 0, 0, 0);
                if (it + 4 < nk) {                    // refill queue slot j (stays in flight)
                    qa[j] = *(const bf16x8_t*)(pa + (size_t)(it + 4) * 32);
                    qb[j] = *(const bf16x8_t*)(pb + (size_t)(it + 4) * 32);
                }
            }
        }
    }

#pragma unroll
    for (int fi = 0; fi < 2; fi++)
#pragma unroll
        for (int fj = 0; fj < 2; fj++)
#pragma unroll
            for (int rr = 0; rr < 4; rr++) {
                int m = row0 + wr * 32 + fi * 16 + fh * 4 + rr;
                int n = col0 + wc * 32 + fj * 16 + fl;
                if (m >= M) continue;
                float v = acc[fi][fj][rr];
                if (EPI == 0) {
                    if (n < N) ((float*)Cv)[(size_t)m * NC + n] = v;
                } else if (EPI == 1) {
                    if (n < NC) {
                        float o = 0.0f;
                        if (n < N) { o = v + bias[n]; o = 0.5f * o * (1.0f + erff(o * 0.70710678118654752f)); }
                        ((unsigned short*)Cv)[(size_t)m * NC + n] = f2bf(o);
                    }
                } else if (EPI == 2) {
                    if (n < N) {
                        v += bias[n];
                        ((float*)Cv)[(size_t)m * NC + n] = 1.0f / (1.0f + expf(-v));
                    }
                } else if (EPI == 4) {
                    if (n < N) {
                        v += bias[n] + pe_val(m & (TDIM - 1), n);
                        ((float*)Cv)[(size_t)m * NC + n] = v;
                    }
                } else if (EPI == 5) {
                    int b = n / 320, col = n - b * 320;
                    if (col < DD) ((float*)Cv)[((size_t)b * PACK + m) * DD + col] = v;
                } else {  // EPI 6
                    int b = n / 320, col = n - b * 320;
                    if (col < 288) {
                        unsigned short o = (col < DD) ? f2bf(v) : (unsigned short)0;
                        ((unsigned short*)Cv)[((size_t)(b * 1024 + m)) * 288 + col] = o;
                    }
                }
            }
}

// ---------------- glue kernels ----------------
__global__ void zero_masks_k(int* maskt, int* maskf) {
    int i = blockIdx.x * 256 + threadIdx.x;
    if (i < 2 * TDIM) maskt[i] = 0;
    if (i < PACK) maskf[i] = 0;
}

__global__ void tab_k(float* tabc, float* tabs) {
    int i = blockIdx.x * 256 + threadIdx.x;
    if (i >= 1024) return;
    double ang = (double)i * (3.14159265358979323846 * 2.0 / 1024.0);
    tabc[i] = (float)cos(ang);
    tabs[i] = (float)sin(ang);
}

// split-bf16 Twid: [1088 rows x 3072], A-packing segs {hi, hi, lo}
__global__ void twid_hl_fill_k(const float* __restrict__ tabc, const float* __restrict__ tabs,
                               unsigned short* __restrict__ thl) {
    int row = blockIdx.x;   // 0..1087
    unsigned short* dst = thl + (size_t)row * 3072;
    for (int c = threadIdx.x; c < 3072; c += 256) {
        int seg = c >> 10, t = c & 1023;
        float v = 0.0f;
        if (row < PACK) v = (row < NFREQ) ? tabc[(row * t) & 1023] : -tabs[((row - NFREQ) * t) & 1023];
        unsigned short hi = f2bf(v);
        dst[c] = (seg < 2) ? hi : f2bf(v - bf2f(hi));
    }
}

// x [2048x526] f32 -> xhl [2048x1632] bf16, A-packing segs {hi, hi, lo}
__global__ void conv_x_hl_k(const float* __restrict__ x, unsigned short* __restrict__ xhl) {
    int r = blockIdx.x;   // 0..2047
    const float* src = x + (size_t)r * CC;
    unsigned short* dst = xhl + (size_t)r * 1632;
    for (int c = threadIdx.x; c < 1632; c += 256) {
        int seg = c / 544, cc = c - seg * 544;
        float v = (cc < CC) ? src[cc] : 0.0f;
        unsigned short hi = f2bf(v);
        dst[c] = (seg < 2) ? hi : f2bf(v - bf2f(hi));
    }
}

// W_emb [263x526] f32 -> whl [320x1632] bf16, B-packing segs {hi, lo, hi}
__global__ void conv_w_hl_k(const float* __restrict__ W, unsigned short* __restrict__ whl) {
    int n = blockIdx.x;   // 0..319
    unsigned short* dst = whl + (size_t)n * 1632;
    for (int c = threadIdx.x; c < 1632; c += 256) {
        int seg = c / 544, cc = c - seg * 544;
        float v = (n < DD && cc < CC) ? W[(size_t)n * CC + cc] : 0.0f;
        unsigned short hi = f2bf(v);
        dst[c] = (seg == 1) ? f2bf(v - bf2f(hi)) : hi;
    }
}

// ex [2][1024][263] f32 -> exthl [640][3072] bf16 (row = 320b+n), B-packing {hi, lo, hi}
__global__ void conv_exT_hl_k(const float* __restrict__ ex, unsigned short* __restrict__ exthl) {
    int b = blockIdx.x / 320, n = blockIdx.x % 320;
    unsigned short* dst = exthl + ((size_t)b * 320 + n) * 3072;
    const float* src = ex + (size_t)b * TDIM * DD + n;
    for (int c = threadIdx.x; c < 3072; c += 256) {
        int seg = c >> 10, t = c & 1023;
        float v = (n < DD) ? src[(size_t)t * DD] : 0.0f;
        unsigned short hi = f2bf(v);
        dst[c] = (seg == 1) ? f2bf(v - bf2f(hi)) : hi;
    }
}

__global__ void itwid_fill_bf_k(const float* __restrict__ tabc, const float* __restrict__ tabs,
                                unsigned short* __restrict__ IT) {
    int t = blockIdx.x;
    for (int col = threadIdx.x; col < 1056; col += 256) {
        float v = 0.0f;
        if (col < NFREQ) {
            int k = col;
            float w = (k == 0 || k == 512) ? 1.0f : 2.0f;
            v = (w * (1.0f / 1024.0f)) * tabc[(k * t) & 1023];
        } else if (col < PACK) {
            int k = col - NFREQ;
            v = (k == 0 || k == 512) ? 0.0f : (-2.0f / 1024.0f) * tabs[(k * t) & 1023];
        }
        IT[(size_t)t * 1056 + col] = f2bf(v);
    }
}

// fused weight conversions (writes ALL pad zeros)
__global__ void conv_weights_k(const float* __restrict__ W1t, const float* __restrict__ W2t,
                               const float* __restrict__ W_emb,
                               unsigned short* __restrict__ w1b, unsigned short* __restrict__ w2b,
                               unsigned short* __restrict__ wemT) {
    int r = blockIdx.x;   // 0..1215
    if (r < 640) {
        int rr = r & 319;
        const float* src = (r < 320) ? W1t : W2t;
        unsigned short* dst = (r < 320) ? w1b : w2b;
        for (int c = threadIdx.x; c < 288; c += 256) {
            float v = (rr < DD && c < DD) ? src[(size_t)rr * DD + c] : 0.0f;
            dst[(size_t)rr * 288 + c] = f2bf(v);
        }
    } else {
        int rr = r - 640;  // 0..575
        for (int c = threadIdx.x; c < 288; c += 256) {
            float v = (rr < CC && c < DD) ? W_emb[(size_t)c * CC + rr] : 0.0f;
            wemT[(size_t)rr * 288 + c] = f2bf(v);
        }
    }
}

__global__ __launch_bounds__(64) void sliding_score_k(const float* __restrict__ ex,
                                                      double* __restrict__ score)
{
    const int ib = blockIdx.x;
    const int t = ib & (TDIM - 1);
    const int t0 = max(0, t - 24);
    const int nt = t - t0 + 1;
    const float cnt = (float)nt;
    const int lane = threadIdx.x;
    const float* base = ex + ((size_t)(ib - t) + t0) * DD;
    double ms = 0.0, vs = 0.0;
    for (int d = lane; d < DD; d += 64) {
        float s1 = 0.0f, s2 = 0.0f;
        for (int r = 0; r < nt; r++) {
            float v = base[(size_t)r * DD + d];
            s1 += v;
            s2 += v * v;
        }
        float m1 = s1 / cnt;
        float var = s2 / cnt - m1 * m1;
        ms += (double)m1;
        vs += (double)var;
    }
#pragma unroll
    for (int off = 32; off; off >>= 1) { ms += __shfl_xor(ms, off); vs += __shfl_xor(vs, off); }
    if (lane == 0) score[ib] = vs / (ms + (double)1e-6f);
}

__global__ __launch_bounds__(512) void topk_sort_k(const double* __restrict__ score,
                                                   int n, int kcount,
                                                   float* __restrict__ out_f,
                                                   int* __restrict__ out_i,
                                                   int* __restrict__ mask)
{
    __shared__ double sv[1024];
    __shared__ int    si[1024];
    const int b = blockIdx.x, tid = threadIdx.x;
    const double* s = score + (size_t)b * n;
    for (int i = tid; i < 1024; i += 512) {
        sv[i] = (i < n) ? s[i] : -1.0e300;
        si[i] = i;
    }
    __syncthreads();
    for (int k = 2; k <= 1024; k <<= 1) {
        for (int j = k >> 1; j > 0; j >>= 1) {
            for (int t = tid; t < 1024; t += 512) {
                int l = t ^ j;
                if (l > t) {
                    double v0 = sv[t], v1 = sv[l];
                    int i0 = si[t], i1 = si[l];
                    bool g = (v0 > v1) || (v0 == v1 && i0 < i1);
                    bool wrong = ((t & k) == 0) ? !g : g;
                    if (wrong) {
                        sv[t] = v1; sv[l] = v0;
                        si[t] = i1; si[l] = i0;
                    }
                }
            }
            __syncthreads();
        }
    }
    for (int t = tid; t < kcount; t += 512) {
        int bi = si[t];
        out_f[(size_t)b * kcount + t] = (float)bi;
        out_i[b * kcount + t] = bi;
        mask[b * n + bi] = 1;
    }
}

__global__ void build_masked_k(const float* __restrict__ ex, const float* __restrict__ ttok,
                               const int* __restrict__ maskt, unsigned short* __restrict__ mb) {
    int bt = blockIdx.x;
    int d = threadIdx.x;
    if (d >= 288) return;
    float v = 0.0f;
    if (d < DD) v = maskt[bt] ? ttok[d] : ex[(size_t)bt * DD + d];
    mb[(size_t)bt * 288 + d] = f2bf(v);
}

__global__ void select_k(const int* __restrict__ maskt, const float* __restrict__ proj,
                         unsigned short* __restrict__ mb) {
    int bt = blockIdx.x;
    int d = threadIdx.x;
    if (d >= DD) return;
    if (!maskt[bt]) mb[(size_t)bt * 288 + d] = f2bf(proj[(size_t)bt * DD + d]);
}

__global__ void mag_k(const float* __restrict__ cxp, double* __restrict__ magm) {
    int ib = blockIdx.x;
    int b = ib / NFREQ, k = ib % NFREQ;
    int lane = threadIdx.x;
    const float* re = cxp + ((size_t)b * PACK + k) * DD;
    const float* im = cxp + ((size_t)b * PACK + NFREQ + k) * DD;
    double acc = 0.0;
    for (int d = lane; d < DD; d += 64) {
        float r = re[d], i = im[d];
        acc += (double)sqrtf(r * r + i * i);
    }
#pragma unroll
    for (int off = 32; off; off >>= 1) acc += __shfl_xor(acc, off);
    if (lane == 0) magm[ib] = acc / (double)DD;
}

__global__ void fmask_apply_k(float* __restrict__ cxp, const int* __restrict__ idxf,
                              const float* __restrict__ tokr, const float* __restrict__ toki) {
    int b = blockIdx.x / KTOP, j = blockIdx.x % KTOP;
    int d = threadIdx.x;
    if (d >= DD) return;
    int k = idxf[b * KTOP + j];
    float* base = cxp + (size_t)b * PACK * DD;
    base[(size_t)k * DD + d] = tokr[d];
    base[(size_t)(NFREQ + k) * DD + d] = toki[d];
}

// cxp f32 [2][1026][263] -> cxpT bf16 [640][1056] (row = 320b+n, full fill incl. pads)
__global__ void conv_cxpT_k(const float* __restrict__ cxp, unsigned short* __restrict__ cxpT) {
    int b = blockIdx.x / 320, n = blockIdx.x % 320;
    unsigned short* dst = cxpT + ((size_t)b * 320 + n) * 1056;
    const float* src = cxp + (size_t)b * PACK * DD + n;
    for (int c = threadIdx.x; c < 1056; c += 256) {
        float v = (n < DD && c < PACK) ? src[(size_t)c * DD] : 0.0f;
        dst[c] = f2bf(v);
    }
}

// ---------------- launch ----------------
extern "C" void kernel_launch(void* const* d_in, const int* in_sizes, int n_in,
                              void* d_out, int out_size, void* d_ws, size_t ws_size,
                              hipStream_t stream) {
    (void)in_sizes; (void)n_in; (void)out_size; (void)ws_size;
    const float* x      = (const float*)d_in[0];
    const float* W_emb  = (const float*)d_in[1];
    const float* b_emb  = (const float*)d_in[2];
    const float* ttok   = (const float*)d_in[3];
    const float* W1t    = (const float*)d_in[4];
    const float* b1t    = (const float*)d_in[5];
    const float* W2t    = (const float*)d_in[6];
    const float* b2t    = (const float*)d_in[7];
    const float* ftr    = (const float*)d_in[8];
    const float* fti    = (const float*)d_in[9];
    float* out = (float*)d_out;
    float* ws  = (float*)d_ws;

    float* ex     = ws + WS_EX;
    float* proj   = ws + WS_PROJ;
    float* cxp    = ws + WS_CXP;
    float* tabc   = ws + WS_TABC;
    float* tabs   = ws + WS_TABS;
    double* score = (double*)(ws + WS_SCORE);
    double* magm  = (double*)(ws + WS_MAGM);
    int* maskt    = (int*)(ws + WS_MASKT);
    int* idxt     = (int*)(ws + WS_IDXT);
    int* idxf     = (int*)(ws + WS_IDXF);
    int* maskf    = (int*)(ws + WS_MASKF);
    unsigned short* w1b   = (unsigned short*)(ws + WS_W1BF);
    unsigned short* w2b   = (unsigned short*)(ws + WS_W2BF);
    unsigned short* wemT  = (unsigned short*)(ws + WS_WEMT);
    unsigned short* maskb = (unsigned short*)(ws + WS_MASKB);
    unsigned short* hb    = (unsigned short*)(ws + WS_HBF);
    unsigned short* xtb   = (unsigned short*)(ws + WS_XTBF);
    unsigned short* itb   = (unsigned short*)(ws + WS_ITBF);
    unsigned short* cxpT  = (unsigned short*)(ws + WS_CXPT);
    unsigned short* xhl   = (unsigned short*)(ws + WS_XHL);
    unsigned short* thl   = (unsigned short*)(ws + WS_THL);
    unsigned short* whl   = (unsigned short*)(ws + WS_WHL);
    unsigned short* exthl = (unsigned short*)(ws + WS_EXTHL);

    // init + tables + operand conversions
    zero_masks_k<<<8, 256, 0, stream>>>(maskt, maskf);
    tab_k<<<4, 256, 0, stream>>>(tabc, tabs);
    twid_hl_fill_k<<<1088, 256, 0, stream>>>(tabc, tabs, thl);
    itwid_fill_bf_k<<<TDIM, 256, 0, stream>>>(tabc, tabs, itb);
    conv_weights_k<<<1216, 256, 0, stream>>>(W1t, W2t, W_emb, w1b, w2b, wemT);
    conv_x_hl_k<<<2048, 256, 0, stream>>>(x, xhl);
    conv_w_hl_k<<<320, 256, 0, stream>>>(W_emb, whl);

    // ex = x @ W_emb^T + b_emb + pe  (split-bf16 MFMA, K'=1632)
    gemm_mfma<4><<<160, 256, 0, stream>>>(xhl, whl, b_emb, ex, 2048, DD, 1632, DD, 5);

    // temporal score -> topk
    sliding_score_k<<<2048, 64, 0, stream>>>(ex, score);
    topk_sort_k<<<2, 512, 0, stream>>>(score, TDIM, KTOP, out + OFF_IDXT, idxt, maskt);

    // masked -> h -> proj -> select -> out_t
    build_masked_k<<<2048, 320, 0, stream>>>(ex, ttok, maskt, maskb);
    gemm_mfma<1><<<160, 256, 0, stream>>>(maskb, w1b, b1t, hb, 2048, DD, 288, 288, 5);
    gemm_mfma<2><<<160, 256, 0, stream>>>(hb, w2b, b2t, proj, 2048, DD, 288, DD, 5);
    select_k<<<2048, 320, 0, stream>>>(maskt, proj, maskb);
    gemm_mfma<0><<<288, 256, 0, stream>>>(maskb, wemT, nullptr, out + OFF_OUTT, 2048, CC, 288, CC, 9);

    // forward DFT (split-bf16 MFMA, K'=3072, batches merged in N): cxp[b] = Twid @ ex[b]
    conv_exT_hl_k<<<640, 256, 0, stream>>>(ex, exthl);
    gemm_mfma<5><<<170, 256, 0, stream>>>(thl, exthl, nullptr, cxp, PACK, 640, 3072, 0, 10);
    mag_k<<<2 * NFREQ, 64, 0, stream>>>(cxp, magm);
    topk_sort_k<<<2, 512, 0, stream>>>(magm, NFREQ, KTOP, out + OFF_IDXF, idxf, maskf);
    fmask_apply_k<<<2 * KTOP, 320, 0, stream>>>(cxp, idxf, ftr, fti);
    conv_cxpT_k<<<640, 256, 0, stream>>>(cxp, cxpT);

    // inverse DFT (MFMA, batches merged in N): xtb[b] = ITwid @ cxp[b]^T^T
    gemm_mfma<6><<<160, 256, 0, stream>>>(itb, cxpT, nullptr, xtb, 1024, 640, 1056, 0, 10);
    // out_f = xt @ W_emb
    gemm_mfma<0><<<288, 256, 0, stream>>>(xtb, wemT, nullptr, out + OFF_OUTF, 2048, CC, 288, CC, 9);
}

// Round 12
// 214.167 us; speedup vs baseline: 1.1902x; 1.0596x over previous
//
#include <hip/hip_runtime.h>

#define TDIM 1024
#define DD   263
#define CC   526
#define NFREQ 513
#define PACK 1026
#define KTOP 102

// ---------------- ws layout (float offsets) ----------------
static const size_t WS_EX     = 0;          // 538624 f32
static const size_t WS_W1BF   = 538624;     // 320x288 bf16
static const size_t WS_W2BF   = 584704;
static const size_t WS_WEMT   = 630784;     // 576x288 bf16
static const size_t WS_MASKB  = 1615872;    // 2048x288 bf16
static const size_t WS_HBF    = 2154496;
static const size_t WS_PROJ   = 2693120;    // f32 2048x263
static const size_t WS_XTBF   = 3231744;    // 2048x288 bf16
static const size_t WS_CXP    = 3770368;    // f32 2*1026*263
static const size_t WS_EXTHL  = 4310044;    // [640][3072] bf16 = 983040 f
static const size_t WS_ITSEL  = 5360668;    // [2048][224] bf16 = 229376 f
static const size_t WS_DELTA  = 5901340;    // [640][224] bf16 = 71680 f
static const size_t WS_TABC   = 6411292;    // 1024
static const size_t WS_TABS   = 6412316;    // 1024
static const size_t WS_SCORE  = 6413340;    // double[2048]
static const size_t WS_MAGM   = 6417436;    // double[1026]
static const size_t WS_MASKT  = 6419488;    // int[2048]
static const size_t WS_IDXT   = 6421536;    // int[204]
static const size_t WS_IDXF   = 6421740;    // int[204]
static const size_t WS_MASKF  = 6421944;    // int[1026]
static const size_t WS_XHL    = 6422972;    // 2048x1632 bf16 = 1671168 f
static const size_t WS_THL    = 8094140;    // 1088x3072 bf16 = 1671168 f
static const size_t WS_WHL    = 9765308;    // 320x1632 bf16 = 261120 f
static const size_t WS_TOTAL  = 10740380;   // floats

static const size_t OFF_OUTT = 0;
static const size_t OFF_IDXT = 1077248;
static const size_t OFF_OUTF = 1077452;
static const size_t OFF_IDXF = 2154700;

typedef __bf16 bf16x8_t __attribute__((ext_vector_type(8)));
typedef float  f32x4_t  __attribute__((ext_vector_type(4)));

__device__ __forceinline__ unsigned short f2bf(float f) {
    unsigned int u = __float_as_uint(f);
    unsigned int r = (u + 0x7fffu + ((u >> 16) & 1u)) >> 16;
    return (unsigned short)r;
}
__device__ __forceinline__ float bf2f(unsigned short h) {
    return __uint_as_float(((unsigned int)h) << 16);
}

__device__ __forceinline__ float pe_val(int t, int d) {
    const float sc = (float)(-9.210340371976184 / 263.0);  // -ln(10000)/D
    int j = d >> 1;
    float div = expf((float)(2 * j) * sc);
    float a = (float)t * div;
    return (d & 1) ? cosf(a) : sinf(a);
}

// raw workgroup barrier: no implicit vmcnt(0) drain (prefetch stays in flight)
#define WG_FENCE()   asm volatile("" ::: "memory")
#define WG_BARRIER() { WG_FENCE(); __builtin_amdgcn_s_barrier(); WG_FENCE(); }

// ---------------- bf16 MFMA GEMM, reg-prefetch-queue + XCD swizzle ----------------
// C = A @ Bt^T. A [>=M x SA] bf16, Bt [64*gy x SA] bf16. Tile 64x64, 4 waves 2x2.
// Flat grid (gx*gy blocks), x-major XCD-bijective swizzle.
// EPI: 0 ->f32 [m*NC+n], n<N;  1 bias+gelu->bf16 pad to NC;  2 bias+sigmoid->f32;
//      4 bias+pe->f32 + exthl hi/lo/hi scatter (aux);  5 DFT scatter ->cxp f32;
//      7 corr: xtb = bf16(ex + v), ex via bias ptr, Bt batch-offset by row0>>10
template<int EPI>
__global__ __launch_bounds__(256) void gemm_mfma(const unsigned short* __restrict__ A,
                                                 const unsigned short* __restrict__ Bt,
                                                 const float* __restrict__ bias,
                                                 void* __restrict__ Cv,
                                                 void* __restrict__ aux,
                                                 int M, int N, int SA, int NC, int gy)
{
    __shared__ unsigned short As[64][40];
    __shared__ unsigned short Bs[64][40];
    // XCD-bijective chunked swizzle (m204): consecutive logical ids share A-panel
    const int nwg = gridDim.x;
    const int hw = blockIdx.x;
    const int q = nwg >> 3, r = nwg & 7, xcd = hw & 7;
    const int logical = (xcd < r ? xcd * (q + 1) : r * (q + 1) + (xcd - r) * q) + (hw >> 3);
    const int row0 = (logical / gy) * 64, col0 = (logical % gy) * 64;
    if (EPI == 7) Bt += (size_t)(row0 >> 10) * 320 * SA;   // per-batch delta panel

    const int tid  = threadIdx.x;
    const int wid = tid >> 6, lane = tid & 63;
    const int wr = wid >> 1, wc = wid & 1;
    const int srow = tid >> 2, skoff = (tid & 3) * 8;
    const int fl = lane & 15, fh = lane >> 4;
    f32x4_t acc[2][2];
#pragma unroll
    for (int i = 0; i < 2; i++)
#pragma unroll
        for (int j = 0; j < 2; j++) acc[i][j] = (f32x4_t){0.f, 0.f, 0.f, 0.f};

    const int nk = SA / 32;
    const unsigned short* pa = A  + (size_t)(row0 + srow) * SA + skoff;
    const unsigned short* pb = Bt + (size_t)(col0 + srow) * SA + skoff;

    bf16x8_t qa[4], qb[4];
#pragma unroll
    for (int j = 0; j < 4; ++j) {
        if (j < nk) {
            qa[j] = *(const bf16x8_t*)(pa + (size_t)j * 32);
            qb[j] = *(const bf16x8_t*)(pb + (size_t)j * 32);
        }
    }

    for (int itb = 0; itb < nk; itb += 4) {
#pragma unroll
        for (int j = 0; j < 4; ++j) {
            const int it = itb + j;
            if (it < nk) {
                if (it > 0) WG_BARRIER();            // all waves done reading LDS
                *(bf16x8_t*)(&As[srow][skoff]) = qa[j];   // compiler waits vmcnt for qa[j]
                *(bf16x8_t*)(&Bs[srow][skoff]) = qb[j];
                asm volatile("s_waitcnt lgkmcnt(0)" ::: "memory");
                WG_BARRIER();                         // all writes visible
                bf16x8_t fa0 = *(const bf16x8_t*)(&As[wr * 32 + fl][fh * 8]);
                bf16x8_t fa1 = *(const bf16x8_t*)(&As[wr * 32 + 16 + fl][fh * 8]);
                bf16x8_t fb0 = *(const bf16x8_t*)(&Bs[wc * 32 + fl][fh * 8]);
                bf16x8_t fb1 = *(const bf16x8_t*)(&Bs[wc * 32 + 16 + fl][fh * 8]);
                acc[0][0] = __builtin_amdgcn_mfma_f32_16x16x32_bf16(fa0, fb0, acc[0][0], 0, 0, 0);
                acc[0][1] = __builtin_amdgcn_mfma_f32_16x16x32_bf16(fa0, fb1, acc[0][1], 0, 0, 0);
                acc[1][0] = __builtin_amdgcn_mfma_f32_16x16x32_bf16(fa1, fb0, acc[1][0], 0, 0, 0);
                acc[1][1] = __builtin_amdgcn_mfma_f32_16x16x32_bf16(fa1, fb1, acc[1][1], 0, 0, 0);
                if (it + 4 < nk) {                    // refill queue slot j (stays in flight)
                    qa[j] = *(const bf16x8_t*)(pa + (size_t)(it + 4) * 32);
                    qb[j] = *(const bf16x8_t*)(pb + (size_t)(it + 4) * 32);
                }
            }
        }
    }

#pragma unroll
    for (int fi = 0; fi < 2; fi++)
#pragma unroll
        for (int fj = 0; fj < 2; fj++)
#pragma unroll
            for (int rr = 0; rr < 4; rr++) {
                int m = row0 + wr * 32 + fi * 16 + fh * 4 + rr;
                int n = col0 + wc * 32 + fj * 16 + fl;
                if (m >= M) continue;
                float v = acc[fi][fj][rr];
                if (EPI == 0) {
                    if (n < N) ((float*)Cv)[(size_t)m * NC + n] = v;
                } else if (EPI == 1) {
                    if (n < NC) {
                        float o = 0.0f;
                        if (n < N) { o = v + bias[n]; o = 0.5f * o * (1.0f + erff(o * 0.70710678118654752f)); }
                        ((unsigned short*)Cv)[(size_t)m * NC + n] = f2bf(o);
                    }
                } else if (EPI == 2) {
                    if (n < N) {
                        v += bias[n];
                        ((float*)Cv)[(size_t)m * NC + n] = 1.0f / (1.0f + expf(-v));
                    }
                } else if (EPI == 4) {
                    if (n < N) {
                        float o = v + bias[n] + pe_val(m & (TDIM - 1), n);
                        ((float*)Cv)[(size_t)m * NC + n] = o;
                        // fused exT hi/lo/hi scatter for the DFT B-operand
                        unsigned short hi = f2bf(o);
                        unsigned short lo = f2bf(o - bf2f(hi));
                        size_t b2 = ((size_t)(m >> 10) * 320 + n) * 3072 + (m & 1023);
                        unsigned short* xh = (unsigned short*)aux;
                        xh[b2] = hi; xh[b2 + 1024] = lo; xh[b2 + 2048] = hi;
                    }
                } else if (EPI == 5) {
                    int b = n / 320, col = n - b * 320;
                    if (col < DD) ((float*)Cv)[((size_t)b * PACK + m) * DD + col] = v;
                } else {  // EPI 7
                    if (n < 288) {
                        unsigned short o = 0;
                        if (n < DD) o = f2bf(bias[(size_t)m * DD + n] + v);
                        ((unsigned short*)Cv)[(size_t)m * 288 + n] = o;
                    }
                }
            }
}

// ---------------- glue kernels ----------------
__global__ void zero_masks_k(int* maskt, int* maskf) {
    int i = blockIdx.x * 256 + threadIdx.x;
    if (i < 2 * TDIM) maskt[i] = 0;
    if (i < PACK) maskf[i] = 0;
}

__global__ void tab_k(float* tabc, float* tabs) {
    int i = blockIdx.x * 256 + threadIdx.x;
    if (i >= 1024) return;
    double ang = (double)i * (3.14159265358979323846 * 2.0 / 1024.0);
    tabc[i] = (float)cos(ang);
    tabs[i] = (float)sin(ang);
}

// split-bf16 Twid: [1088 rows x 3072], A-packing segs {hi, hi, lo}
__global__ void twid_hl_fill_k(const float* __restrict__ tabc, const float* __restrict__ tabs,
                               unsigned short* __restrict__ thl) {
    int row = blockIdx.x;   // 0..1087
    unsigned short* dst = thl + (size_t)row * 3072;
    for (int c = threadIdx.x; c < 3072; c += 256) {
        int seg = c >> 10, t = c & 1023;
        float v = 0.0f;
        if (row < PACK) v = (row < NFREQ) ? tabc[(row * t) & 1023] : -tabs[((row - NFREQ) * t) & 1023];
        unsigned short hi = f2bf(v);
        dst[c] = (seg < 2) ? hi : f2bf(v - bf2f(hi));
    }
}

// x [2048x526] f32 -> xhl [2048x1632] bf16, A-packing segs {hi, hi, lo}
__global__ void conv_x_hl_k(const float* __restrict__ x, unsigned short* __restrict__ xhl) {
    int r = blockIdx.x;   // 0..2047
    const float* src = x + (size_t)r * CC;
    unsigned short* dst = xhl + (size_t)r * 1632;
    for (int c = threadIdx.x; c < 1632; c += 256) {
        int seg = c / 544, cc = c - seg * 544;
        float v = (cc < CC) ? src[cc] : 0.0f;
        unsigned short hi = f2bf(v);
        dst[c] = (seg < 2) ? hi : f2bf(v - bf2f(hi));
    }
}

// W_emb [263x526] f32 -> whl [320x1632] bf16, B-packing segs {hi, lo, hi}
__global__ void conv_w_hl_k(const float* __restrict__ W, unsigned short* __restrict__ whl) {
    int n = blockIdx.x;   // 0..319
    unsigned short* dst = whl + (size_t)n * 1632;
    for (int c = threadIdx.x; c < 1632; c += 256) {
        int seg = c / 544, cc = c - seg * 544;
        float v = (n < DD && cc < CC) ? W[(size_t)n * CC + cc] : 0.0f;
        unsigned short hi = f2bf(v);
        dst[c] = (seg == 1) ? f2bf(v - bf2f(hi)) : hi;
    }
}

// fused weight conversions (writes ALL pad zeros)
__global__ void conv_weights_k(const float* __restrict__ W1t, const float* __restrict__ W2t,
                               const float* __restrict__ W_emb,
                               unsigned short* __restrict__ w1b, unsigned short* __restrict__ w2b,
                               unsigned short* __restrict__ wemT) {
    int r = blockIdx.x;   // 0..1215
    if (r < 640) {
        int rr = r & 319;
        const float* src = (r < 320) ? W1t : W2t;
        unsigned short* dst = (r < 320) ? w1b : w2b;
        for (int c = threadIdx.x; c < 288; c += 256) {
            float v = (rr < DD && c < DD) ? src[(size_t)rr * DD + c] : 0.0f;
            dst[(size_t)rr * 288 + c] = f2bf(v);
        }
    } else {
        int rr = r - 640;  // 0..575
        for (int c = threadIdx.x; c < 288; c += 256) {
            float v = (rr < CC && c < DD) ? W_emb[(size_t)c * CC + rr] : 0.0f;
            wemT[(size_t)rr * 288 + c] = f2bf(v);
        }
    }
}

__global__ __launch_bounds__(64) void sliding_score_k(const float* __restrict__ ex,
                                                      double* __restrict__ score)
{
    const int ib = blockIdx.x;
    const int t = ib & (TDIM - 1);
    const int t0 = max(0, t - 24);
    const int nt = t - t0 + 1;
    const float cnt = (float)nt;
    const int lane = threadIdx.x;
    const float* base = ex + ((size_t)(ib - t) + t0) * DD;
    double ms = 0.0, vs = 0.0;
    for (int d = lane; d < DD; d += 64) {
        float s1 = 0.0f, s2 = 0.0f;
        for (int r = 0; r < nt; r++) {
            float v = base[(size_t)r * DD + d];
            s1 += v;
            s2 += v * v;
        }
        float m1 = s1 / cnt;
        float var = s2 / cnt - m1 * m1;
        ms += (double)m1;
        vs += (double)var;
    }
#pragma unroll
    for (int off = 32; off; off >>= 1) { ms += __shfl_xor(ms, off); vs += __shfl_xor(vs, off); }
    if (lane == 0) score[ib] = vs / (ms + (double)1e-6f);
}

__global__ __launch_bounds__(512) void topk_sort_k(const double* __restrict__ score,
                                                   int n, int kcount,
                                                   float* __restrict__ out_f,
                                                   int* __restrict__ out_i,
                                                   int* __restrict__ mask)
{
    __shared__ double sv[1024];
    __shared__ int    si[1024];
    const int b = blockIdx.x, tid = threadIdx.x;
    const double* s = score + (size_t)b * n;
    for (int i = tid; i < 1024; i += 512) {
        sv[i] = (i < n) ? s[i] : -1.0e300;
        si[i] = i;
    }
    __syncthreads();
    for (int k = 2; k <= 1024; k <<= 1) {
        for (int j = k >> 1; j > 0; j >>= 1) {
            for (int t = tid; t < 1024; t += 512) {
                int l = t ^ j;
                if (l > t) {
                    double v0 = sv[t], v1 = sv[l];
                    int i0 = si[t], i1 = si[l];
                    bool g = (v0 > v1) || (v0 == v1 && i0 < i1);
                    bool wrong = ((t & k) == 0) ? !g : g;
                    if (wrong) {
                        sv[t] = v1; sv[l] = v0;
                        si[t] = i1; si[l] = i0;
                    }
                }
            }
            __syncthreads();
        }
    }
    for (int t = tid; t < kcount; t += 512) {
        int bi = si[t];
        out_f[(size_t)b * kcount + t] = (float)bi;
        out_i[b * kcount + t] = bi;
        mask[b * n + bi] = 1;
    }
}

__global__ void build_masked_k(const float* __restrict__ ex, const float* __restrict__ ttok,
                               const int* __restrict__ maskt, unsigned short* __restrict__ mb) {
    int bt = blockIdx.x;
    int d = threadIdx.x;
    if (d >= 288) return;
    float v = 0.0f;
    if (d < DD) v = maskt[bt] ? ttok[d] : ex[(size_t)bt * DD + d];
    mb[(size_t)bt * 288 + d] = f2bf(v);
}

__global__ void select_k(const int* __restrict__ maskt, const float* __restrict__ proj,
                         unsigned short* __restrict__ mb) {
    int bt = blockIdx.x;
    int d = threadIdx.x;
    if (d >= DD) return;
    if (!maskt[bt]) mb[(size_t)bt * 288 + d] = f2bf(proj[(size_t)bt * DD + d]);
}

__global__ void mag_k(const float* __restrict__ cxp, double* __restrict__ magm) {
    int ib = blockIdx.x;
    int b = ib / NFREQ, k = ib % NFREQ;
    int lane = threadIdx.x;
    const float* re = cxp + ((size_t)b * PACK + k) * DD;
    const float* im = cxp + ((size_t)b * PACK + NFREQ + k) * DD;
    double acc = 0.0;
    for (int d = lane; d < DD; d += 64) {
        float r = re[d], i = im[d];
        acc += (double)sqrtf(r * r + i * i);
    }
#pragma unroll
    for (int off = 32; off; off >>= 1) acc += __shfl_xor(acc, off);
    if (lane == 0) magm[ib] = acc / (double)DD;
}

// builds IT_sel [2048][224] and delta [640][224] bf16 for the rank-102 correction
__global__ void sel_delta_k(const float* __restrict__ tabc, const float* __restrict__ tabs,
                            const int* __restrict__ idxf, const float* __restrict__ cxp,
                            const float* __restrict__ ftr, const float* __restrict__ fti,
                            unsigned short* __restrict__ itsel, unsigned short* __restrict__ delta) {
    int blk = blockIdx.x;
    if (blk < 2048) {
        int b = blk >> 10, t = blk & 1023;
        unsigned short* dst = itsel + (size_t)blk * 224;
        for (int j = threadIdx.x; j < 224; j += 256) {
            float v = 0.0f;
            if (j < KTOP) {
                int k = idxf[b * KTOP + j];
                float w = (k == 0 || k == 512) ? 1.0f : 2.0f;
                v = (w * (1.0f / 1024.0f)) * tabc[(k * t) & 1023];
            } else if (j >= 112 && j < 112 + KTOP) {
                int k = idxf[b * KTOP + j - 112];
                v = (k == 0 || k == 512) ? 0.0f : (-2.0f / 1024.0f) * tabs[(k * t) & 1023];
            }
            dst[j] = f2bf(v);
        }
    } else {
        int idx = blk - 2048;
        int b = idx / 320, d = idx - (idx / 320) * 320;
        unsigned short* dst = delta + (size_t)idx * 224;
        for (int j = threadIdx.x; j < 224; j += 256) {
            float v = 0.0f;
            if (d < DD) {
                if (j < KTOP) {
                    int k = idxf[b * KTOP + j];
                    v = ftr[d] - cxp[((size_t)b * PACK + k) * DD + d];
                } else if (j >= 112 && j < 112 + KTOP) {
                    int k = idxf[b * KTOP + j - 112];
                    v = fti[d] - cxp[((size_t)b * PACK + NFREQ + k) * DD + d];
                }
            }
            dst[j] = f2bf(v);
        }
    }
}

// ---------------- launch ----------------
extern "C" void kernel_launch(void* const* d_in, const int* in_sizes, int n_in,
                              void* d_out, int out_size, void* d_ws, size_t ws_size,
                              hipStream_t stream) {
    (void)in_sizes; (void)n_in; (void)out_size; (void)ws_size;
    const float* x      = (const float*)d_in[0];
    const float* W_emb  = (const float*)d_in[1];
    const float* b_emb  = (const float*)d_in[2];
    const float* ttok   = (const float*)d_in[3];
    const float* W1t    = (const float*)d_in[4];
    const float* b1t    = (const float*)d_in[5];
    const float* W2t    = (const float*)d_in[6];
    const float* b2t    = (const float*)d_in[7];
    const float* ftr    = (const float*)d_in[8];
    const float* fti    = (const float*)d_in[9];
    float* out = (float*)d_out;
    float* ws  = (float*)d_ws;

    float* ex     = ws + WS_EX;
    float* proj   = ws + WS_PROJ;
    float* cxp    = ws + WS_CXP;
    float* tabc   = ws + WS_TABC;
    float* tabs   = ws + WS_TABS;
    double* score = (double*)(ws + WS_SCORE);
    double* magm  = (double*)(ws + WS_MAGM);
    int* maskt    = (int*)(ws + WS_MASKT);
    int* idxt     = (int*)(ws + WS_IDXT);
    int* idxf     = (int*)(ws + WS_IDXF);
    int* maskf    = (int*)(ws + WS_MASKF);
    unsigned short* w1b   = (unsigned short*)(ws + WS_W1BF);
    unsigned short* w2b   = (unsigned short*)(ws + WS_W2BF);
    unsigned short* wemT  = (unsigned short*)(ws + WS_WEMT);
    unsigned short* maskb = (unsigned short*)(ws + WS_MASKB);
    unsigned short* hb    = (unsigned short*)(ws + WS_HBF);
    unsigned short* xtb   = (unsigned short*)(ws + WS_XTBF);
    unsigned short* itsel = (unsigned short*)(ws + WS_ITSEL);
    unsigned short* delta = (unsigned short*)(ws + WS_DELTA);
    unsigned short* xhl   = (unsigned short*)(ws + WS_XHL);
    unsigned short* thl   = (unsigned short*)(ws + WS_THL);
    unsigned short* whl   = (unsigned short*)(ws + WS_WHL);
    unsigned short* exthl = (unsigned short*)(ws + WS_EXTHL);

    // init + tables + operand conversions
    zero_masks_k<<<8, 256, 0, stream>>>(maskt, maskf);
    tab_k<<<4, 256, 0, stream>>>(tabc, tabs);
    twid_hl_fill_k<<<1088, 256, 0, stream>>>(tabc, tabs, thl);
    conv_weights_k<<<1216, 256, 0, stream>>>(W1t, W2t, W_emb, w1b, w2b, wemT);
    conv_x_hl_k<<<2048, 256, 0, stream>>>(x, xhl);
    conv_w_hl_k<<<320, 256, 0, stream>>>(W_emb, whl);

    // ex = x @ W_emb^T + b_emb + pe  (split-bf16 MFMA, K'=1632; fused exT-hl scatter)
    gemm_mfma<4><<<160, 256, 0, stream>>>(xhl, whl, b_emb, ex, exthl, 2048, DD, 1632, DD, 5);

    // temporal score -> topk
    sliding_score_k<<<2048, 64, 0, stream>>>(ex, score);
    topk_sort_k<<<2, 512, 0, stream>>>(score, TDIM, KTOP, out + OFF_IDXT, idxt, maskt);

    // masked -> h -> proj -> select -> out_t
    build_masked_k<<<2048, 320, 0, stream>>>(ex, ttok, maskt, maskb);
    gemm_mfma<1><<<160, 256, 0, stream>>>(maskb, w1b, b1t, hb, nullptr, 2048, DD, 288, 288, 5);
    gemm_mfma<2><<<160, 256, 0, stream>>>(hb, w2b, b2t, proj, nullptr, 2048, DD, 288, DD, 5);
    select_k<<<2048, 320, 0, stream>>>(maskt, proj, maskb);
    gemm_mfma<0><<<288, 256, 0, stream>>>(maskb, wemT, nullptr, out + OFF_OUTT, nullptr,
                                          2048, CC, 288, CC, 9);

    // forward DFT (split-bf16 MFMA, K'=3072, batches merged in N): cxp[b] = Twid @ ex[b]
    gemm_mfma<5><<<170, 256, 0, stream>>>(thl, exthl, nullptr, cxp, nullptr, PACK, 640, 3072, 0, 10);
    mag_k<<<2 * NFREQ, 64, 0, stream>>>(cxp, magm);
    topk_sort_k<<<2, 512, 0, stream>>>(magm, NFREQ, KTOP, out + OFF_IDXF, idxf, maskf);

    // rank-102 correction instead of full iDFT: xt = ex + IT_sel @ delta
    sel_delta_k<<<2688, 256, 0, stream>>>(tabc, tabs, idxf, cxp, ftr, fti, itsel, delta);
    gemm_mfma<7><<<160, 256, 0, stream>>>(itsel, delta, ex, xtb, nullptr, 2048, 320, 224, 288, 5);

    // out_f = xt @ W_emb
    gemm_mfma<0><<<288, 256, 0, stream>>>(xtb, wemT, nullptr, out + OFF_OUTF, nullptr,
                                          2048, CC, 288, CC, 9);
}

// Round 13
// 200.331 us; speedup vs baseline: 1.2724x; 1.0691x over previous
//
#include <hip/hip_runtime.h>

#define TDIM 1024
#define DD   263
#define CC   526
#define NFREQ 513
#define PACK 1026
#define KTOP 102

// ---------------- ws layout (float offsets) ----------------
static const size_t WS_EX     = 0;          // 538624 f32
static const size_t WS_W1BF   = 538624;     // 320x288 bf16
static const size_t WS_W2BF   = 584704;
static const size_t WS_WEMT   = 630784;     // 576x288 bf16 (ends 713728)
static const size_t WS_MASKB  = 1615872;    // 2048x288 bf16 = 294912 f
static const size_t WS_XTBF   = 1910784;    // 2048x288 bf16 (contiguous after MASKB)
static const size_t WS_HBF    = 2693120;    // 2048x288 bf16 (old proj slot)
static const size_t WS_CXP    = 3770368;    // f32 2*1026*263
static const size_t WS_EXTHL  = 4310044;    // [640][3072] bf16 = 983040 f
static const size_t WS_ITSEL  = 5360668;    // [2048][224] bf16 = 229376 f
static const size_t WS_DELTA  = 5901340;    // [640][224] bf16 = 71680 f
static const size_t WS_TABC   = 6411292;    // 1024
static const size_t WS_TABS   = 6412316;    // 1024
static const size_t WS_SCORE  = 6413340;    // double[2048]
static const size_t WS_MAGM   = 6417436;    // double[1026]
static const size_t WS_MASKT  = 6419488;    // int[2048]
static const size_t WS_IDXT   = 6421536;    // int[204]
static const size_t WS_IDXF   = 6421740;    // int[204]
static const size_t WS_MASKF  = 6421944;    // int[1026]
static const size_t WS_XHL    = 6422972;    // 2048x1632 bf16 = 1671168 f
static const size_t WS_THL    = 8094140;    // 1088x3072 bf16 = 1671168 f
static const size_t WS_WHL    = 9765308;    // 320x1632 bf16 = 261120 f
static const size_t WS_TOTAL  = 10740380;   // floats

static const size_t OFF_OUTT = 0;
static const size_t OFF_IDXT = 1077248;
static const size_t OFF_OUTF = 1077452;
static const size_t OFF_IDXF = 2154700;

typedef __bf16 bf16x8_t __attribute__((ext_vector_type(8)));
typedef float  f32x4_t  __attribute__((ext_vector_type(4)));

__device__ __forceinline__ unsigned short f2bf(float f) {
    unsigned int u = __float_as_uint(f);
    unsigned int r = (u + 0x7fffu + ((u >> 16) & 1u)) >> 16;
    return (unsigned short)r;
}
__device__ __forceinline__ float bf2f(unsigned short h) {
    return __uint_as_float(((unsigned int)h) << 16);
}

__device__ __forceinline__ float pe_val(int t, int d) {
    const float sc = (float)(-9.210340371976184 / 263.0);  // -ln(10000)/D
    int j = d >> 1;
    float div = expf((float)(2 * j) * sc);
    float a = (float)t * div;
    return (d & 1) ? cosf(a) : sinf(a);
}

// raw workgroup barrier: no implicit vmcnt(0) drain (prefetch stays in flight)
#define WG_FENCE()   asm volatile("" ::: "memory")
#define WG_BARRIER() { WG_FENCE(); __builtin_amdgcn_s_barrier(); WG_FENCE(); }

// ---------------- bf16 MFMA GEMM, reg-prefetch-queue + XCD swizzle ----------------
// C = A @ Bt^T. A [>=M x SA] bf16, Bt [64*gy x SA] bf16. Tile 64x64, 4 waves 2x2.
// Flat grid (gx*gy blocks), x-major XCD-bijective swizzle.
// EPI: 0 ->f32 [m*NC+n], n<N;  1 bias+gelu->bf16 pad to NC;
//      4 bias+pe->f32 + exthl hi/lo/hi scatter (aux);  5 DFT scatter ->cxp f32;
//      7 corr: xtb = bf16(ex + v), ex via bias ptr, Bt batch-offset by row0>>10;
//      8 sigmoid+select: write maskb rows where !maskt (aux=maskt);
//      9 dual-out: m<2048 -> out_t else out_f
template<int EPI>
__global__ __launch_bounds__(256) void gemm_mfma(const unsigned short* __restrict__ A,
                                                 const unsigned short* __restrict__ Bt,
                                                 const float* __restrict__ bias,
                                                 void* __restrict__ Cv,
                                                 void* __restrict__ aux,
                                                 int M, int N, int SA, int NC, int gy)
{
    __shared__ unsigned short As[64][40];
    __shared__ unsigned short Bs[64][40];
    // XCD-bijective chunked swizzle (m204): consecutive logical ids share A-panel
    const int nwg = gridDim.x;
    const int hw = blockIdx.x;
    const int q = nwg >> 3, r = nwg & 7, xcd = hw & 7;
    const int logical = (xcd < r ? xcd * (q + 1) : r * (q + 1) + (xcd - r) * q) + (hw >> 3);
    const int row0 = (logical / gy) * 64, col0 = (logical % gy) * 64;
    if (EPI == 7) Bt += (size_t)(row0 >> 10) * 320 * SA;   // per-batch delta panel

    const int tid  = threadIdx.x;
    const int wid = tid >> 6, lane = tid & 63;
    const int wr = wid >> 1, wc = wid & 1;
    const int srow = tid >> 2, skoff = (tid & 3) * 8;
    const int fl = lane & 15, fh = lane >> 4;
    f32x4_t acc[2][2];
#pragma unroll
    for (int i = 0; i < 2; i++)
#pragma unroll
        for (int j = 0; j < 2; j++) acc[i][j] = (f32x4_t){0.f, 0.f, 0.f, 0.f};

    const int nk = SA / 32;
    const unsigned short* pa = A  + (size_t)(row0 + srow) * SA + skoff;
    const unsigned short* pb = Bt + (size_t)(col0 + srow) * SA + skoff;

    bf16x8_t qa[4], qb[4];
#pragma unroll
    for (int j = 0; j < 4; ++j) {
        if (j < nk) {
            qa[j] = *(const bf16x8_t*)(pa + (size_t)j * 32);
            qb[j] = *(const bf16x8_t*)(pb + (size_t)j * 32);
        }
    }

    for (int itb = 0; itb < nk; itb += 4) {
#pragma unroll
        for (int j = 0; j < 4; ++j) {
            const int it = itb + j;
            if (it < nk) {
                if (it > 0) WG_BARRIER();            // all waves done reading LDS
                *(bf16x8_t*)(&As[srow][skoff]) = qa[j];   // compiler waits vmcnt for qa[j]
                *(bf16x8_t*)(&Bs[srow][skoff]) = qb[j];
                asm volatile("s_waitcnt lgkmcnt(0)" ::: "memory");
                WG_BARRIER();                         // all writes visible
                bf16x8_t fa0 = *(const bf16x8_t*)(&As[wr * 32 + fl][fh * 8]);
                bf16x8_t fa1 = *(const bf16x8_t*)(&As[wr * 32 + 16 + fl][fh * 8]);
                bf16x8_t fb0 = *(const bf16x8_t*)(&Bs[wc * 32 + fl][fh * 8]);
                bf16x8_t fb1 = *(const bf16x8_t*)(&Bs[wc * 32 + 16 + fl][fh * 8]);
                acc[0][0] = __builtin_amdgcn_mfma_f32_16x16x32_bf16(fa0, fb0, acc[0][0], 0, 0, 0);
                acc[0][1] = __builtin_amdgcn_mfma_f32_16x16x32_bf16(fa0, fb1, acc[0][1], 0, 0, 0);
                acc[1][0] = __builtin_amdgcn_mfma_f32_16x16x32_bf16(fa1, fb0, acc[1][0], 0, 0, 0);
                acc[1][1] = __builtin_amdgcn_mfma_f32_16x16x32_bf16(fa1, fb1, acc[1][1], 0, 0, 0);
                if (it + 4 < nk) {                    // refill queue slot j (stays in flight)
                    qa[j] = *(const bf16x8_t*)(pa + (size_t)(it + 4) * 32);
                    qb[j] = *(const bf16x8_t*)(pb + (size_t)(it + 4) * 32);
                }
            }
        }
    }

#pragma unroll
    for (int fi = 0; fi < 2; fi++)
#pragma unroll
        for (int fj = 0; fj < 2; fj++)
#pragma unroll
            for (int rr = 0; rr < 4; rr++) {
                int m = row0 + wr * 32 + fi * 16 + fh * 4 + rr;
                int n = col0 + wc * 32 + fj * 16 + fl;
                if (m >= M) continue;
                float v = acc[fi][fj][rr];
                if (EPI == 0) {
                    if (n < N) ((float*)Cv)[(size_t)m * NC + n] = v;
                } else if (EPI == 1) {
                    if (n < NC) {
                        float o = 0.0f;
                        if (n < N) { o = v + bias[n]; o = 0.5f * o * (1.0f + erff(o * 0.70710678118654752f)); }
                        ((unsigned short*)Cv)[(size_t)m * NC + n] = f2bf(o);
                    }
                } else if (EPI == 4) {
                    if (n < N) {
                        float o = v + bias[n] + pe_val(m & (TDIM - 1), n);
                        ((float*)Cv)[(size_t)m * NC + n] = o;
                        // fused exT hi/lo/hi scatter for the DFT B-operand
                        unsigned short hi = f2bf(o);
                        unsigned short lo = f2bf(o - bf2f(hi));
                        size_t b2 = ((size_t)(m >> 10) * 320 + n) * 3072 + (m & 1023);
                        unsigned short* xh = (unsigned short*)aux;
                        xh[b2] = hi; xh[b2 + 1024] = lo; xh[b2 + 2048] = hi;
                    }
                } else if (EPI == 5) {
                    int b = n / 320, col = n - b * 320;
                    if (col < DD) ((float*)Cv)[((size_t)b * PACK + m) * DD + col] = v;
                } else if (EPI == 7) {
                    if (n < 288) {
                        unsigned short o = 0;
                        if (n < DD) o = f2bf(bias[(size_t)m * DD + n] + v);
                        ((unsigned short*)Cv)[(size_t)m * 288 + n] = o;
                    }
                } else if (EPI == 8) {
                    const int* mt = (const int*)aux;
                    if (n < 288 && !mt[m]) {
                        unsigned short o = 0;
                        if (n < DD) {
                            float s = v + bias[n];
                            o = f2bf(1.0f / (1.0f + expf(-s)));
                        }
                        ((unsigned short*)Cv)[(size_t)m * 288 + n] = o;
                    }
                } else {  // EPI 9: dual output
                    if (n < CC) {
                        size_t off = (m < 2048) ? (size_t)m * CC + n
                                                : (size_t)OFF_OUTF + (size_t)(m - 2048) * CC + n;
                        ((float*)Cv)[off] = v;
                    }
                }
            }
}

// ---------------- fused init: masks + sincos tables ----------------
__global__ void init0_k(int* maskt, int* maskf, float* tabc, float* tabs) {
    int i = blockIdx.x * 256 + threadIdx.x;
    if (i < 2 * TDIM) maskt[i] = 0;
    if (i < PACK) maskf[i] = 0;
    if (i < 1024) {
        double ang = (double)i * (3.14159265358979323846 * 2.0 / 1024.0);
        tabc[i] = (float)cos(ang);
        tabs[i] = (float)sin(ang);
    }
}

// ---------------- fused conversions: twid_hl + weights + x_hl + w_hl ----------------
__global__ void convall_k(const float* __restrict__ tabc, const float* __restrict__ tabs,
                          const float* __restrict__ W1t, const float* __restrict__ W2t,
                          const float* __restrict__ W_emb, const float* __restrict__ x,
                          unsigned short* __restrict__ thl,
                          unsigned short* __restrict__ w1b, unsigned short* __restrict__ w2b,
                          unsigned short* __restrict__ wemT,
                          unsigned short* __restrict__ xhl, unsigned short* __restrict__ whl)
{
    int blk = blockIdx.x;
    if (blk < 1088) {
        // split-bf16 Twid row: [1088][3072], A-packing segs {hi, hi, lo}
        int row = blk;
        unsigned short* dst = thl + (size_t)row * 3072;
        for (int c = threadIdx.x; c < 3072; c += 256) {
            int seg = c >> 10, t = c & 1023;
            float v = 0.0f;
            if (row < PACK) v = (row < NFREQ) ? tabc[(row * t) & 1023] : -tabs[((row - NFREQ) * t) & 1023];
            unsigned short hi = f2bf(v);
            dst[c] = (seg < 2) ? hi : f2bf(v - bf2f(hi));
        }
    } else if (blk < 2304) {
        // weight conversions (writes ALL pad zeros)
        int r = blk - 1088;
        if (r < 640) {
            int rr = r & 319;
            const float* src = (r < 320) ? W1t : W2t;
            unsigned short* dst = (r < 320) ? w1b : w2b;
            for (int c = threadIdx.x; c < 288; c += 256) {
                float v = (rr < DD && c < DD) ? src[(size_t)rr * DD + c] : 0.0f;
                dst[(size_t)rr * 288 + c] = f2bf(v);
            }
        } else {
            int rr = r - 640;  // 0..575
            for (int c = threadIdx.x; c < 288; c += 256) {
                float v = (rr < CC && c < DD) ? W_emb[(size_t)c * CC + rr] : 0.0f;
                wemT[(size_t)rr * 288 + c] = f2bf(v);
            }
        }
    } else if (blk < 4352) {
        // x row -> xhl [2048][1632], A-packing segs {hi, hi, lo}
        int r = blk - 2304;
        const float* src = x + (size_t)r * CC;
        unsigned short* dst = xhl + (size_t)r * 1632;
        for (int c = threadIdx.x; c < 1632; c += 256) {
            int seg = c / 544, cc = c - seg * 544;
            float v = (cc < CC) ? src[cc] : 0.0f;
            unsigned short hi = f2bf(v);
            dst[c] = (seg < 2) ? hi : f2bf(v - bf2f(hi));
        }
    } else {
        // W_emb col -> whl [320][1632], B-packing segs {hi, lo, hi}
        int n = blk - 4352;
        unsigned short* dst = whl + (size_t)n * 1632;
        for (int c = threadIdx.x; c < 1632; c += 256) {
            int seg = c / 544, cc = c - seg * 544;
            float v = (n < DD && cc < CC) ? W_emb[(size_t)n * CC + cc] : 0.0f;
            unsigned short hi = f2bf(v);
            dst[c] = (seg == 1) ? f2bf(v - bf2f(hi)) : hi;
        }
    }
}

__global__ __launch_bounds__(64) void sliding_score_k(const float* __restrict__ ex,
                                                      double* __restrict__ score)
{
    const int ib = blockIdx.x;
    const int t = ib & (TDIM - 1);
    const int t0 = max(0, t - 24);
    const int nt = t - t0 + 1;
    const float cnt = (float)nt;
    const int lane = threadIdx.x;
    const float* base = ex + ((size_t)(ib - t) + t0) * DD;
    double ms = 0.0, vs = 0.0;
    for (int d = lane; d < DD; d += 64) {
        float s1 = 0.0f, s2 = 0.0f;
        for (int r = 0; r < nt; r++) {
            float v = base[(size_t)r * DD + d];
            s1 += v;
            s2 += v * v;
        }
        float m1 = s1 / cnt;
        float var = s2 / cnt - m1 * m1;
        ms += (double)m1;
        vs += (double)var;
    }
#pragma unroll
    for (int off = 32; off; off >>= 1) { ms += __shfl_xor(ms, off); vs += __shfl_xor(vs, off); }
    if (lane == 0) score[ib] = vs / (ms + (double)1e-6f);
}

__global__ __launch_bounds__(512) void topk_sort_k(const double* __restrict__ score,
                                                   int n, int kcount,
                                                   float* __restrict__ out_f,
                                                   int* __restrict__ out_i,
                                                   int* __restrict__ mask)
{
    __shared__ double sv[1024];
    __shared__ int    si[1024];
    const int b = blockIdx.x, tid = threadIdx.x;
    const double* s = score + (size_t)b * n;
    for (int i = tid; i < 1024; i += 512) {
        sv[i] = (i < n) ? s[i] : -1.0e300;
        si[i] = i;
    }
    __syncthreads();
    for (int k = 2; k <= 1024; k <<= 1) {
        for (int j = k >> 1; j > 0; j >>= 1) {
            for (int t = tid; t < 1024; t += 512) {
                int l = t ^ j;
                if (l > t) {
                    double v0 = sv[t], v1 = sv[l];
                    int i0 = si[t], i1 = si[l];
                    bool g = (v0 > v1) || (v0 == v1 && i0 < i1);
                    bool wrong = ((t & k) == 0) ? !g : g;
                    if (wrong) {
                        sv[t] = v1; sv[l] = v0;
                        si[t] = i1; si[l] = i0;
                    }
                }
            }
            __syncthreads();
        }
    }
    for (int t = tid; t < kcount; t += 512) {
        int bi = si[t];
        out_f[(size_t)b * kcount + t] = (float)bi;
        out_i[b * kcount + t] = bi;
        mask[b * n + bi] = 1;
    }
}

__global__ void build_masked_k(const float* __restrict__ ex, const float* __restrict__ ttok,
                               const int* __restrict__ maskt, unsigned short* __restrict__ mb) {
    int bt = blockIdx.x;
    int d = threadIdx.x;
    if (d >= 288) return;
    float v = 0.0f;
    if (d < DD) v = maskt[bt] ? ttok[d] : ex[(size_t)bt * DD + d];
    mb[(size_t)bt * 288 + d] = f2bf(v);
}

__global__ void mag_k(const float* __restrict__ cxp, double* __restrict__ magm) {
    int ib = blockIdx.x;
    int b = ib / NFREQ, k = ib % NFREQ;
    int lane = threadIdx.x;
    const float* re = cxp + ((size_t)b * PACK + k) * DD;
    const float* im = cxp + ((size_t)b * PACK + NFREQ + k) * DD;
    double acc = 0.0;
    for (int d = lane; d < DD; d += 64) {
        float r = re[d], i = im[d];
        acc += (double)sqrtf(r * r + i * i);
    }
#pragma unroll
    for (int off = 32; off; off >>= 1) acc += __shfl_xor(acc, off);
    if (lane == 0) magm[ib] = acc / (double)DD;
}

// builds IT_sel [2048][224] and delta [640][224] bf16 for the rank-102 correction
__global__ void sel_delta_k(const float* __restrict__ tabc, const float* __restrict__ tabs,
                            const int* __restrict__ idxf, const float* __restrict__ cxp,
                            const float* __restrict__ ftr, const float* __restrict__ fti,
                            unsigned short* __restrict__ itsel, unsigned short* __restrict__ delta) {
    int blk = blockIdx.x;
    if (blk < 2048) {
        int b = blk >> 10, t = blk & 1023;
        unsigned short* dst = itsel + (size_t)blk * 224;
        for (int j = threadIdx.x; j < 224; j += 256) {
            float v = 0.0f;
            if (j < KTOP) {
                int k = idxf[b * KTOP + j];
                float w = (k == 0 || k == 512) ? 1.0f : 2.0f;
                v = (w * (1.0f / 1024.0f)) * tabc[(k * t) & 1023];
            } else if (j >= 112 && j < 112 + KTOP) {
                int k = idxf[b * KTOP + j - 112];
                v = (k == 0 || k == 512) ? 0.0f : (-2.0f / 1024.0f) * tabs[(k * t) & 1023];
            }
            dst[j] = f2bf(v);
        }
    } else {
        int idx = blk - 2048;
        int b = idx / 320, d = idx - (idx / 320) * 320;
        unsigned short* dst = delta + (size_t)idx * 224;
        for (int j = threadIdx.x; j < 224; j += 256) {
            float v = 0.0f;
            if (d < DD) {
                if (j < KTOP) {
                    int k = idxf[b * KTOP + j];
                    v = ftr[d] - cxp[((size_t)b * PACK + k) * DD + d];
                } else if (j >= 112 && j < 112 + KTOP) {
                    int k = idxf[b * KTOP + j - 112];
                    v = fti[d] - cxp[((size_t)b * PACK + NFREQ + k) * DD + d];
                }
            }
            dst[j] = f2bf(v);
        }
    }
}

// ---------------- launch ----------------
extern "C" void kernel_launch(void* const* d_in, const int* in_sizes, int n_in,
                              void* d_out, int out_size, void* d_ws, size_t ws_size,
                              hipStream_t stream) {
    (void)in_sizes; (void)n_in; (void)out_size; (void)ws_size;
    const float* x      = (const float*)d_in[0];
    const float* W_emb  = (const float*)d_in[1];
    const float* b_emb  = (const float*)d_in[2];
    const float* ttok   = (const float*)d_in[3];
    const float* W1t    = (const float*)d_in[4];
    const float* b1t    = (const float*)d_in[5];
    const float* W2t    = (const float*)d_in[6];
    const float* b2t    = (const float*)d_in[7];
    const float* ftr    = (const float*)d_in[8];
    const float* fti    = (const float*)d_in[9];
    float* out = (float*)d_out;
    float* ws  = (float*)d_ws;

    float* ex     = ws + WS_EX;
    float* cxp    = ws + WS_CXP;
    float* tabc   = ws + WS_TABC;
    float* tabs   = ws + WS_TABS;
    double* score = (double*)(ws + WS_SCORE);
    double* magm  = (double*)(ws + WS_MAGM);
    int* maskt    = (int*)(ws + WS_MASKT);
    int* idxt     = (int*)(ws + WS_IDXT);
    int* idxf     = (int*)(ws + WS_IDXF);
    int* maskf    = (int*)(ws + WS_MASKF);
    unsigned short* w1b   = (unsigned short*)(ws + WS_W1BF);
    unsigned short* w2b   = (unsigned short*)(ws + WS_W2BF);
    unsigned short* wemT  = (unsigned short*)(ws + WS_WEMT);
    unsigned short* maskb = (unsigned short*)(ws + WS_MASKB);
    unsigned short* hb    = (unsigned short*)(ws + WS_HBF);
    unsigned short* xtb   = (unsigned short*)(ws + WS_XTBF);
    unsigned short* itsel = (unsigned short*)(ws + WS_ITSEL);
    unsigned short* delta = (unsigned short*)(ws + WS_DELTA);
    unsigned short* xhl   = (unsigned short*)(ws + WS_XHL);
    unsigned short* thl   = (unsigned short*)(ws + WS_THL);
    unsigned short* whl   = (unsigned short*)(ws + WS_WHL);
    unsigned short* exthl = (unsigned short*)(ws + WS_EXTHL);

    // fused init + fused conversions
    init0_k<<<8, 256, 0, stream>>>(maskt, maskf, tabc, tabs);
    convall_k<<<4672, 256, 0, stream>>>(tabc, tabs, W1t, W2t, W_emb, x,
                                        thl, w1b, w2b, wemT, xhl, whl);

    // ex = x @ W_emb^T + b_emb + pe  (split-bf16 MFMA, K'=1632; fused exT-hl scatter)
    gemm_mfma<4><<<160, 256, 0, stream>>>(xhl, whl, b_emb, ex, exthl, 2048, DD, 1632, DD, 5);

    // temporal score -> topk
    sliding_score_k<<<2048, 64, 0, stream>>>(ex, score);
    topk_sort_k<<<2, 512, 0, stream>>>(score, TDIM, KTOP, out + OFF_IDXT, idxt, maskt);

    // masked -> h -> (sigmoid+select into maskb)
    build_masked_k<<<2048, 320, 0, stream>>>(ex, ttok, maskt, maskb);
    gemm_mfma<1><<<160, 256, 0, stream>>>(maskb, w1b, b1t, hb, nullptr, 2048, DD, 288, 288, 5);
    gemm_mfma<8><<<160, 256, 0, stream>>>(hb, w2b, b2t, maskb, maskt, 2048, DD, 288, 288, 5);

    // forward DFT (split-bf16 MFMA, K'=3072, batches merged in N): cxp[b] = Twid @ ex[b]
    gemm_mfma<5><<<170, 256, 0, stream>>>(thl, exthl, nullptr, cxp, nullptr, PACK, 640, 3072, 0, 10);
    mag_k<<<2 * NFREQ, 64, 0, stream>>>(cxp, magm);
    topk_sort_k<<<2, 512, 0, stream>>>(magm, NFREQ, KTOP, out + OFF_IDXF, idxf, maskf);

    // rank-102 correction instead of full iDFT: xt = ex + IT_sel @ delta
    sel_delta_k<<<2688, 256, 0, stream>>>(tabc, tabs, idxf, cxp, ftr, fti, itsel, delta);
    gemm_mfma<7><<<160, 256, 0, stream>>>(itsel, delta, ex, xtb, nullptr, 2048, 320, 224, 288, 5);

    // merged out_t / out_f:  [maskb ; xtb] (contiguous 4096x288) @ wemT
    gemm_mfma<9><<<576, 256, 0, stream>>>(maskb, wemT, nullptr, out, nullptr, 4096, CC, 288, CC, 9);
}

// Round 14
// 162.230 us; speedup vs baseline: 1.5713x; 1.2349x over previous
//
#include <hip/hip_runtime.h>

#define TDIM 1024
#define DD   263
#define CC   526
#define NFREQ 513
#define PACK 1026
#define KTOP 102

// ---------------- ws layout (float offsets) ----------------
static const size_t WS_EX     = 0;          // 538624 f32
static const size_t WS_W1BF   = 538624;     // 320x288 bf16
static const size_t WS_W2BF   = 584704;
static const size_t WS_WEMT   = 630784;     // 576x288 bf16 (ends 713728)
static const size_t WS_MASKB  = 1615872;    // 2048x288 bf16 = 294912 f
static const size_t WS_XTBF   = 1910784;    // 2048x288 bf16 (contiguous after MASKB)
static const size_t WS_HBF    = 2693120;    // 2048x288 bf16
static const size_t WS_CXP    = 3770368;    // f32 2*1026*263
static const size_t WS_EXTHL  = 4310044;    // [640][3072] bf16 = 983040 f
static const size_t WS_ITSEL  = 5360668;    // [2048][224] bf16 = 229376 f
static const size_t WS_DELTA  = 5901340;    // [640][224] bf16 = 71680 f
static const size_t WS_TABC   = 6411292;    // 1024
static const size_t WS_TABS   = 6412316;    // 1024
static const size_t WS_SCORE  = 6413340;    // double[2048]
static const size_t WS_MAGM   = 6417436;    // double[1026]
static const size_t WS_MASKT  = 6419488;    // int[2048]
static const size_t WS_IDXT   = 6421536;    // int[204]
static const size_t WS_IDXF   = 6421740;    // int[204]
static const size_t WS_MASKF  = 6421944;    // int[1026]
static const size_t WS_XHL    = 6422972;    // 2048x1632 bf16 = 1671168 f
static const size_t WS_THL    = 8094140;    // 1088x3072 bf16 = 1671168 f
static const size_t WS_WHL    = 9765308;    // 320x1632 bf16 = 261120 f
static const size_t WS_TOTAL  = 10740380;   // floats

static const size_t OFF_OUTT = 0;
static const size_t OFF_IDXT = 1077248;
static const size_t OFF_OUTF = 1077452;
static const size_t OFF_IDXF = 2154700;

typedef __bf16 bf16x8_t __attribute__((ext_vector_type(8)));
typedef float  f32x4_t  __attribute__((ext_vector_type(4)));

__device__ __forceinline__ unsigned short f2bf(float f) {
    unsigned int u = __float_as_uint(f);
    unsigned int r = (u + 0x7fffu + ((u >> 16) & 1u)) >> 16;
    return (unsigned short)r;
}
__device__ __forceinline__ float bf2f(unsigned short h) {
    return __uint_as_float(((unsigned int)h) << 16);
}

__device__ __forceinline__ float pe_val(int t, int d) {
    const float sc = (float)(-9.210340371976184 / 263.0);  // -ln(10000)/D
    int j = d >> 1;
    float div = expf((float)(2 * j) * sc);
    float a = (float)t * div;
    return (d & 1) ? cosf(a) : sinf(a);
}

// raw workgroup barrier: no implicit vmcnt(0) drain (prefetch stays in flight)
#define WG_FENCE()   asm volatile("" ::: "memory")
#define WG_BARRIER() { WG_FENCE(); __builtin_amdgcn_s_barrier(); WG_FENCE(); }

// ---------------- bf16 MFMA GEMM, reg-prefetch-queue + XCD swizzle ----------------
// C = A @ Bt^T. A [>=M x SA] bf16, Bt [64*gy x SA] bf16. Tile 64x64, 4 waves 2x2.
// KU: K-elems staged per iteration = 32*KU (SA must divide).
// EPI: 0 ->f32 [m*NC+n], n<N;  1 bias+gelu->bf16 pad to NC;
//      4 bias+pe->f32 + exthl hi/lo/hi scatter (aux);  5 DFT scatter ->cxp f32;
//      7 corr: xtb = bf16(ex + v);  8 sigmoid+select (aux=maskt);
//      9 dual-out: m<2048 -> out_t else out_f
template<int EPI, int KU>
__global__ __launch_bounds__(256) void gemm_mfma(const unsigned short* __restrict__ A,
                                                 const unsigned short* __restrict__ Bt,
                                                 const float* __restrict__ bias,
                                                 void* __restrict__ Cv,
                                                 void* __restrict__ aux,
                                                 int M, int N, int SA, int NC, int gy)
{
    __shared__ unsigned short As[64][32 * KU + 8];
    __shared__ unsigned short Bs[64][32 * KU + 8];
    // XCD-bijective chunked swizzle (m204)
    const int nwg = gridDim.x;
    const int hw = blockIdx.x;
    const int q = nwg >> 3, r = nwg & 7, xcd = hw & 7;
    const int logical = (xcd < r ? xcd * (q + 1) : r * (q + 1) + (xcd - r) * q) + (hw >> 3);
    const int row0 = (logical / gy) * 64, col0 = (logical % gy) * 64;
    if (EPI == 7) Bt += (size_t)(row0 >> 10) * 320 * SA;   // per-batch delta panel

    const int tid  = threadIdx.x;
    const int wid = tid >> 6, lane = tid & 63;
    const int wr = wid >> 1, wc = wid & 1;
    const int srow = tid >> 2, skoff = (tid & 3) * 8;
    const int fl = lane & 15, fh = lane >> 4;
    f32x4_t acc[2][2];
#pragma unroll
    for (int i = 0; i < 2; i++)
#pragma unroll
        for (int j = 0; j < 2; j++) acc[i][j] = (f32x4_t){0.f, 0.f, 0.f, 0.f};

    const int nk = SA / (32 * KU);
    const unsigned short* pa = A  + (size_t)(row0 + srow) * SA + skoff;
    const unsigned short* pb = Bt + (size_t)(col0 + srow) * SA + skoff;

    bf16x8_t qa[4][KU], qb[4][KU];
#pragma unroll
    for (int j = 0; j < 4; ++j) {
        if (j < nk) {
#pragma unroll
            for (int u = 0; u < KU; ++u) {
                qa[j][u] = *(const bf16x8_t*)(pa + (size_t)j * (32 * KU) + u * 32);
                qb[j][u] = *(const bf16x8_t*)(pb + (size_t)j * (32 * KU) + u * 32);
            }
        }
    }

    for (int itb = 0; itb < nk; itb += 4) {
#pragma unroll
        for (int j = 0; j < 4; ++j) {
            const int it = itb + j;
            if (it < nk) {
                if (it > 0) WG_BARRIER();            // all waves done reading LDS
#pragma unroll
                for (int u = 0; u < KU; ++u) {
                    *(bf16x8_t*)(&As[srow][u * 32 + skoff]) = qa[j][u];
                    *(bf16x8_t*)(&Bs[srow][u * 32 + skoff]) = qb[j][u];
                }
                asm volatile("s_waitcnt lgkmcnt(0)" ::: "memory");
                WG_BARRIER();                         // all writes visible
#pragma unroll
                for (int u = 0; u < KU; ++u) {
                    bf16x8_t fa0 = *(const bf16x8_t*)(&As[wr * 32 + fl][u * 32 + fh * 8]);
                    bf16x8_t fa1 = *(const bf16x8_t*)(&As[wr * 32 + 16 + fl][u * 32 + fh * 8]);
                    bf16x8_t fb0 = *(const bf16x8_t*)(&Bs[wc * 32 + fl][u * 32 + fh * 8]);
                    bf16x8_t fb1 = *(const bf16x8_t*)(&Bs[wc * 32 + 16 + fl][u * 32 + fh * 8]);
                    acc[0][0] = __builtin_amdgcn_mfma_f32_16x16x32_bf16(fa0, fb0, acc[0][0], 0, 0, 0);
                    acc[0][1] = __builtin_amdgcn_mfma_f32_16x16x32_bf16(fa0, fb1, acc[0][1], 0, 0, 0);
                    acc[1][0] = __builtin_amdgcn_mfma_f32_16x16x32_bf16(fa1, fb0, acc[1][0], 0, 0, 0);
                    acc[1][1] = __builtin_amdgcn_mfma_f32_16x16x32_bf16(fa1, fb1, acc[1][1], 0, 0, 0);
                }
                if (it + 4 < nk) {                    // refill queue slot j (stays in flight)
#pragma unroll
                    for (int u = 0; u < KU; ++u) {
                        qa[j][u] = *(const bf16x8_t*)(pa + (size_t)(it + 4) * (32 * KU) + u * 32);
                        qb[j][u] = *(const bf16x8_t*)(pb + (size_t)(it + 4) * (32 * KU) + u * 32);
                    }
                }
            }
        }
    }

#pragma unroll
    for (int fi = 0; fi < 2; fi++)
#pragma unroll
        for (int fj = 0; fj < 2; fj++)
#pragma unroll
            for (int rr = 0; rr < 4; rr++) {
                int m = row0 + wr * 32 + fi * 16 + fh * 4 + rr;
                int n = col0 + wc * 32 + fj * 16 + fl;
                if (m >= M) continue;
                float v = acc[fi][fj][rr];
                if (EPI == 0) {
                    if (n < N) ((float*)Cv)[(size_t)m * NC + n] = v;
                } else if (EPI == 1) {
                    if (n < NC) {
                        float o = 0.0f;
                        if (n < N) { o = v + bias[n]; o = 0.5f * o * (1.0f + erff(o * 0.70710678118654752f)); }
                        ((unsigned short*)Cv)[(size_t)m * NC + n] = f2bf(o);
                    }
                } else if (EPI == 4) {
                    if (n < N) {
                        float o = v + bias[n] + pe_val(m & (TDIM - 1), n);
                        ((float*)Cv)[(size_t)m * NC + n] = o;
                        unsigned short hi = f2bf(o);
                        unsigned short lo = f2bf(o - bf2f(hi));
                        size_t b2 = ((size_t)(m >> 10) * 320 + n) * 3072 + (m & 1023);
                        unsigned short* xh = (unsigned short*)aux;
                        xh[b2] = hi; xh[b2 + 1024] = lo; xh[b2 + 2048] = hi;
                    }
                } else if (EPI == 5) {
                    int b = n / 320, col = n - b * 320;
                    if (col < DD) ((float*)Cv)[((size_t)b * PACK + m) * DD + col] = v;
                } else if (EPI == 7) {
                    if (n < 288) {
                        unsigned short o = 0;
                        if (n < DD) o = f2bf(bias[(size_t)m * DD + n] + v);
                        ((unsigned short*)Cv)[(size_t)m * 288 + n] = o;
                    }
                } else if (EPI == 8) {
                    const int* mt = (const int*)aux;
                    if (n < 288 && !mt[m]) {
                        unsigned short o = 0;
                        if (n < DD) {
                            float s = v + bias[n];
                            o = f2bf(1.0f / (1.0f + expf(-s)));
                        }
                        ((unsigned short*)Cv)[(size_t)m * 288 + n] = o;
                    }
                } else {  // EPI 9: dual output
                    if (n < CC) {
                        size_t off = (m < 2048) ? (size_t)m * CC + n
                                                : (size_t)OFF_OUTF + (size_t)(m - 2048) * CC + n;
                        ((float*)Cv)[off] = v;
                    }
                }
            }
}

// ---------------- fused init: masks + sincos tables ----------------
__global__ void init0_k(int* maskt, int* maskf, float* tabc, float* tabs) {
    int i = blockIdx.x * 256 + threadIdx.x;
    if (i < 2 * TDIM) maskt[i] = 0;
    if (i < PACK) maskf[i] = 0;
    if (i < 1024) {
        double ang = (double)i * (3.14159265358979323846 * 2.0 / 1024.0);
        tabc[i] = (float)cos(ang);
        tabs[i] = (float)sin(ang);
    }
}

// ---------------- fused conversions: twid_hl + weights + x_hl + w_hl ----------------
__global__ void convall_k(const float* __restrict__ tabc, const float* __restrict__ tabs,
                          const float* __restrict__ W1t, const float* __restrict__ W2t,
                          const float* __restrict__ W_emb, const float* __restrict__ x,
                          unsigned short* __restrict__ thl,
                          unsigned short* __restrict__ w1b, unsigned short* __restrict__ w2b,
                          unsigned short* __restrict__ wemT,
                          unsigned short* __restrict__ xhl, unsigned short* __restrict__ whl)
{
    int blk = blockIdx.x;
    if (blk < 1088) {
        int row = blk;
        unsigned short* dst = thl + (size_t)row * 3072;
        for (int c = threadIdx.x; c < 3072; c += 256) {
            int seg = c >> 10, t = c & 1023;
            float v = 0.0f;
            if (row < PACK) v = (row < NFREQ) ? tabc[(row * t) & 1023] : -tabs[((row - NFREQ) * t) & 1023];
            unsigned short hi = f2bf(v);
            dst[c] = (seg < 2) ? hi : f2bf(v - bf2f(hi));
        }
    } else if (blk < 2304) {
        int r = blk - 1088;
        if (r < 640) {
            int rr = r & 319;
            const float* src = (r < 320) ? W1t : W2t;
            unsigned short* dst = (r < 320) ? w1b : w2b;
            for (int c = threadIdx.x; c < 288; c += 256) {
                float v = (rr < DD && c < DD) ? src[(size_t)rr * DD + c] : 0.0f;
                dst[(size_t)rr * 288 + c] = f2bf(v);
            }
        } else {
            int rr = r - 640;  // 0..575
            for (int c = threadIdx.x; c < 288; c += 256) {
                float v = (rr < CC && c < DD) ? W_emb[(size_t)c * CC + rr] : 0.0f;
                wemT[(size_t)rr * 288 + c] = f2bf(v);
            }
        }
    } else if (blk < 4352) {
        int r = blk - 2304;
        const float* src = x + (size_t)r * CC;
        unsigned short* dst = xhl + (size_t)r * 1632;
        for (int c = threadIdx.x; c < 1632; c += 256) {
            int seg = c / 544, cc = c - seg * 544;
            float v = (cc < CC) ? src[cc] : 0.0f;
            unsigned short hi = f2bf(v);
            dst[c] = (seg < 2) ? hi : f2bf(v - bf2f(hi));
        }
    } else {
        int n = blk - 4352;
        unsigned short* dst = whl + (size_t)n * 1632;
        for (int c = threadIdx.x; c < 1632; c += 256) {
            int seg = c / 544, cc = c - seg * 544;
            float v = (n < DD && cc < CC) ? W_emb[(size_t)n * CC + cc] : 0.0f;
            unsigned short hi = f2bf(v);
            dst[c] = (seg == 1) ? f2bf(v - bf2f(hi)) : hi;
        }
    }
}

__global__ __launch_bounds__(64) void sliding_score_k(const float* __restrict__ ex,
                                                      double* __restrict__ score)
{
    const int ib = blockIdx.x;
    const int t = ib & (TDIM - 1);
    const int lane = threadIdx.x;
    double ms = 0.0, vs = 0.0;
    if (t >= 24) {
        // fast path: full 25-wide window, loads fully unrolled -> pipelined
        const float* base = ex + (size_t)(ib - 24) * DD;
        for (int d = lane; d < DD; d += 64) {
            float s1 = 0.0f, s2 = 0.0f;
#pragma unroll
            for (int r = 0; r < 25; r++) {
                float v = base[(size_t)r * DD + d];
                s1 += v;
                s2 += v * v;
            }
            float m1 = s1 * (1.0f / 25.0f);
            float var = s2 * (1.0f / 25.0f) - m1 * m1;
            ms += (double)m1;
            vs += (double)var;
        }
    } else {
        const int nt = t + 1;
        const float cnt = (float)nt;
        const float* base = ex + (size_t)(ib - t) * DD;
        for (int d = lane; d < DD; d += 64) {
            float s1 = 0.0f, s2 = 0.0f;
            for (int r = 0; r < nt; r++) {
                float v = base[(size_t)r * DD + d];
                s1 += v;
                s2 += v * v;
            }
            float m1 = s1 / cnt;
            float var = s2 / cnt - m1 * m1;
            ms += (double)m1;
            vs += (double)var;
        }
    }
#pragma unroll
    for (int off = 32; off; off >>= 1) { ms += __shfl_xor(ms, off); vs += __shfl_xor(vs, off); }
    if (lane == 0) score[ib] = vs / (ms + (double)1e-6f);
}

__global__ __launch_bounds__(512) void topk_sort_k(const double* __restrict__ score,
                                                   int n, int kcount,
                                                   float* __restrict__ out_f,
                                                   int* __restrict__ out_i,
                                                   int* __restrict__ mask)
{
    __shared__ double sv[1024];
    __shared__ int    si[1024];
    const int b = blockIdx.x, tid = threadIdx.x;
    const double* s = score + (size_t)b * n;
    for (int i = tid; i < 1024; i += 512) {
        sv[i] = (i < n) ? s[i] : -1.0e300;
        si[i] = i;
    }
    __syncthreads();
    for (int k = 2; k <= 1024; k <<= 1) {
        for (int j = k >> 1; j > 0; j >>= 1) {
            // exact pair enumeration: insert 0-bit at position log2(j)
            int t = ((tid & ~(j - 1)) << 1) | (tid & (j - 1));
            int l = t | j;
            double v0 = sv[t], v1 = sv[l];
            int i0 = si[t], i1 = si[l];
            bool g = (v0 > v1) || (v0 == v1 && i0 < i1);  // t-elem ranks first
            bool wrong = ((t & k) == 0) ? !g : g;
            if (wrong) {
                sv[t] = v1; sv[l] = v0;
                si[t] = i1; si[l] = i0;
            }
            __syncthreads();
        }
    }
    for (int t = tid; t < kcount; t += 512) {
        int bi = si[t];
        out_f[(size_t)b * kcount + t] = (float)bi;
        out_i[b * kcount + t] = bi;
        mask[b * n + bi] = 1;
    }
}

__global__ void build_masked_k(const float* __restrict__ ex, const float* __restrict__ ttok,
                               const int* __restrict__ maskt, unsigned short* __restrict__ mb) {
    int bt = blockIdx.x;
    int d = threadIdx.x;
    if (d >= 288) return;
    float v = 0.0f;
    if (d < DD) v = maskt[bt] ? ttok[d] : ex[(size_t)bt * DD + d];
    mb[(size_t)bt * 288 + d] = f2bf(v);
}

__global__ void mag_k(const float* __restrict__ cxp, double* __restrict__ magm) {
    int ib = blockIdx.x;
    int b = ib / NFREQ, k = ib % NFREQ;
    int lane = threadIdx.x;
    const float* re = cxp + ((size_t)b * PACK + k) * DD;
    const float* im = cxp + ((size_t)b * PACK + NFREQ + k) * DD;
    double acc = 0.0;
    for (int d = lane; d < DD; d += 64) {
        float r = re[d], i = im[d];
        acc += (double)sqrtf(r * r + i * i);
    }
#pragma unroll
    for (int off = 32; off; off >>= 1) acc += __shfl_xor(acc, off);
    if (lane == 0) magm[ib] = acc / (double)DD;
}

// builds IT_sel [2048][224] and delta [640][224] bf16 for the rank-102 correction
__global__ void sel_delta_k(const float* __restrict__ tabc, const float* __restrict__ tabs,
                            const int* __restrict__ idxf, const float* __restrict__ cxp,
                            const float* __restrict__ ftr, const float* __restrict__ fti,
                            unsigned short* __restrict__ itsel, unsigned short* __restrict__ delta) {
    int blk = blockIdx.x;
    if (blk < 2048) {
        int b = blk >> 10, t = blk & 1023;
        unsigned short* dst = itsel + (size_t)blk * 224;
        for (int j = threadIdx.x; j < 224; j += 256) {
            float v = 0.0f;
            if (j < KTOP) {
                int k = idxf[b * KTOP + j];
                float w = (k == 0 || k == 512) ? 1.0f : 2.0f;
                v = (w * (1.0f / 1024.0f)) * tabc[(k * t) & 1023];
            } else if (j >= 112 && j < 112 + KTOP) {
                int k = idxf[b * KTOP + j - 112];
                v = (k == 0 || k == 512) ? 0.0f : (-2.0f / 1024.0f) * tabs[(k * t) & 1023];
            }
            dst[j] = f2bf(v);
        }
    } else {
        int idx = blk - 2048;
        int b = idx / 320, d = idx - (idx / 320) * 320;
        unsigned short* dst = delta + (size_t)idx * 224;
        for (int j = threadIdx.x; j < 224; j += 256) {
            float v = 0.0f;
            if (d < DD) {
                if (j < KTOP) {
                    int k = idxf[b * KTOP + j];
                    v = ftr[d] - cxp[((size_t)b * PACK + k) * DD + d];
                } else if (j >= 112 && j < 112 + KTOP) {
                    int k = idxf[b * KTOP + j - 112];
                    v = fti[d] - cxp[((size_t)b * PACK + NFREQ + k) * DD + d];
                }
            }
            dst[j] = f2bf(v);
        }
    }
}

// ---------------- launch ----------------
extern "C" void kernel_launch(void* const* d_in, const int* in_sizes, int n_in,
                              void* d_out, int out_size, void* d_ws, size_t ws_size,
                              hipStream_t stream) {
    (void)in_sizes; (void)n_in; (void)out_size; (void)ws_size;
    const float* x      = (const float*)d_in[0];
    const float* W_emb  = (const float*)d_in[1];
    const float* b_emb  = (const float*)d_in[2];
    const float* ttok   = (const float*)d_in[3];
    const float* W1t    = (const float*)d_in[4];
    const float* b1t    = (const float*)d_in[5];
    const float* W2t    = (const float*)d_in[6];
    const float* b2t    = (const float*)d_in[7];
    const float* ftr    = (const float*)d_in[8];
    const float* fti    = (const float*)d_in[9];
    float* out = (float*)d_out;
    float* ws  = (float*)d_ws;

    float* ex     = ws + WS_EX;
    float* cxp    = ws + WS_CXP;
    float* tabc   = ws + WS_TABC;
    float* tabs   = ws + WS_TABS;
    double* score = (double*)(ws + WS_SCORE);
    double* magm  = (double*)(ws + WS_MAGM);
    int* maskt    = (int*)(ws + WS_MASKT);
    int* idxt     = (int*)(ws + WS_IDXT);
    int* idxf     = (int*)(ws + WS_IDXF);
    int* maskf    = (int*)(ws + WS_MASKF);
    unsigned short* w1b   = (unsigned short*)(ws + WS_W1BF);
    unsigned short* w2b   = (unsigned short*)(ws + WS_W2BF);
    unsigned short* wemT  = (unsigned short*)(ws + WS_WEMT);
    unsigned short* maskb = (unsigned short*)(ws + WS_MASKB);
    unsigned short* hb    = (unsigned short*)(ws + WS_HBF);
    unsigned short* xtb   = (unsigned short*)(ws + WS_XTBF);
    unsigned short* itsel = (unsigned short*)(ws + WS_ITSEL);
    unsigned short* delta = (unsigned short*)(ws + WS_DELTA);
    unsigned short* xhl   = (unsigned short*)(ws + WS_XHL);
    unsigned short* thl   = (unsigned short*)(ws + WS_THL);
    unsigned short* whl   = (unsigned short*)(ws + WS_WHL);
    unsigned short* exthl = (unsigned short*)(ws + WS_EXTHL);

    // fused init + fused conversions
    init0_k<<<8, 256, 0, stream>>>(maskt, maskf, tabc, tabs);
    convall_k<<<4672, 256, 0, stream>>>(tabc, tabs, W1t, W2t, W_emb, x,
                                        thl, w1b, w2b, wemT, xhl, whl);

    // ex = x @ W_emb^T + b_emb + pe  (split-bf16 MFMA, K'=1632; fused exT-hl scatter)
    gemm_mfma<4, 1><<<160, 256, 0, stream>>>(xhl, whl, b_emb, ex, exthl, 2048, DD, 1632, DD, 5);

    // temporal score -> topk
    sliding_score_k<<<2048, 64, 0, stream>>>(ex, score);
    topk_sort_k<<<2, 512, 0, stream>>>(score, TDIM, KTOP, out + OFF_IDXT, idxt, maskt);

    // masked -> h -> (sigmoid+select into maskb)
    build_masked_k<<<2048, 320, 0, stream>>>(ex, ttok, maskt, maskb);
    gemm_mfma<1, 1><<<160, 256, 0, stream>>>(maskb, w1b, b1t, hb, nullptr, 2048, DD, 288, 288, 5);
    gemm_mfma<8, 1><<<160, 256, 0, stream>>>(hb, w2b, b2t, maskb, maskt, 2048, DD, 288, 288, 5);

    // forward DFT (split-bf16 MFMA, K'=3072, KU=2, batches merged in N)
    gemm_mfma<5, 2><<<170, 256, 0, stream>>>(thl, exthl, nullptr, cxp, nullptr, PACK, 640, 3072, 0, 10);
    mag_k<<<2 * NFREQ, 64, 0, stream>>>(cxp, magm);
    topk_sort_k<<<2, 512, 0, stream>>>(magm, NFREQ, KTOP, out + OFF_IDXF, idxf, maskf);

    // rank-102 correction instead of full iDFT: xt = ex + IT_sel @ delta
    sel_delta_k<<<2688, 256, 0, stream>>>(tabc, tabs, idxf, cxp, ftr, fti, itsel, delta);
    gemm_mfma<7, 1><<<160, 256, 0, stream>>>(itsel, delta, ex, xtb, nullptr, 2048, 320, 224, 288, 5);

    // merged out_t / out_f:  [maskb ; xtb] (contiguous 4096x288) @ wemT
    gemm_mfma<9, 1><<<576, 256, 0, stream>>>(maskb, wemT, nullptr, out, nullptr, 4096, CC, 288, CC, 9);
}

// Round 16
// 130.169 us; speedup vs baseline: 1.9583x; 1.2463x over previous
//
#include <hip/hip_runtime.h>

#define TDIM 1024
#define DD   263
#define CC   526
#define NFREQ 513
#define PACK 1026
#define KTOP 102

// ---------------- ws layout (float offsets) ----------------
static const size_t WS_EX     = 0;          // 538624 f32
static const size_t WS_W1BF   = 538624;     // 320x288 bf16
static const size_t WS_W2BF   = 584704;
static const size_t WS_WEMT   = 630784;     // 576x288 bf16 (ends 713728)
static const size_t WS_MASKB  = 1615872;    // 2048x288 bf16 = 294912 f
static const size_t WS_XTBF   = 1910784;    // 2048x288 bf16 (contiguous after MASKB)
static const size_t WS_HBF    = 2693120;    // 2048x288 bf16
static const size_t WS_CXP    = 3770368;    // f32 2*1026*263
static const size_t WS_EXTHL  = 4310044;    // [640][3072] bf16 = 983040 f
static const size_t WS_ITSEL  = 5360668;    // [2048][224] bf16 = 229376 f
static const size_t WS_DELTA  = 5901340;    // [640][224] bf16 = 71680 f
static const size_t WS_TABC   = 6411292;    // 1024
static const size_t WS_TABS   = 6412316;    // 1024
static const size_t WS_SCORE  = 6413340;    // double[2048]
static const size_t WS_MAGM   = 6417436;    // double[1026]
static const size_t WS_MASKT  = 6419488;    // int[2048]
static const size_t WS_IDXT   = 6421536;    // int[204]
static const size_t WS_IDXF   = 6421740;    // int[204]
static const size_t WS_MASKF  = 6421944;    // int[1026]
static const size_t WS_XHL    = 6422972;    // 2048x1632 bf16 = 1671168 f
static const size_t WS_THL    = 8094140;    // 1088x3072 bf16 = 1671168 f
static const size_t WS_WHL    = 9765308;    // 320x1632 bf16 = 261120 f
static const size_t WS_TOTAL  = 10740380;   // floats

static const size_t OFF_OUTT = 0;
static const size_t OFF_IDXT = 1077248;
static const size_t OFF_OUTF = 1077452;
static const size_t OFF_IDXF = 2154700;

typedef __bf16 bf16x8_t __attribute__((ext_vector_type(8)));
typedef float  f32x4_t  __attribute__((ext_vector_type(4)));

__device__ __forceinline__ unsigned short f2bf(float f) {
    unsigned int u = __float_as_uint(f);
    unsigned int r = (u + 0x7fffu + ((u >> 16) & 1u)) >> 16;
    return (unsigned short)r;
}
__device__ __forceinline__ float bf2f(unsigned short h) {
    return __uint_as_float(((unsigned int)h) << 16);
}

__device__ __forceinline__ float pe_val(int t, int d) {
    const float sc = (float)(-9.210340371976184 / 263.0);  // -ln(10000)/D
    int j = d >> 1;
    float div = expf((float)(2 * j) * sc);
    float a = (float)t * div;
    return (d & 1) ? cosf(a) : sinf(a);
}

// raw workgroup barrier: no implicit vmcnt(0) drain (prefetch stays in flight)
#define WG_FENCE()   asm volatile("" ::: "memory")
#define WG_BARRIER() { WG_FENCE(); __builtin_amdgcn_s_barrier(); WG_FENCE(); }

// ---------------- bf16 MFMA GEMM body (device fn; hw/nwg are LOCAL grid id/size) ----------------
// C = A @ Bt^T. A [>=M x SA] bf16, Bt [64*gy x SA] bf16. Tile 64x64, 4 waves 2x2, 256 thr.
// EPI: 0 ->f32; 1 bias+gelu->bf16; 4 bias+pe->f32 + exthl scatter (aux); 5 DFT scatter ->cxp;
//      7 corr: xtb=bf16(ex+v); 8 sigmoid+select (aux=maskt); 9 dual-out
template<int EPI, int KU>
__device__ __forceinline__ void gemm_body(int hw, int nwg,
                                          const unsigned short* __restrict__ A,
                                          const unsigned short* __restrict__ Bt,
                                          const float* __restrict__ bias,
                                          void* __restrict__ Cv,
                                          void* __restrict__ aux,
                                          int M, int N, int SA, int NC, int gy)
{
    __shared__ unsigned short As[64][32 * KU + 8];
    __shared__ unsigned short Bs[64][32 * KU + 8];
    // XCD-bijective chunked swizzle (m204)
    const int q = nwg >> 3, r = nwg & 7, xcd = hw & 7;
    const int logical = (xcd < r ? xcd * (q + 1) : r * (q + 1) + (xcd - r) * q) + (hw >> 3);
    const int row0 = (logical / gy) * 64, col0 = (logical % gy) * 64;
    if (EPI == 7) Bt += (size_t)(row0 >> 10) * 320 * SA;   // per-batch delta panel

    const int tid  = threadIdx.x;
    const int wid = tid >> 6, lane = tid & 63;
    const int wr = wid >> 1, wc = wid & 1;
    const int srow = tid >> 2, skoff = (tid & 3) * 8;
    const int fl = lane & 15, fh = lane >> 4;
    f32x4_t acc[2][2];
#pragma unroll
    for (int i = 0; i < 2; i++)
#pragma unroll
        for (int j = 0; j < 2; j++) acc[i][j] = (f32x4_t){0.f, 0.f, 0.f, 0.f};

    const int nk = SA / (32 * KU);
    const unsigned short* pa = A  + (size_t)(row0 + srow) * SA + skoff;
    const unsigned short* pb = Bt + (size_t)(col0 + srow) * SA + skoff;

    bf16x8_t qa[4][KU], qb[4][KU];
#pragma unroll
    for (int j = 0; j < 4; ++j) {
        if (j < nk) {
#pragma unroll
            for (int u = 0; u < KU; ++u) {
                qa[j][u] = *(const bf16x8_t*)(pa + (size_t)j * (32 * KU) + u * 32);
                qb[j][u] = *(const bf16x8_t*)(pb + (size_t)j * (32 * KU) + u * 32);
            }
        }
    }

    for (int itb = 0; itb < nk; itb += 4) {
#pragma unroll
        for (int j = 0; j < 4; ++j) {
            const int it = itb + j;
            if (it < nk) {
                if (it > 0) WG_BARRIER();
#pragma unroll
                for (int u = 0; u < KU; ++u) {
                    *(bf16x8_t*)(&As[srow][u * 32 + skoff]) = qa[j][u];
                    *(bf16x8_t*)(&Bs[srow][u * 32 + skoff]) = qb[j][u];
                }
                asm volatile("s_waitcnt lgkmcnt(0)" ::: "memory");
                WG_BARRIER();
#pragma unroll
                for (int u = 0; u < KU; ++u) {
                    bf16x8_t fa0 = *(const bf16x8_t*)(&As[wr * 32 + fl][u * 32 + fh * 8]);
                    bf16x8_t fa1 = *(const bf16x8_t*)(&As[wr * 32 + 16 + fl][u * 32 + fh * 8]);
                    bf16x8_t fb0 = *(const bf16x8_t*)(&Bs[wc * 32 + fl][u * 32 + fh * 8]);
                    bf16x8_t fb1 = *(const bf16x8_t*)(&Bs[wc * 32 + 16 + fl][u * 32 + fh * 8]);
                    acc[0][0] = __builtin_amdgcn_mfma_f32_16x16x32_bf16(fa0, fb0, acc[0][0], 0, 0, 0);
                    acc[0][1] = __builtin_amdgcn_mfma_f32_16x16x32_bf16(fa0, fb1, acc[0][1], 0, 0, 0);
                    acc[1][0] = __builtin_amdgcn_mfma_f32_16x16x32_bf16(fa1, fb0, acc[1][0], 0, 0, 0);
                    acc[1][1] = __builtin_amdgcn_mfma_f32_16x16x32_bf16(fa1, fb1, acc[1][1], 0, 0, 0);
                }
                if (it + 4 < nk) {
#pragma unroll
                    for (int u = 0; u < KU; ++u) {
                        qa[j][u] = *(const bf16x8_t*)(pa + (size_t)(it + 4) * (32 * KU) + u * 32);
                        qb[j][u] = *(const bf16x8_t*)(pb + (size_t)(it + 4) * (32 * KU) + u * 32);
                    }
                }
            }
        }
    }

#pragma unroll
    for (int fi = 0; fi < 2; fi++)
#pragma unroll
        for (int fj = 0; fj < 2; fj++)
#pragma unroll
            for (int rr = 0; rr < 4; rr++) {
                int m = row0 + wr * 32 + fi * 16 + fh * 4 + rr;
                int n = col0 + wc * 32 + fj * 16 + fl;
                if (m >= M) continue;
                float v = acc[fi][fj][rr];
                if (EPI == 0) {
                    if (n < N) ((float*)Cv)[(size_t)m * NC + n] = v;
                } else if (EPI == 1) {
                    if (n < NC) {
                        float o = 0.0f;
                        if (n < N) { o = v + bias[n]; o = 0.5f * o * (1.0f + erff(o * 0.70710678118654752f)); }
                        ((unsigned short*)Cv)[(size_t)m * NC + n] = f2bf(o);
                    }
                } else if (EPI == 4) {
                    if (n < N) {
                        float o = v + bias[n] + pe_val(m & (TDIM - 1), n);
                        ((float*)Cv)[(size_t)m * NC + n] = o;
                        unsigned short hi = f2bf(o);
                        unsigned short lo = f2bf(o - bf2f(hi));
                        size_t b2 = ((size_t)(m >> 10) * 320 + n) * 3072 + (m & 1023);
                        unsigned short* xh = (unsigned short*)aux;
                        xh[b2] = hi; xh[b2 + 1024] = lo; xh[b2 + 2048] = hi;
                    }
                } else if (EPI == 5) {
                    int b = n / 320, col = n - b * 320;
                    if (col < DD) ((float*)Cv)[((size_t)b * PACK + m) * DD + col] = v;
                } else if (EPI == 7) {
                    if (n < 288) {
                        unsigned short o = 0;
                        if (n < DD) o = f2bf(bias[(size_t)m * DD + n] + v);
                        ((unsigned short*)Cv)[(size_t)m * 288 + n] = o;
                    }
                } else if (EPI == 8) {
                    const int* mt = (const int*)aux;
                    if (n < 288 && !mt[m]) {
                        unsigned short o = 0;
                        if (n < DD) {
                            float s = v + bias[n];
                            o = f2bf(1.0f / (1.0f + expf(-s)));
                        }
                        ((unsigned short*)Cv)[(size_t)m * 288 + n] = o;
                    }
                } else {  // EPI 9: dual output
                    if (n < CC) {
                        size_t off = (m < 2048) ? (size_t)m * CC + n
                                                : (size_t)OFF_OUTF + (size_t)(m - 2048) * CC + n;
                        ((float*)Cv)[off] = v;
                    }
                }
            }
}

template<int EPI, int KU>
__global__ __launch_bounds__(256) void gemm_k(const unsigned short* __restrict__ A,
                                              const unsigned short* __restrict__ Bt,
                                              const float* __restrict__ bias,
                                              void* __restrict__ Cv, void* __restrict__ aux,
                                              int M, int N, int SA, int NC, int gy)
{
    gemm_body<EPI, KU>(blockIdx.x, gridDim.x, A, Bt, bias, Cv, aux, M, N, SA, NC, gy);
}

// ---------------- wave bodies (identical arithmetic to r14) ----------------
__device__ __forceinline__ void score_wave(int ib, const float* __restrict__ ex,
                                           double* __restrict__ score) {
    const int t = ib & (TDIM - 1);
    const int lane = threadIdx.x & 63;
    double ms = 0.0, vs = 0.0;
    if (t >= 24) {
        const float* base = ex + (size_t)(ib - 24) * DD;
        for (int d = lane; d < DD; d += 64) {
            float s1 = 0.0f, s2 = 0.0f;
#pragma unroll
            for (int r = 0; r < 25; r++) {
                float v = base[(size_t)r * DD + d];
                s1 += v;
                s2 += v * v;
            }
            float m1 = s1 * (1.0f / 25.0f);
            float var = s2 * (1.0f / 25.0f) - m1 * m1;
            ms += (double)m1;
            vs += (double)var;
        }
    } else {
        const int nt = t + 1;
        const float cnt = (float)nt;
        const float* base = ex + (size_t)(ib - t) * DD;
        for (int d = lane; d < DD; d += 64) {
            float s1 = 0.0f, s2 = 0.0f;
            for (int r = 0; r < nt; r++) {
                float v = base[(size_t)r * DD + d];
                s1 += v;
                s2 += v * v;
            }
            float m1 = s1 / cnt;
            float var = s2 / cnt - m1 * m1;
            ms += (double)m1;
            vs += (double)var;
        }
    }
#pragma unroll
    for (int off = 32; off; off >>= 1) { ms += __shfl_xor(ms, off); vs += __shfl_xor(vs, off); }
    if (lane == 0) score[ib] = vs / (ms + (double)1e-6f);
}

__device__ __forceinline__ void mag_wave(int ib, const float* __restrict__ cxp,
                                         double* __restrict__ magm) {
    int b = ib / NFREQ, k = ib % NFREQ;
    int lane = threadIdx.x & 63;
    const float* re = cxp + ((size_t)b * PACK + k) * DD;
    const float* im = cxp + ((size_t)b * PACK + NFREQ + k) * DD;
    double acc = 0.0;
    for (int d = lane; d < DD; d += 64) {
        float r = re[d], i = im[d];
        acc += (double)sqrtf(r * r + i * i);
    }
#pragma unroll
    for (int off = 32; off; off >>= 1) acc += __shfl_xor(acc, off);
    if (lane == 0) magm[ib] = acc / (double)DD;
}

// topk body (512 threads; exact pair enumeration)
__device__ __forceinline__ void topk_body(int b, const double* __restrict__ score,
                                          int n, int kcount,
                                          float* __restrict__ out_f, int* __restrict__ out_i,
                                          int* __restrict__ mask) {
    __shared__ double sv[1024];
    __shared__ int    si[1024];
    const int tid = threadIdx.x;
    const double* s = score + (size_t)b * n;
    for (int i = tid; i < 1024; i += 512) {
        sv[i] = (i < n) ? s[i] : -1.0e300;
        si[i] = i;
    }
    __syncthreads();
    for (int k = 2; k <= 1024; k <<= 1) {
        for (int j = k >> 1; j > 0; j >>= 1) {
            int t = ((tid & ~(j - 1)) << 1) | (tid & (j - 1));
            int l = t | j;
            double v0 = sv[t], v1 = sv[l];
            int i0 = si[t], i1 = si[l];
            bool g = (v0 > v1) || (v0 == v1 && i0 < i1);
            bool wrong = ((t & k) == 0) ? !g : g;
            if (wrong) {
                sv[t] = v1; sv[l] = v0;
                si[t] = i1; si[l] = i0;
            }
            __syncthreads();
        }
    }
    for (int t = tid; t < kcount; t += 512) {
        int bi = si[t];
        out_f[(size_t)b * kcount + t] = (float)bi;
        out_i[b * kcount + t] = bi;
        mask[b * n + bi] = 1;
    }
}

__device__ __forceinline__ void build_masked_body(int bt, const float* __restrict__ ex,
                                                  const float* __restrict__ ttok,
                                                  const int* __restrict__ maskt,
                                                  unsigned short* __restrict__ mb) {
    int d = threadIdx.x;
    if (d >= 288) return;
    float v = 0.0f;
    if (d < DD) v = maskt[bt] ? ttok[d] : ex[(size_t)bt * DD + d];
    mb[(size_t)bt * 288 + d] = f2bf(v);
}

__device__ __forceinline__ void sel_delta_body(int blk,
                                               const float* __restrict__ tabc, const float* __restrict__ tabs,
                                               const int* __restrict__ idxf, const float* __restrict__ cxp,
                                               const float* __restrict__ ftr, const float* __restrict__ fti,
                                               unsigned short* __restrict__ itsel,
                                               unsigned short* __restrict__ delta) {
    if (blk < 2048) {
        int b = blk >> 10, t = blk & 1023;
        unsigned short* dst = itsel + (size_t)blk * 224;
        for (int j = threadIdx.x; j < 224; j += 256) {
            float v = 0.0f;
            if (j < KTOP) {
                int k = idxf[b * KTOP + j];
                float w = (k == 0 || k == 512) ? 1.0f : 2.0f;
                v = (w * (1.0f / 1024.0f)) * tabc[(k * t) & 1023];
            } else if (j >= 112 && j < 112 + KTOP) {
                int k = idxf[b * KTOP + j - 112];
                v = (k == 0 || k == 512) ? 0.0f : (-2.0f / 1024.0f) * tabs[(k * t) & 1023];
            }
            dst[j] = f2bf(v);
        }
    } else {
        int idx = blk - 2048;
        int b = idx / 320, d = idx - (idx / 320) * 320;
        unsigned short* dst = delta + (size_t)idx * 224;
        for (int j = threadIdx.x; j < 224; j += 256) {
            float v = 0.0f;
            if (d < DD) {
                if (j < KTOP) {
                    int k = idxf[b * KTOP + j];
                    v = ftr[d] - cxp[((size_t)b * PACK + k) * DD + d];
                } else if (j >= 112 && j < 112 + KTOP) {
                    int k = idxf[b * KTOP + j - 112];
                    v = fti[d] - cxp[((size_t)b * PACK + NFREQ + k) * DD + d];
                }
            }
            dst[j] = f2bf(v);
        }
    }
}

// ---------------- fused kernels (block-range dispatch; independent nodes overlap) ----------------
__global__ __launch_bounds__(256) void fused_dft_score_k(const unsigned short* __restrict__ thl,
                                                         const unsigned short* __restrict__ exthl,
                                                         float* __restrict__ cxp,
                                                         const float* __restrict__ ex,
                                                         double* __restrict__ score)
{
    if (blockIdx.x < 170) {
        gemm_body<5, 2>(blockIdx.x, 170, thl, exthl, nullptr, cxp, nullptr, PACK, 640, 3072, 0, 10);
    } else {
        int ib = (int)(blockIdx.x - 170) * 4 + (threadIdx.x >> 6);
        score_wave(ib, ex, score);
    }
}

__global__ __launch_bounds__(512) void fused_topkt_mag_k(const double* __restrict__ score,
                                                         float* __restrict__ outf, int* __restrict__ idxt,
                                                         int* __restrict__ maskt,
                                                         const float* __restrict__ cxp,
                                                         double* __restrict__ magm)
{
    if (blockIdx.x < 2) {
        topk_body(blockIdx.x, score, TDIM, KTOP, outf, idxt, maskt);
    } else {
        int ib = (int)(blockIdx.x - 2) * 8 + (threadIdx.x >> 6);
        if (ib < 2 * NFREQ) mag_wave(ib, cxp, magm);
    }
}

__global__ __launch_bounds__(512) void fused_topkf_bm_k(const double* __restrict__ magm,
                                                        float* __restrict__ outf, int* __restrict__ idxf,
                                                        int* __restrict__ maskf,
                                                        const float* __restrict__ ex,
                                                        const float* __restrict__ ttok,
                                                        const int* __restrict__ maskt,
                                                        unsigned short* __restrict__ mb)
{
    if (blockIdx.x < 2) {
        topk_body(blockIdx.x, magm, NFREQ, KTOP, outf, idxf, maskf);
    } else {
        build_masked_body(blockIdx.x - 2, ex, ttok, maskt, mb);
    }
}

__global__ __launch_bounds__(256) void fused_h_seldelta_k(const unsigned short* __restrict__ maskb,
                                                          const unsigned short* __restrict__ w1b,
                                                          const float* __restrict__ b1t,
                                                          unsigned short* __restrict__ hb,
                                                          const float* __restrict__ tabc,
                                                          const float* __restrict__ tabs,
                                                          const int* __restrict__ idxf,
                                                          const float* __restrict__ cxp,
                                                          const float* __restrict__ ftr,
                                                          const float* __restrict__ fti,
                                                          unsigned short* __restrict__ itsel,
                                                          unsigned short* __restrict__ delta)
{
    if (blockIdx.x < 160) {
        gemm_body<1, 1>(blockIdx.x, 160, maskb, w1b, b1t, hb, nullptr, 2048, DD, 288, 288, 5);
    } else {
        sel_delta_body(blockIdx.x - 160, tabc, tabs, idxf, cxp, ftr, fti, itsel, delta);
    }
}

__global__ __launch_bounds__(256) void fused_sig_corr_k(const unsigned short* __restrict__ hb,
                                                        const unsigned short* __restrict__ w2b,
                                                        const float* __restrict__ b2t,
                                                        unsigned short* __restrict__ maskb,
                                                        const int* __restrict__ maskt,
                                                        const unsigned short* __restrict__ itsel,
                                                        const unsigned short* __restrict__ delta,
                                                        const float* __restrict__ ex,
                                                        unsigned short* __restrict__ xtb)
{
    if (blockIdx.x < 160) {
        gemm_body<8, 1>(blockIdx.x, 160, hb, w2b, b2t, maskb, (void*)maskt, 2048, DD, 288, 288, 5);
    } else {
        gemm_body<7, 1>(blockIdx.x - 160, 160, itsel, delta, ex, xtb, nullptr, 2048, 320, 224, 288, 5);
    }
}

// ---------------- fused init: masks + sincos tables ----------------
__global__ void init0_k(int* maskt, int* maskf, float* tabc, float* tabs) {
    int i = blockIdx.x * 256 + threadIdx.x;
    if (i < 2 * TDIM) maskt[i] = 0;
    if (i < PACK) maskf[i] = 0;
    if (i < 1024) {
        double ang = (double)i * (3.14159265358979323846 * 2.0 / 1024.0);
        tabc[i] = (float)cos(ang);
        tabs[i] = (float)sin(ang);
    }
}

// ---------------- fused conversions: twid_hl + weights + x_hl + w_hl ----------------
__global__ void convall_k(const float* __restrict__ tabc, const float* __restrict__ tabs,
                          const float* __restrict__ W1t, const float* __restrict__ W2t,
                          const float* __restrict__ W_emb, const float* __restrict__ x,
                          unsigned short* __restrict__ thl,
                          unsigned short* __restrict__ w1b, unsigned short* __restrict__ w2b,
                          unsigned short* __restrict__ wemT,
                          unsigned short* __restrict__ xhl, unsigned short* __restrict__ whl)
{
    int blk = blockIdx.x;
    if (blk < 1088) {
        int row = blk;
        unsigned short* dst = thl + (size_t)row * 3072;
        for (int c = threadIdx.x; c < 3072; c += 256) {
            int seg = c >> 10, t = c & 1023;
            float v = 0.0f;
            if (row < PACK) v = (row < NFREQ) ? tabc[(row * t) & 1023] : -tabs[((row - NFREQ) * t) & 1023];
            unsigned short hi = f2bf(v);
            dst[c] = (seg < 2) ? hi : f2bf(v - bf2f(hi));
        }
    } else if (blk < 2304) {
        int r = blk - 1088;
        if (r < 640) {
            int rr = r & 319;
            const float* src = (r < 320) ? W1t : W2t;
            unsigned short* dst = (r < 320) ? w1b : w2b;
            for (int c = threadIdx.x; c < 288; c += 256) {
                float v = (rr < DD && c < DD) ? src[(size_t)rr * DD + c] : 0.0f;
                dst[(size_t)rr * 288 + c] = f2bf(v);
            }
        } else {
            int rr = r - 640;  // 0..575
            for (int c = threadIdx.x; c < 288; c += 256) {
                float v = (rr < CC && c < DD) ? W_emb[(size_t)c * CC + rr] : 0.0f;
                wemT[(size_t)rr * 288 + c] = f2bf(v);
            }
        }
    } else if (blk < 4352) {
        int r = blk - 2304;
        const float* src = x + (size_t)r * CC;
        unsigned short* dst = xhl + (size_t)r * 1632;
        for (int c = threadIdx.x; c < 1632; c += 256) {
            int seg = c / 544, cc = c - seg * 544;
            float v = (cc < CC) ? src[cc] : 0.0f;
            unsigned short hi = f2bf(v);
            dst[c] = (seg < 2) ? hi : f2bf(v - bf2f(hi));
        }
    } else {
        int n = blk - 4352;
        unsigned short* dst = whl + (size_t)n * 1632;
        for (int c = threadIdx.x; c < 1632; c += 256) {
            int seg = c / 544, cc = c - seg * 544;
            float v = (n < DD && cc < CC) ? W_emb[(size_t)n * CC + cc] : 0.0f;
            unsigned short hi = f2bf(v);
            dst[c] = (seg == 1) ? f2bf(v - bf2f(hi)) : hi;
        }
    }
}

// ---------------- launch ----------------
extern "C" void kernel_launch(void* const* d_in, const int* in_sizes, int n_in,
                              void* d_out, int out_size, void* d_ws, size_t ws_size,
                              hipStream_t stream) {
    (void)in_sizes; (void)n_in; (void)out_size; (void)ws_size;
    const float* x      = (const float*)d_in[0];
    const float* W_emb  = (const float*)d_in[1];
    const float* b_emb  = (const float*)d_in[2];
    const float* ttok   = (const float*)d_in[3];
    const float* W1t    = (const float*)d_in[4];
    const float* b1t    = (const float*)d_in[5];
    const float* W2t    = (const float*)d_in[6];
    const float* b2t    = (const float*)d_in[7];
    const float* ftr    = (const float*)d_in[8];
    const float* fti    = (const float*)d_in[9];
    float* out = (float*)d_out;
    float* ws  = (float*)d_ws;

    float* ex     = ws + WS_EX;
    float* cxp    = ws + WS_CXP;
    float* tabc   = ws + WS_TABC;
    float* tabs   = ws + WS_TABS;
    double* score = (double*)(ws + WS_SCORE);
    double* magm  = (double*)(ws + WS_MAGM);
    int* maskt    = (int*)(ws + WS_MASKT);
    int* idxt     = (int*)(ws + WS_IDXT);
    int* idxf     = (int*)(ws + WS_IDXF);
    int* maskf    = (int*)(ws + WS_MASKF);
    unsigned short* w1b   = (unsigned short*)(ws + WS_W1BF);
    unsigned short* w2b   = (unsigned short*)(ws + WS_W2BF);
    unsigned short* wemT  = (unsigned short*)(ws + WS_WEMT);
    unsigned short* maskb = (unsigned short*)(ws + WS_MASKB);
    unsigned short* hb    = (unsigned short*)(ws + WS_HBF);
    unsigned short* xtb   = (unsigned short*)(ws + WS_XTBF);
    unsigned short* itsel = (unsigned short*)(ws + WS_ITSEL);
    unsigned short* delta = (unsigned short*)(ws + WS_DELTA);
    unsigned short* xhl   = (unsigned short*)(ws + WS_XHL);
    unsigned short* thl   = (unsigned short*)(ws + WS_THL);
    unsigned short* whl   = (unsigned short*)(ws + WS_WHL);
    unsigned short* exthl = (unsigned short*)(ws + WS_EXTHL);

    // 1-2: fused init + fused conversions
    init0_k<<<8, 256, 0, stream>>>(maskt, maskf, tabc, tabs);
    convall_k<<<4672, 256, 0, stream>>>(tabc, tabs, W1t, W2t, W_emb, x,
                                        thl, w1b, w2b, wemT, xhl, whl);

    // 3: ex = x @ W_emb^T + b_emb + pe (split-bf16 MFMA; fused exT-hl scatter)
    gemm_k<4, 1><<<160, 256, 0, stream>>>(xhl, whl, b_emb, ex, exthl, 2048, DD, 1632, DD, 5);

    // 4: forward DFT (freq branch) || sliding score (temporal branch)
    fused_dft_score_k<<<682, 256, 0, stream>>>(thl, exthl, cxp, ex, score);

    // 5: topk_t || mag
    fused_topkt_mag_k<<<131, 512, 0, stream>>>(score, out + OFF_IDXT, idxt, maskt, cxp, magm);

    // 6: topk_f || build_masked
    fused_topkf_bm_k<<<2050, 512, 0, stream>>>(magm, out + OFF_IDXF, idxf, maskf,
                                               ex, ttok, maskt, maskb);

    // 7: h GEMM || sel_delta
    fused_h_seldelta_k<<<2848, 256, 0, stream>>>(maskb, w1b, b1t, hb,
                                                 tabc, tabs, idxf, cxp, ftr, fti, itsel, delta);

    // 8: sigmoid+select GEMM || corr GEMM (xt = ex + IT_sel @ delta)
    fused_sig_corr_k<<<320, 256, 0, stream>>>(hb, w2b, b2t, maskb, maskt,
                                              itsel, delta, ex, xtb);

    // 9: merged out_t / out_f: [maskb ; xtb] (contiguous 4096x288) @ wemT
    gemm_k<9, 1><<<576, 256, 0, stream>>>(maskb, wemT, nullptr, out, nullptr, 4096, CC, 288, CC, 9);
}

// Round 17
// 125.275 us; speedup vs baseline: 2.0348x; 1.0391x over previous
//
#include <hip/hip_runtime.h>

#define TDIM 1024
#define DD   263
#define CC   526
#define NFREQ 513
#define PACK 1026
#define KTOP 102

// ---------------- ws layout (float offsets) ----------------
static const size_t WS_EX     = 0;          // 538624 f32
static const size_t WS_W1BF   = 538624;     // 320x288 bf16
static const size_t WS_W2BF   = 584704;
static const size_t WS_WEMT   = 630784;     // 576x288 bf16 (ends 713728)
static const size_t WS_MASKB  = 1615872;    // 2048x288 bf16 = 294912 f
static const size_t WS_XTBF   = 1910784;    // 2048x288 bf16 (contiguous after MASKB)
static const size_t WS_HBF    = 2693120;    // 2048x288 bf16
static const size_t WS_CXP    = 3770368;    // f32 2*1026*263
static const size_t WS_EXTHL  = 4310044;    // [640][3072] bf16 = 983040 f
static const size_t WS_ITSEL  = 5360668;    // [2048][224] bf16 = 229376 f
static const size_t WS_DELTA  = 5901340;    // [640][224] bf16 = 71680 f
static const size_t WS_TABC   = 6411292;    // 1024
static const size_t WS_TABS   = 6412316;    // 1024
static const size_t WS_SCORE  = 6413340;    // double[2048]
static const size_t WS_MAGM   = 6417436;    // double[1026]
static const size_t WS_MASKT  = 6419488;    // int[2048]
static const size_t WS_IDXT   = 6421536;    // int[204]
static const size_t WS_IDXF   = 6421740;    // int[204]
static const size_t WS_MASKF  = 6421944;    // int[1026]
static const size_t WS_XHL    = 6422972;    // 2048x1632 bf16 = 1671168 f
static const size_t WS_THL    = 8094140;    // 1088x3072 bf16 = 1671168 f
static const size_t WS_WHL    = 9765308;    // 320x1632 bf16 = 261120 f
static const size_t WS_TOTAL  = 10740380;   // floats

static const size_t OFF_OUTT = 0;
static const size_t OFF_IDXT = 1077248;
static const size_t OFF_OUTF = 1077452;
static const size_t OFF_IDXF = 2154700;

typedef __bf16 bf16x8_t __attribute__((ext_vector_type(8)));
typedef float  f32x4_t  __attribute__((ext_vector_type(4)));

__device__ __forceinline__ unsigned short f2bf(float f) {
    unsigned int u = __float_as_uint(f);
    unsigned int r = (u + 0x7fffu + ((u >> 16) & 1u)) >> 16;
    return (unsigned short)r;
}
__device__ __forceinline__ float bf2f(unsigned short h) {
    return __uint_as_float(((unsigned int)h) << 16);
}

__device__ __forceinline__ float pe_val(int t, int d) {
    const float sc = (float)(-9.210340371976184 / 263.0);  // -ln(10000)/D
    int j = d >> 1;
    float div = expf((float)(2 * j) * sc);
    float a = (float)t * div;
    return (d & 1) ? cosf(a) : sinf(a);
}

// raw workgroup barrier: no implicit vmcnt(0) drain (prefetch stays in flight)
#define WG_FENCE()   asm volatile("" ::: "memory")
#define WG_BARRIER() { WG_FENCE(); __builtin_amdgcn_s_barrier(); WG_FENCE(); }

// ---------------- bf16 MFMA GEMM body (device fn; hw/nwg are LOCAL grid id/size) ----------------
// C = A @ Bt^T. A [>=M x SA] bf16, Bt [64*gy x SA] bf16. Tile 64x64, 4 waves 2x2, 256 thr.
// KU: K-elems staged per iteration = 32*KU (SA must divide). Same MFMA order for any KU.
// EPI: 0 ->f32; 1 bias+gelu->bf16; 4 bias+pe->f32 + exthl scatter (aux); 5 DFT scatter ->cxp;
//      7 corr: xtb=bf16(ex+v); 8 sigmoid+select (aux=maskt); 9 dual-out
template<int EPI, int KU>
__device__ __forceinline__ void gemm_body(int hw, int nwg,
                                          const unsigned short* __restrict__ A,
                                          const unsigned short* __restrict__ Bt,
                                          const float* __restrict__ bias,
                                          void* __restrict__ Cv,
                                          void* __restrict__ aux,
                                          int M, int N, int SA, int NC, int gy)
{
    __shared__ unsigned short As[64][32 * KU + 8];
    __shared__ unsigned short Bs[64][32 * KU + 8];
    // XCD-bijective chunked swizzle (m204)
    const int q = nwg >> 3, r = nwg & 7, xcd = hw & 7;
    const int logical = (xcd < r ? xcd * (q + 1) : r * (q + 1) + (xcd - r) * q) + (hw >> 3);
    const int row0 = (logical / gy) * 64, col0 = (logical % gy) * 64;
    if (EPI == 7) Bt += (size_t)(row0 >> 10) * 320 * SA;   // per-batch delta panel

    const int tid  = threadIdx.x;
    const int wid = tid >> 6, lane = tid & 63;
    const int wr = wid >> 1, wc = wid & 1;
    const int srow = tid >> 2, skoff = (tid & 3) * 8;
    const int fl = lane & 15, fh = lane >> 4;
    f32x4_t acc[2][2];
#pragma unroll
    for (int i = 0; i < 2; i++)
#pragma unroll
        for (int j = 0; j < 2; j++) acc[i][j] = (f32x4_t){0.f, 0.f, 0.f, 0.f};

    const int nk = SA / (32 * KU);
    const unsigned short* pa = A  + (size_t)(row0 + srow) * SA + skoff;
    const unsigned short* pb = Bt + (size_t)(col0 + srow) * SA + skoff;

    bf16x8_t qa[4][KU], qb[4][KU];
#pragma unroll
    for (int j = 0; j < 4; ++j) {
        if (j < nk) {
#pragma unroll
            for (int u = 0; u < KU; ++u) {
                qa[j][u] = *(const bf16x8_t*)(pa + (size_t)j * (32 * KU) + u * 32);
                qb[j][u] = *(const bf16x8_t*)(pb + (size_t)j * (32 * KU) + u * 32);
            }
        }
    }

    for (int itb = 0; itb < nk; itb += 4) {
#pragma unroll
        for (int j = 0; j < 4; ++j) {
            const int it = itb + j;
            if (it < nk) {
                if (it > 0) WG_BARRIER();
#pragma unroll
                for (int u = 0; u < KU; ++u) {
                    *(bf16x8_t*)(&As[srow][u * 32 + skoff]) = qa[j][u];
                    *(bf16x8_t*)(&Bs[srow][u * 32 + skoff]) = qb[j][u];
                }
                asm volatile("s_waitcnt lgkmcnt(0)" ::: "memory");
                WG_BARRIER();
#pragma unroll
                for (int u = 0; u < KU; ++u) {
                    bf16x8_t fa0 = *(const bf16x8_t*)(&As[wr * 32 + fl][u * 32 + fh * 8]);
                    bf16x8_t fa1 = *(const bf16x8_t*)(&As[wr * 32 + 16 + fl][u * 32 + fh * 8]);
                    bf16x8_t fb0 = *(const bf16x8_t*)(&Bs[wc * 32 + fl][u * 32 + fh * 8]);
                    bf16x8_t fb1 = *(const bf16x8_t*)(&Bs[wc * 32 + 16 + fl][u * 32 + fh * 8]);
                    acc[0][0] = __builtin_amdgcn_mfma_f32_16x16x32_bf16(fa0, fb0, acc[0][0], 0, 0, 0);
                    acc[0][1] = __builtin_amdgcn_mfma_f32_16x16x32_bf16(fa0, fb1, acc[0][1], 0, 0, 0);
                    acc[1][0] = __builtin_amdgcn_mfma_f32_16x16x32_bf16(fa1, fb0, acc[1][0], 0, 0, 0);
                    acc[1][1] = __builtin_amdgcn_mfma_f32_16x16x32_bf16(fa1, fb1, acc[1][1], 0, 0, 0);
                }
                if (it + 4 < nk) {
#pragma unroll
                    for (int u = 0; u < KU; ++u) {
                        qa[j][u] = *(const bf16x8_t*)(pa + (size_t)(it + 4) * (32 * KU) + u * 32);
                        qb[j][u] = *(const bf16x8_t*)(pb + (size_t)(it + 4) * (32 * KU) + u * 32);
                    }
                }
            }
        }
    }

#pragma unroll
    for (int fi = 0; fi < 2; fi++)
#pragma unroll
        for (int fj = 0; fj < 2; fj++)
#pragma unroll
            for (int rr = 0; rr < 4; rr++) {
                int m = row0 + wr * 32 + fi * 16 + fh * 4 + rr;
                int n = col0 + wc * 32 + fj * 16 + fl;
                if (m >= M) continue;
                float v = acc[fi][fj][rr];
                if (EPI == 0) {
                    if (n < N) ((float*)Cv)[(size_t)m * NC + n] = v;
                } else if (EPI == 1) {
                    if (n < NC) {
                        float o = 0.0f;
                        if (n < N) { o = v + bias[n]; o = 0.5f * o * (1.0f + erff(o * 0.70710678118654752f)); }
                        ((unsigned short*)Cv)[(size_t)m * NC + n] = f2bf(o);
                    }
                } else if (EPI == 4) {
                    if (n < N) {
                        float o = v + bias[n] + pe_val(m & (TDIM - 1), n);
                        ((float*)Cv)[(size_t)m * NC + n] = o;
                        unsigned short hi = f2bf(o);
                        unsigned short lo = f2bf(o - bf2f(hi));
                        size_t b2 = ((size_t)(m >> 10) * 320 + n) * 3072 + (m & 1023);
                        unsigned short* xh = (unsigned short*)aux;
                        xh[b2] = hi; xh[b2 + 1024] = lo; xh[b2 + 2048] = hi;
                    }
                } else if (EPI == 5) {
                    int b = n / 320, col = n - b * 320;
                    if (col < DD) ((float*)Cv)[((size_t)b * PACK + m) * DD + col] = v;
                } else if (EPI == 7) {
                    if (n < 288) {
                        unsigned short o = 0;
                        if (n < DD) o = f2bf(bias[(size_t)m * DD + n] + v);
                        ((unsigned short*)Cv)[(size_t)m * 288 + n] = o;
                    }
                } else if (EPI == 8) {
                    const int* mt = (const int*)aux;
                    if (n < 288 && !mt[m]) {
                        unsigned short o = 0;
                        if (n < DD) {
                            float s = v + bias[n];
                            o = f2bf(1.0f / (1.0f + expf(-s)));
                        }
                        ((unsigned short*)Cv)[(size_t)m * 288 + n] = o;
                    }
                } else {  // EPI 9: dual output
                    if (n < CC) {
                        size_t off = (m < 2048) ? (size_t)m * CC + n
                                                : (size_t)OFF_OUTF + (size_t)(m - 2048) * CC + n;
                        ((float*)Cv)[off] = v;
                    }
                }
            }
}

template<int EPI, int KU>
__global__ __launch_bounds__(256) void gemm_k(const unsigned short* __restrict__ A,
                                              const unsigned short* __restrict__ Bt,
                                              const float* __restrict__ bias,
                                              void* __restrict__ Cv, void* __restrict__ aux,
                                              int M, int N, int SA, int NC, int gy)
{
    gemm_body<EPI, KU>(blockIdx.x, gridDim.x, A, Bt, bias, Cv, aux, M, N, SA, NC, gy);
}

// ---------------- wave bodies ----------------
__device__ __forceinline__ void score_wave(int ib, const float* __restrict__ ex,
                                           double* __restrict__ score) {
    const int t = ib & (TDIM - 1);
    const int lane = threadIdx.x & 63;
    double ms = 0.0, vs = 0.0;
    if (t >= 24) {
        const float* base = ex + (size_t)(ib - 24) * DD;
        for (int d = lane; d < DD; d += 64) {
            float s1 = 0.0f, s2 = 0.0f;
#pragma unroll
            for (int r = 0; r < 25; r++) {
                float v = base[(size_t)r * DD + d];
                s1 += v;
                s2 += v * v;
            }
            float m1 = s1 * (1.0f / 25.0f);
            float var = s2 * (1.0f / 25.0f) - m1 * m1;
            ms += (double)m1;
            vs += (double)var;
        }
    } else {
        const int nt = t + 1;
        const float cnt = (float)nt;
        const float* base = ex + (size_t)(ib - t) * DD;
        for (int d = lane; d < DD; d += 64) {
            float s1 = 0.0f, s2 = 0.0f;
            for (int r = 0; r < nt; r++) {
                float v = base[(size_t)r * DD + d];
                s1 += v;
                s2 += v * v;
            }
            float m1 = s1 / cnt;
            float var = s2 / cnt - m1 * m1;
            ms += (double)m1;
            vs += (double)var;
        }
    }
#pragma unroll
    for (int off = 32; off; off >>= 1) { ms += __shfl_xor(ms, off); vs += __shfl_xor(vs, off); }
    if (lane == 0) score[ib] = vs / (ms + (double)1e-6f);
}

__device__ __forceinline__ void mag_wave(int ib, const float* __restrict__ cxp,
                                         double* __restrict__ magm) {
    int b = ib / NFREQ, k = ib % NFREQ;
    int lane = threadIdx.x & 63;
    const float* re = cxp + ((size_t)b * PACK + k) * DD;
    const float* im = cxp + ((size_t)b * PACK + NFREQ + k) * DD;
    double acc = 0.0;
    for (int d = lane; d < DD; d += 64) {
        float r = re[d], i = im[d];
        acc += (double)sqrtf(r * r + i * i);
    }
#pragma unroll
    for (int off = 32; off; off >>= 1) acc += __shfl_xor(acc, off);
    if (lane == 0) magm[ib] = acc / (double)DD;
}

// topk body (512 threads; exact pair enumeration)
__device__ __forceinline__ void topk_body(int b, const double* __restrict__ score,
                                          int n, int kcount,
                                          float* __restrict__ out_f, int* __restrict__ out_i,
                                          int* __restrict__ mask) {
    __shared__ double sv[1024];
    __shared__ int    si[1024];
    const int tid = threadIdx.x;
    const double* s = score + (size_t)b * n;
    for (int i = tid; i < 1024; i += 512) {
        sv[i] = (i < n) ? s[i] : -1.0e300;
        si[i] = i;
    }
    __syncthreads();
    for (int k = 2; k <= 1024; k <<= 1) {
        for (int j = k >> 1; j > 0; j >>= 1) {
            int t = ((tid & ~(j - 1)) << 1) | (tid & (j - 1));
            int l = t | j;
            double v0 = sv[t], v1 = sv[l];
            int i0 = si[t], i1 = si[l];
            bool g = (v0 > v1) || (v0 == v1 && i0 < i1);
            bool wrong = ((t & k) == 0) ? !g : g;
            if (wrong) {
                sv[t] = v1; sv[l] = v0;
                si[t] = i1; si[l] = i0;
            }
            __syncthreads();
        }
    }
    for (int t = tid; t < kcount; t += 512) {
        int bi = si[t];
        out_f[(size_t)b * kcount + t] = (float)bi;
        out_i[b * kcount + t] = bi;
        mask[b * n + bi] = 1;
    }
}

__device__ __forceinline__ void build_masked_body(int bt, const float* __restrict__ ex,
                                                  const float* __restrict__ ttok,
                                                  const int* __restrict__ maskt,
                                                  unsigned short* __restrict__ mb) {
    int d = threadIdx.x;
    if (d >= 288) return;
    float v = 0.0f;
    if (d < DD) v = maskt[bt] ? ttok[d] : ex[(size_t)bt * DD + d];
    mb[(size_t)bt * 288 + d] = f2bf(v);
}

__device__ __forceinline__ void sel_delta_body(int blk,
                                               const float* __restrict__ tabc, const float* __restrict__ tabs,
                                               const int* __restrict__ idxf, const float* __restrict__ cxp,
                                               const float* __restrict__ ftr, const float* __restrict__ fti,
                                               unsigned short* __restrict__ itsel,
                                               unsigned short* __restrict__ delta) {
    if (blk < 2048) {
        int b = blk >> 10, t = blk & 1023;
        unsigned short* dst = itsel + (size_t)blk * 224;
        for (int j = threadIdx.x; j < 224; j += 256) {
            float v = 0.0f;
            if (j < KTOP) {
                int k = idxf[b * KTOP + j];
                float w = (k == 0 || k == 512) ? 1.0f : 2.0f;
                v = (w * (1.0f / 1024.0f)) * tabc[(k * t) & 1023];
            } else if (j >= 112 && j < 112 + KTOP) {
                int k = idxf[b * KTOP + j - 112];
                v = (k == 0 || k == 512) ? 0.0f : (-2.0f / 1024.0f) * tabs[(k * t) & 1023];
            }
            dst[j] = f2bf(v);
        }
    } else {
        int idx = blk - 2048;
        int b = idx / 320, d = idx - (idx / 320) * 320;
        unsigned short* dst = delta + (size_t)idx * 224;
        for (int j = threadIdx.x; j < 224; j += 256) {
            float v = 0.0f;
            if (d < DD) {
                if (j < KTOP) {
                    int k = idxf[b * KTOP + j];
                    v = ftr[d] - cxp[((size_t)b * PACK + k) * DD + d];
                } else if (j >= 112 && j < 112 + KTOP) {
                    int k = idxf[b * KTOP + j - 112];
                    v = fti[d] - cxp[((size_t)b * PACK + NFREQ + k) * DD + d];
                }
            }
            dst[j] = f2bf(v);
        }
    }
}

// ---------------- fused kernels (block-range dispatch; independent nodes overlap) ----------------
__global__ __launch_bounds__(256) void fused_dft_score_k(const unsigned short* __restrict__ thl,
                                                         const unsigned short* __restrict__ exthl,
                                                         float* __restrict__ cxp,
                                                         const float* __restrict__ ex,
                                                         double* __restrict__ score)
{
    if (blockIdx.x < 170) {
        gemm_body<5, 4>(blockIdx.x, 170, thl, exthl, nullptr, cxp, nullptr, PACK, 640, 3072, 0, 10);
    } else {
        int ib = (int)(blockIdx.x - 170) * 4 + (threadIdx.x >> 6);
        score_wave(ib, ex, score);
    }
}

__global__ __launch_bounds__(512) void fused_topkt_mag_k(const double* __restrict__ score,
                                                         float* __restrict__ outf, int* __restrict__ idxt,
                                                         int* __restrict__ maskt,
                                                         const float* __restrict__ cxp,
                                                         double* __restrict__ magm)
{
    if (blockIdx.x < 2) {
        topk_body(blockIdx.x, score, TDIM, KTOP, outf, idxt, maskt);
    } else {
        int ib = (int)(blockIdx.x - 2) * 8 + (threadIdx.x >> 6);
        if (ib < 2 * NFREQ) mag_wave(ib, cxp, magm);
    }
}

__global__ __launch_bounds__(512) void fused_topkf_bm_k(const double* __restrict__ magm,
                                                        float* __restrict__ outf, int* __restrict__ idxf,
                                                        int* __restrict__ maskf,
                                                        const float* __restrict__ ex,
                                                        const float* __restrict__ ttok,
                                                        const int* __restrict__ maskt,
                                                        unsigned short* __restrict__ mb)
{
    if (blockIdx.x < 2) {
        topk_body(blockIdx.x, magm, NFREQ, KTOP, outf, idxf, maskf);
    } else {
        build_masked_body(blockIdx.x - 2, ex, ttok, maskt, mb);
    }
}

__global__ __launch_bounds__(256) void fused_h_seldelta_k(const unsigned short* __restrict__ maskb,
                                                          const unsigned short* __restrict__ w1b,
                                                          const float* __restrict__ b1t,
                                                          unsigned short* __restrict__ hb,
                                                          const float* __restrict__ tabc,
                                                          const float* __restrict__ tabs,
                                                          const int* __restrict__ idxf,
                                                          const float* __restrict__ cxp,
                                                          const float* __restrict__ ftr,
                                                          const float* __restrict__ fti,
                                                          unsigned short* __restrict__ itsel,
                                                          unsigned short* __restrict__ delta)
{
    if (blockIdx.x < 160) {
        gemm_body<1, 3>(blockIdx.x, 160, maskb, w1b, b1t, hb, nullptr, 2048, DD, 288, 288, 5);
    } else {
        sel_delta_body(blockIdx.x - 160, tabc, tabs, idxf, cxp, ftr, fti, itsel, delta);
    }
}

__global__ __launch_bounds__(256) void fused_sig_corr_k(const unsigned short* __restrict__ hb,
                                                        const unsigned short* __restrict__ w2b,
                                                        const float* __restrict__ b2t,
                                                        unsigned short* __restrict__ maskb,
                                                        const int* __restrict__ maskt,
                                                        const unsigned short* __restrict__ itsel,
                                                        const unsigned short* __restrict__ delta,
                                                        const float* __restrict__ ex,
                                                        unsigned short* __restrict__ xtb)
{
    if (blockIdx.x < 160) {
        gemm_body<8, 3>(blockIdx.x, 160, hb, w2b, b2t, maskb, (void*)maskt, 2048, DD, 288, 288, 5);
    } else {
        gemm_body<7, 1>(blockIdx.x - 160, 160, itsel, delta, ex, xtb, nullptr, 2048, 320, 224, 288, 5);
    }
}

// ---------------- fused init: masks + sincos tables ----------------
__global__ void init0_k(int* maskt, int* maskf, float* tabc, float* tabs) {
    int i = blockIdx.x * 256 + threadIdx.x;
    if (i < 2 * TDIM) maskt[i] = 0;
    if (i < PACK) maskf[i] = 0;
    if (i < 1024) {
        double ang = (double)i * (3.14159265358979323846 * 2.0 / 1024.0);
        tabc[i] = (float)cos(ang);
        tabs[i] = (float)sin(ang);
    }
}

// ---------------- fused conversions: twid_hl + weights + x_hl + w_hl ----------------
__global__ void convall_k(const float* __restrict__ tabc, const float* __restrict__ tabs,
                          const float* __restrict__ W1t, const float* __restrict__ W2t,
                          const float* __restrict__ W_emb, const float* __restrict__ x,
                          unsigned short* __restrict__ thl,
                          unsigned short* __restrict__ w1b, unsigned short* __restrict__ w2b,
                          unsigned short* __restrict__ wemT,
                          unsigned short* __restrict__ xhl, unsigned short* __restrict__ whl)
{
    int blk = blockIdx.x;
    if (blk < 1088) {
        int row = blk;
        unsigned short* dst = thl + (size_t)row * 3072;
        for (int c = threadIdx.x; c < 3072; c += 256) {
            int seg = c >> 10, t = c & 1023;
            float v = 0.0f;
            if (row < PACK) v = (row < NFREQ) ? tabc[(row * t) & 1023] : -tabs[((row - NFREQ) * t) & 1023];
            unsigned short hi = f2bf(v);
            dst[c] = (seg < 2) ? hi : f2bf(v - bf2f(hi));
        }
    } else if (blk < 2304) {
        int r = blk - 1088;
        if (r < 640) {
            int rr = r & 319;
            const float* src = (r < 320) ? W1t : W2t;
            unsigned short* dst = (r < 320) ? w1b : w2b;
            for (int c = threadIdx.x; c < 288; c += 256) {
                float v = (rr < DD && c < DD) ? src[(size_t)rr * DD + c] : 0.0f;
                dst[(size_t)rr * 288 + c] = f2bf(v);
            }
        } else {
            int rr = r - 640;  // 0..575
            for (int c = threadIdx.x; c < 288; c += 256) {
                float v = (rr < CC && c < DD) ? W_emb[(size_t)c * CC + rr] : 0.0f;
                wemT[(size_t)rr * 288 + c] = f2bf(v);
            }
        }
    } else if (blk < 4352) {
        int r = blk - 2304;
        const float* src = x + (size_t)r * CC;
        unsigned short* dst = xhl + (size_t)r * 1632;
        for (int c = threadIdx.x; c < 1632; c += 256) {
            int seg = c / 544, cc = c - seg * 544;
            float v = (cc < CC) ? src[cc] : 0.0f;
            unsigned short hi = f2bf(v);
            dst[c] = (seg < 2) ? hi : f2bf(v - bf2f(hi));
        }
    } else {
        int n = blk - 4352;
        unsigned short* dst = whl + (size_t)n * 1632;
        for (int c = threadIdx.x; c < 1632; c += 256) {
            int seg = c / 544, cc = c - seg * 544;
            float v = (n < DD && cc < CC) ? W_emb[(size_t)n * CC + cc] : 0.0f;
            unsigned short hi = f2bf(v);
            dst[c] = (seg == 1) ? f2bf(v - bf2f(hi)) : hi;
        }
    }
}

// ---------------- launch ----------------
extern "C" void kernel_launch(void* const* d_in, const int* in_sizes, int n_in,
                              void* d_out, int out_size, void* d_ws, size_t ws_size,
                              hipStream_t stream) {
    (void)in_sizes; (void)n_in; (void)out_size; (void)ws_size;
    const float* x      = (const float*)d_in[0];
    const float* W_emb  = (const float*)d_in[1];
    const float* b_emb  = (const float*)d_in[2];
    const float* ttok   = (const float*)d_in[3];
    const float* W1t    = (const float*)d_in[4];
    const float* b1t    = (const float*)d_in[5];
    const float* W2t    = (const float*)d_in[6];
    const float* b2t    = (const float*)d_in[7];
    const float* ftr    = (const float*)d_in[8];
    const float* fti    = (const float*)d_in[9];
    float* out = (float*)d_out;
    float* ws  = (float*)d_ws;

    float* ex     = ws + WS_EX;
    float* cxp    = ws + WS_CXP;
    float* tabc   = ws + WS_TABC;
    float* tabs   = ws + WS_TABS;
    double* score = (double*)(ws + WS_SCORE);
    double* magm  = (double*)(ws + WS_MAGM);
    int* maskt    = (int*)(ws + WS_MASKT);
    int* idxt     = (int*)(ws + WS_IDXT);
    int* idxf     = (int*)(ws + WS_IDXF);
    int* maskf    = (int*)(ws + WS_MASKF);
    unsigned short* w1b   = (unsigned short*)(ws + WS_W1BF);
    unsigned short* w2b   = (unsigned short*)(ws + WS_W2BF);
    unsigned short* wemT  = (unsigned short*)(ws + WS_WEMT);
    unsigned short* maskb = (unsigned short*)(ws + WS_MASKB);
    unsigned short* hb    = (unsigned short*)(ws + WS_HBF);
    unsigned short* xtb   = (unsigned short*)(ws + WS_XTBF);
    unsigned short* itsel = (unsigned short*)(ws + WS_ITSEL);
    unsigned short* delta = (unsigned short*)(ws + WS_DELTA);
    unsigned short* xhl   = (unsigned short*)(ws + WS_XHL);
    unsigned short* thl   = (unsigned short*)(ws + WS_THL);
    unsigned short* whl   = (unsigned short*)(ws + WS_WHL);
    unsigned short* exthl = (unsigned short*)(ws + WS_EXTHL);

    // 1-2: fused init + fused conversions
    init0_k<<<8, 256, 0, stream>>>(maskt, maskf, tabc, tabs);
    convall_k<<<4672, 256, 0, stream>>>(tabc, tabs, W1t, W2t, W_emb, x,
                                        thl, w1b, w2b, wemT, xhl, whl);

    // 3: ex = x @ W_emb^T + b_emb + pe (split-bf16 MFMA, KU=3; fused exT-hl scatter)
    gemm_k<4, 3><<<160, 256, 0, stream>>>(xhl, whl, b_emb, ex, exthl, 2048, DD, 1632, DD, 5);

    // 4: forward DFT (KU=4) || sliding score
    fused_dft_score_k<<<682, 256, 0, stream>>>(thl, exthl, cxp, ex, score);

    // 5: topk_t || mag
    fused_topkt_mag_k<<<131, 512, 0, stream>>>(score, out + OFF_IDXT, idxt, maskt, cxp, magm);

    // 6: topk_f || build_masked
    fused_topkf_bm_k<<<2050, 512, 0, stream>>>(magm, out + OFF_IDXF, idxf, maskf,
                                               ex, ttok, maskt, maskb);

    // 7: h GEMM (KU=3) || sel_delta
    fused_h_seldelta_k<<<2848, 256, 0, stream>>>(maskb, w1b, b1t, hb,
                                                 tabc, tabs, idxf, cxp, ftr, fti, itsel, delta);

    // 8: sigmoid+select GEMM (KU=3) || corr GEMM
    fused_sig_corr_k<<<320, 256, 0, stream>>>(hb, w2b, b2t, maskb, maskt,
                                              itsel, delta, ex, xtb);

    // 9: merged out_t / out_f (KU=3): [maskb ; xtb] (contiguous 4096x288) @ wemT
    gemm_k<9, 3><<<576, 256, 0, stream>>>(maskb, wemT, nullptr, out, nullptr, 4096, CC, 288, CC, 9);
}

// Round 18
// 114.423 us; speedup vs baseline: 2.2278x; 1.0948x over previous
//
#include <hip/hip_runtime.h>

#define TDIM 1024
#define DD   263
#define CC   526
#define NFREQ 513
#define PACK 1026
#define KTOP 102

// ---------------- ws layout (float offsets) ----------------
static const size_t WS_EX     = 0;          // 538624 f32
static const size_t WS_W1BF   = 538624;     // 320x288 bf16
static const size_t WS_W2BF   = 584704;
static const size_t WS_WEMT   = 630784;     // 576x288 bf16 (ends 713728)
static const size_t WS_MASKB  = 1615872;    // 2048x288 bf16 = 294912 f
static const size_t WS_XTBF   = 1910784;    // 2048x288 bf16 (contiguous after MASKB)
static const size_t WS_HBF    = 2693120;    // 2048x288 bf16
static const size_t WS_CXP    = 3770368;    // f32 2*1026*263
static const size_t WS_EXTHL  = 4310044;    // [640][3072] bf16 = 983040 f
static const size_t WS_ITSEL  = 5360668;    // [2048][224] bf16 = 229376 f
static const size_t WS_DELTA  = 5901340;    // [640][224] bf16 = 71680 f
static const size_t WS_TABC   = 6411292;    // 1024
static const size_t WS_TABS   = 6412316;    // 1024
static const size_t WS_SCORE  = 6413340;    // double[2048]
static const size_t WS_MAGM   = 6417436;    // double[1026]
static const size_t WS_MASKT  = 6419488;    // int[2048]
static const size_t WS_IDXT   = 6421536;    // int[204]
static const size_t WS_IDXF   = 6421740;    // int[204]
static const size_t WS_MASKF  = 6421944;    // int[1026]
static const size_t WS_XHL    = 6422972;    // 2048x1632 bf16 = 1671168 f
static const size_t WS_THL    = 8094140;    // 1088x3072 bf16 = 1671168 f
static const size_t WS_WHL    = 9765308;    // 320x1632 bf16 = 261120 f
static const size_t WS_TOTAL  = 10740380;   // floats

static const size_t OFF_OUTT = 0;
static const size_t OFF_IDXT = 1077248;
static const size_t OFF_OUTF = 1077452;
static const size_t OFF_IDXF = 2154700;

typedef __bf16 bf16x8_t __attribute__((ext_vector_type(8)));
typedef float  f32x4_t  __attribute__((ext_vector_type(4)));

__device__ __forceinline__ unsigned short f2bf(float f) {
    unsigned int u = __float_as_uint(f);
    unsigned int r = (u + 0x7fffu + ((u >> 16) & 1u)) >> 16;
    return (unsigned short)r;
}
__device__ __forceinline__ float bf2f(unsigned short h) {
    return __uint_as_float(((unsigned int)h) << 16);
}

__device__ __forceinline__ float pe_val(int t, int d) {
    const float sc = (float)(-9.210340371976184 / 263.0);  // -ln(10000)/D
    int j = d >> 1;
    float div = expf((float)(2 * j) * sc);
    float a = (float)t * div;
    return (d & 1) ? cosf(a) : sinf(a);
}

// raw workgroup barrier: no implicit vmcnt(0) drain (prefetch stays in flight)
#define WG_FENCE()   asm volatile("" ::: "memory")
#define WG_BARRIER() { WG_FENCE(); __builtin_amdgcn_s_barrier(); WG_FENCE(); }
// wave-local LDS sync: all this wave's LDS ops done; no cross-wave barrier (rule #18: pin with sched_barrier)
#define WAVE_LDS_SYNC() { asm volatile("s_waitcnt lgkmcnt(0)" ::: "memory"); __builtin_amdgcn_sched_barrier(0); }

// ---------------- bf16 MFMA GEMM body (device fn; hw/nwg are LOCAL grid id/size) ----------------
// C = A @ Bt^T. A [>=M x SA] bf16, Bt [64*gy x SA] bf16. Tile 64x64, 4 waves 2x2, 256 thr.
// KU: K-elems staged per iteration = 32*KU (SA must divide). Same MFMA order for any KU.
// EPI: 0 ->f32; 1 bias+gelu->bf16; 4 bias+pe->f32 + exthl scatter (aux); 5 DFT scatter ->cxp;
//      7 corr: xtb=bf16(ex+v); 8 sigmoid+select (aux=maskt); 9 dual-out
template<int EPI, int KU>
__device__ __forceinline__ void gemm_body(int hw, int nwg,
                                          const unsigned short* __restrict__ A,
                                          const unsigned short* __restrict__ Bt,
                                          const float* __restrict__ bias,
                                          void* __restrict__ Cv,
                                          void* __restrict__ aux,
                                          int M, int N, int SA, int NC, int gy)
{
    __shared__ unsigned short As[64][32 * KU + 8];
    __shared__ unsigned short Bs[64][32 * KU + 8];
    // XCD-bijective chunked swizzle (m204)
    const int q = nwg >> 3, r = nwg & 7, xcd = hw & 7;
    const int logical = (xcd < r ? xcd * (q + 1) : r * (q + 1) + (xcd - r) * q) + (hw >> 3);
    const int row0 = (logical / gy) * 64, col0 = (logical % gy) * 64;
    if (EPI == 7) Bt += (size_t)(row0 >> 10) * 320 * SA;   // per-batch delta panel

    const int tid  = threadIdx.x;
    const int wid = tid >> 6, lane = tid & 63;
    const int wr = wid >> 1, wc = wid & 1;
    const int srow = tid >> 2, skoff = (tid & 3) * 8;
    const int fl = lane & 15, fh = lane >> 4;
    f32x4_t acc[2][2];
#pragma unroll
    for (int i = 0; i < 2; i++)
#pragma unroll
        for (int j = 0; j < 2; j++) acc[i][j] = (f32x4_t){0.f, 0.f, 0.f, 0.f};

    const int nk = SA / (32 * KU);
    const unsigned short* pa = A  + (size_t)(row0 + srow) * SA + skoff;
    const unsigned short* pb = Bt + (size_t)(col0 + srow) * SA + skoff;

    bf16x8_t qa[4][KU], qb[4][KU];
#pragma unroll
    for (int j = 0; j < 4; ++j) {
        if (j < nk) {
#pragma unroll
            for (int u = 0; u < KU; ++u) {
                qa[j][u] = *(const bf16x8_t*)(pa + (size_t)j * (32 * KU) + u * 32);
                qb[j][u] = *(const bf16x8_t*)(pb + (size_t)j * (32 * KU) + u * 32);
            }
        }
    }

    for (int itb = 0; itb < nk; itb += 4) {
#pragma unroll
        for (int j = 0; j < 4; ++j) {
            const int it = itb + j;
            if (it < nk) {
                if (it > 0) WG_BARRIER();
#pragma unroll
                for (int u = 0; u < KU; ++u) {
                    *(bf16x8_t*)(&As[srow][u * 32 + skoff]) = qa[j][u];
                    *(bf16x8_t*)(&Bs[srow][u * 32 + skoff]) = qb[j][u];
                }
                asm volatile("s_waitcnt lgkmcnt(0)" ::: "memory");
                WG_BARRIER();
#pragma unroll
                for (int u = 0; u < KU; ++u) {
                    bf16x8_t fa0 = *(const bf16x8_t*)(&As[wr * 32 + fl][u * 32 + fh * 8]);
                    bf16x8_t fa1 = *(const bf16x8_t*)(&As[wr * 32 + 16 + fl][u * 32 + fh * 8]);
                    bf16x8_t fb0 = *(const bf16x8_t*)(&Bs[wc * 32 + fl][u * 32 + fh * 8]);
                    bf16x8_t fb1 = *(const bf16x8_t*)(&Bs[wc * 32 + 16 + fl][u * 32 + fh * 8]);
                    acc[0][0] = __builtin_amdgcn_mfma_f32_16x16x32_bf16(fa0, fb0, acc[0][0], 0, 0, 0);
                    acc[0][1] = __builtin_amdgcn_mfma_f32_16x16x32_bf16(fa0, fb1, acc[0][1], 0, 0, 0);
                    acc[1][0] = __builtin_amdgcn_mfma_f32_16x16x32_bf16(fa1, fb0, acc[1][0], 0, 0, 0);
                    acc[1][1] = __builtin_amdgcn_mfma_f32_16x16x32_bf16(fa1, fb1, acc[1][1], 0, 0, 0);
                }
                if (it + 4 < nk) {
#pragma unroll
                    for (int u = 0; u < KU; ++u) {
                        qa[j][u] = *(const bf16x8_t*)(pa + (size_t)(it + 4) * (32 * KU) + u * 32);
                        qb[j][u] = *(const bf16x8_t*)(pb + (size_t)(it + 4) * (32 * KU) + u * 32);
                    }
                }
            }
        }
    }

#pragma unroll
    for (int fi = 0; fi < 2; fi++)
#pragma unroll
        for (int fj = 0; fj < 2; fj++)
#pragma unroll
            for (int rr = 0; rr < 4; rr++) {
                int m = row0 + wr * 32 + fi * 16 + fh * 4 + rr;
                int n = col0 + wc * 32 + fj * 16 + fl;
                if (m >= M) continue;
                float v = acc[fi][fj][rr];
                if (EPI == 0) {
                    if (n < N) ((float*)Cv)[(size_t)m * NC + n] = v;
                } else if (EPI == 1) {
                    if (n < NC) {
                        float o = 0.0f;
                        if (n < N) { o = v + bias[n]; o = 0.5f * o * (1.0f + erff(o * 0.70710678118654752f)); }
                        ((unsigned short*)Cv)[(size_t)m * NC + n] = f2bf(o);
                    }
                } else if (EPI == 4) {
                    if (n < N) {
                        float o = v + bias[n] + pe_val(m & (TDIM - 1), n);
                        ((float*)Cv)[(size_t)m * NC + n] = o;
                        unsigned short hi = f2bf(o);
                        unsigned short lo = f2bf(o - bf2f(hi));
                        size_t b2 = ((size_t)(m >> 10) * 320 + n) * 3072 + (m & 1023);
                        unsigned short* xh = (unsigned short*)aux;
                        xh[b2] = hi; xh[b2 + 1024] = lo; xh[b2 + 2048] = hi;
                    }
                } else if (EPI == 5) {
                    int b = n / 320, col = n - b * 320;
                    if (col < DD) ((float*)Cv)[((size_t)b * PACK + m) * DD + col] = v;
                } else if (EPI == 7) {
                    if (n < 288) {
                        unsigned short o = 0;
                        if (n < DD) o = f2bf(bias[(size_t)m * DD + n] + v);
                        ((unsigned short*)Cv)[(size_t)m * 288 + n] = o;
                    }
                } else if (EPI == 8) {
                    const int* mt = (const int*)aux;
                    if (n < 288 && !mt[m]) {
                        unsigned short o = 0;
                        if (n < DD) {
                            float s = v + bias[n];
                            o = f2bf(1.0f / (1.0f + expf(-s)));
                        }
                        ((unsigned short*)Cv)[(size_t)m * 288 + n] = o;
                    }
                } else {  // EPI 9: dual output
                    if (n < CC) {
                        size_t off = (m < 2048) ? (size_t)m * CC + n
                                                : (size_t)OFF_OUTF + (size_t)(m - 2048) * CC + n;
                        ((float*)Cv)[off] = v;
                    }
                }
            }
}

template<int EPI, int KU>
__global__ __launch_bounds__(256) void gemm_k(const unsigned short* __restrict__ A,
                                              const unsigned short* __restrict__ Bt,
                                              const float* __restrict__ bias,
                                              void* __restrict__ Cv, void* __restrict__ aux,
                                              int M, int N, int SA, int NC, int gy)
{
    gemm_body<EPI, KU>(blockIdx.x, gridDim.x, A, Bt, bias, Cv, aux, M, N, SA, NC, gy);
}

// ---------------- wave bodies ----------------
__device__ __forceinline__ void score_wave(int ib, const float* __restrict__ ex,
                                           double* __restrict__ score) {
    const int t = ib & (TDIM - 1);
    const int lane = threadIdx.x & 63;
    double ms = 0.0, vs = 0.0;
    if (t >= 24) {
        const float* base = ex + (size_t)(ib - 24) * DD;
        for (int d = lane; d < DD; d += 64) {
            float s1 = 0.0f, s2 = 0.0f;
#pragma unroll
            for (int r = 0; r < 25; r++) {
                float v = base[(size_t)r * DD + d];
                s1 += v;
                s2 += v * v;
            }
            float m1 = s1 * (1.0f / 25.0f);
            float var = s2 * (1.0f / 25.0f) - m1 * m1;
            ms += (double)m1;
            vs += (double)var;
        }
    } else {
        const int nt = t + 1;
        const float cnt = (float)nt;
        const float* base = ex + (size_t)(ib - t) * DD;
        for (int d = lane; d < DD; d += 64) {
            float s1 = 0.0f, s2 = 0.0f;
            for (int r = 0; r < nt; r++) {
                float v = base[(size_t)r * DD + d];
                s1 += v;
                s2 += v * v;
            }
            float m1 = s1 / cnt;
            float var = s2 / cnt - m1 * m1;
            ms += (double)m1;
            vs += (double)var;
        }
    }
#pragma unroll
    for (int off = 32; off; off >>= 1) { ms += __shfl_xor(ms, off); vs += __shfl_xor(vs, off); }
    if (lane == 0) score[ib] = vs / (ms + (double)1e-6f);
}

__device__ __forceinline__ void mag_wave(int ib, const float* __restrict__ cxp,
                                         double* __restrict__ magm) {
    int b = ib / NFREQ, k = ib % NFREQ;
    int lane = threadIdx.x & 63;
    const float* re = cxp + ((size_t)b * PACK + k) * DD;
    const float* im = cxp + ((size_t)b * PACK + NFREQ + k) * DD;
    double acc = 0.0;
    for (int d = lane; d < DD; d += 64) {
        float r = re[d], i = im[d];
        acc += (double)sqrtf(r * r + i * i);
    }
#pragma unroll
    for (int off = 32; off; off >>= 1) acc += __shfl_xor(acc, off);
    if (lane == 0) magm[ib] = acc / (double)DD;
}

// topk body (512 threads; exact pair enumeration; wave-local stages skip s_barrier).
// For j<=64 each wave's pairs live in its own 128-elem chunk (t = insert-0-bit keeps
// tid-wave -> chunk mapping), so only j>=128 stages (and transitions into them) need
// a full barrier. Data movement & comparator identical to the all-barrier version.
__device__ __forceinline__ void topk_body(int b, const double* __restrict__ score,
                                          int n, int kcount,
                                          float* __restrict__ out_f, int* __restrict__ out_i,
                                          int* __restrict__ mask) {
    __shared__ double sv[1024];
    __shared__ int    si[1024];
    const int tid = threadIdx.x;
    const double* s = score + (size_t)b * n;
    for (int i = tid; i < 1024; i += 512) {
        sv[i] = (i < n) ? s[i] : -1.0e300;
        si[i] = i;
    }
    __syncthreads();
    for (int k = 2; k <= 1024; k <<= 1) {
        for (int j = k >> 1; j > 0; j >>= 1) {
            int t = ((tid & ~(j - 1)) << 1) | (tid & (j - 1));
            int l = t | j;
            double v0 = sv[t], v1 = sv[l];
            int i0 = si[t], i1 = si[l];
            bool g = (v0 > v1) || (v0 == v1 && i0 < i1);
            bool wrong = ((t & k) == 0) ? !g : g;
            if (wrong) {
                sv[t] = v1; sv[l] = v0;
                si[t] = i1; si[l] = i0;
            }
            int next_j = (j > 1) ? (j >> 1) : k;   // next stage's j (first j of next k == k)
            if (j >= 128 || next_j >= 128) __syncthreads();
            else WAVE_LDS_SYNC();
        }
    }
    __syncthreads();   // final visibility for output read (crosses wave chunks)
    for (int t = tid; t < kcount; t += 512) {
        int bi = si[t];
        out_f[(size_t)b * kcount + t] = (float)bi;
        out_i[b * kcount + t] = bi;
        mask[b * n + bi] = 1;
    }
}

__device__ __forceinline__ void build_masked_body(int bt, const float* __restrict__ ex,
                                                  const float* __restrict__ ttok,
                                                  const int* __restrict__ maskt,
                                                  unsigned short* __restrict__ mb) {
    int d = threadIdx.x;
    if (d >= 288) return;
    float v = 0.0f;
    if (d < DD) v = maskt[bt] ? ttok[d] : ex[(size_t)bt * DD + d];
    mb[(size_t)bt * 288 + d] = f2bf(v);
}

__device__ __forceinline__ void sel_delta_body(int blk,
                                               const float* __restrict__ tabc, const float* __restrict__ tabs,
                                               const int* __restrict__ idxf, const float* __restrict__ cxp,
                                               const float* __restrict__ ftr, const float* __restrict__ fti,
                                               unsigned short* __restrict__ itsel,
                                               unsigned short* __restrict__ delta) {
    if (blk < 2048) {
        int b = blk >> 10, t = blk & 1023;
        unsigned short* dst = itsel + (size_t)blk * 224;
        for (int j = threadIdx.x; j < 224; j += 256) {
            float v = 0.0f;
            if (j < KTOP) {
                int k = idxf[b * KTOP + j];
                float w = (k == 0 || k == 512) ? 1.0f : 2.0f;
                v = (w * (1.0f / 1024.0f)) * tabc[(k * t) & 1023];
            } else if (j >= 112 && j < 112 + KTOP) {
                int k = idxf[b * KTOP + j - 112];
                v = (k == 0 || k == 512) ? 0.0f : (-2.0f / 1024.0f) * tabs[(k * t) & 1023];
            }
            dst[j] = f2bf(v);
        }
    } else {
        int idx = blk - 2048;
        int b = idx / 320, d = idx - (idx / 320) * 320;
        unsigned short* dst = delta + (size_t)idx * 224;
        for (int j = threadIdx.x; j < 224; j += 256) {
            float v = 0.0f;
            if (d < DD) {
                if (j < KTOP) {
                    int k = idxf[b * KTOP + j];
                    v = ftr[d] - cxp[((size_t)b * PACK + k) * DD + d];
                } else if (j >= 112 && j < 112 + KTOP) {
                    int k = idxf[b * KTOP + j - 112];
                    v = fti[d] - cxp[((size_t)b * PACK + NFREQ + k) * DD + d];
                }
            }
            dst[j] = f2bf(v);
        }
    }
}

__device__ __forceinline__ void thl_row_body(int row, const float* __restrict__ tabc,
                                             const float* __restrict__ tabs,
                                             unsigned short* __restrict__ thl) {
    unsigned short* dst = thl + (size_t)row * 3072;
    for (int c = threadIdx.x; c < 3072; c += 256) {
        int seg = c >> 10, t = c & 1023;
        float v = 0.0f;
        if (row < PACK) v = (row < NFREQ) ? tabc[(row * t) & 1023] : -tabs[((row - NFREQ) * t) & 1023];
        unsigned short hi = f2bf(v);
        dst[c] = (seg < 2) ? hi : f2bf(v - bf2f(hi));
    }
}

// ---------------- fused kernels (block-range dispatch; independent nodes overlap) ----------------
// launch A: init (masks+tables) || weight/x conversions (none need the tables)
__global__ __launch_bounds__(256) void initconv_k(int* maskt, int* maskf, float* tabc, float* tabs,
                                                  const float* __restrict__ W1t,
                                                  const float* __restrict__ W2t,
                                                  const float* __restrict__ W_emb,
                                                  const float* __restrict__ x,
                                                  unsigned short* __restrict__ w1b,
                                                  unsigned short* __restrict__ w2b,
                                                  unsigned short* __restrict__ wemT,
                                                  unsigned short* __restrict__ xhl,
                                                  unsigned short* __restrict__ whl)
{
    int blk = blockIdx.x;
    if (blk < 8) {
        int i = blk * 256 + threadIdx.x;
        if (i < 2 * TDIM) maskt[i] = 0;
        if (i < PACK) maskf[i] = 0;
        if (i < 1024) {
            double ang = (double)i * (3.14159265358979323846 * 2.0 / 1024.0);
            tabc[i] = (float)cos(ang);
            tabs[i] = (float)sin(ang);
        }
    } else if (blk < 1224) {
        int r = blk - 8;   // 0..1215
        if (r < 640) {
            int rr = r & 319;
            const float* src = (r < 320) ? W1t : W2t;
            unsigned short* dst = (r < 320) ? w1b : w2b;
            for (int c = threadIdx.x; c < 288; c += 256) {
                float v = (rr < DD && c < DD) ? src[(size_t)rr * DD + c] : 0.0f;
                dst[(size_t)rr * 288 + c] = f2bf(v);
            }
        } else {
            int rr = r - 640;  // 0..575
            for (int c = threadIdx.x; c < 288; c += 256) {
                float v = (rr < CC && c < DD) ? W_emb[(size_t)c * CC + rr] : 0.0f;
                wemT[(size_t)rr * 288 + c] = f2bf(v);
            }
        }
    } else if (blk < 3272) {
        int r = blk - 1224;  // 0..2047
        const float* src = x + (size_t)r * CC;
        unsigned short* dst = xhl + (size_t)r * 1632;
        for (int c = threadIdx.x; c < 1632; c += 256) {
            int seg = c / 544, cc = c - seg * 544;
            float v = (cc < CC) ? src[cc] : 0.0f;
            unsigned short hi = f2bf(v);
            dst[c] = (seg < 2) ? hi : f2bf(v - bf2f(hi));
        }
    } else {
        int n = blk - 3272;  // 0..319
        unsigned short* dst = whl + (size_t)n * 1632;
        for (int c = threadIdx.x; c < 1632; c += 256) {
            int seg = c / 544, cc = c - seg * 544;
            float v = (n < DD && cc < CC) ? W_emb[(size_t)n * CC + cc] : 0.0f;
            unsigned short hi = f2bf(v);
            dst[c] = (seg == 1) ? f2bf(v - bf2f(hi)) : hi;
        }
    }
}

// launch B: ex GEMM || thl fill (thl not needed until the DFT launch)
__global__ __launch_bounds__(256) void fused_ex_thl_k(const unsigned short* __restrict__ xhl,
                                                      const unsigned short* __restrict__ whl,
                                                      const float* __restrict__ b_emb,
                                                      float* __restrict__ ex,
                                                      unsigned short* __restrict__ exthl,
                                                      const float* __restrict__ tabc,
                                                      const float* __restrict__ tabs,
                                                      unsigned short* __restrict__ thl)
{
    if (blockIdx.x < 160) {
        gemm_body<4, 3>(blockIdx.x, 160, xhl, whl, b_emb, ex, exthl, 2048, DD, 1632, DD, 5);
    } else {
        thl_row_body(blockIdx.x - 160, tabc, tabs, thl);
    }
}

__global__ __launch_bounds__(256) void fused_dft_score_k(const unsigned short* __restrict__ thl,
                                                         const unsigned short* __restrict__ exthl,
                                                         float* __restrict__ cxp,
                                                         const float* __restrict__ ex,
                                                         double* __restrict__ score)
{
    if (blockIdx.x < 170) {
        gemm_body<5, 4>(blockIdx.x, 170, thl, exthl, nullptr, cxp, nullptr, PACK, 640, 3072, 0, 10);
    } else {
        int ib = (int)(blockIdx.x - 170) * 4 + (threadIdx.x >> 6);
        score_wave(ib, ex, score);
    }
}

__global__ __launch_bounds__(512) void fused_topkt_mag_k(const double* __restrict__ score,
                                                         float* __restrict__ outf, int* __restrict__ idxt,
                                                         int* __restrict__ maskt,
                                                         const float* __restrict__ cxp,
                                                         double* __restrict__ magm)
{
    if (blockIdx.x < 2) {
        topk_body(blockIdx.x, score, TDIM, KTOP, outf, idxt, maskt);
    } else {
        int ib = (int)(blockIdx.x - 2) * 8 + (threadIdx.x >> 6);
        if (ib < 2 * NFREQ) mag_wave(ib, cxp, magm);
    }
}

__global__ __launch_bounds__(512) void fused_topkf_bm_k(const double* __restrict__ magm,
                                                        float* __restrict__ outf, int* __restrict__ idxf,
                                                        int* __restrict__ maskf,
                                                        const float* __restrict__ ex,
                                                        const float* __restrict__ ttok,
                                                        const int* __restrict__ maskt,
                                                        unsigned short* __restrict__ mb)
{
    if (blockIdx.x < 2) {
        topk_body(blockIdx.x, magm, NFREQ, KTOP, outf, idxf, maskf);
    } else {
        build_masked_body(blockIdx.x - 2, ex, ttok, maskt, mb);
    }
}

__global__ __launch_bounds__(256) void fused_h_seldelta_k(const unsigned short* __restrict__ maskb,
                                                          const unsigned short* __restrict__ w1b,
                                                          const float* __restrict__ b1t,
                                                          unsigned short* __restrict__ hb,
                                                          const float* __restrict__ tabc,
                                                          const float* __restrict__ tabs,
                                                          const int* __restrict__ idxf,
                                                          const float* __restrict__ cxp,
                                                          const float* __restrict__ ftr,
                                                          const float* __restrict__ fti,
                                                          unsigned short* __restrict__ itsel,
                                                          unsigned short* __restrict__ delta)
{
    if (blockIdx.x < 160) {
        gemm_body<1, 3>(blockIdx.x, 160, maskb, w1b, b1t, hb, nullptr, 2048, DD, 288, 288, 5);
    } else {
        sel_delta_body(blockIdx.x - 160, tabc, tabs, idxf, cxp, ftr, fti, itsel, delta);
    }
}

__global__ __launch_bounds__(256) void fused_sig_corr_k(const unsigned short* __restrict__ hb,
                                                        const unsigned short* __restrict__ w2b,
                                                        const float* __restrict__ b2t,
                                                        unsigned short* __restrict__ maskb,
                                                        const int* __restrict__ maskt,
                                                        const unsigned short* __restrict__ itsel,
                                                        const unsigned short* __restrict__ delta,
                                                        const float* __restrict__ ex,
                                                        unsigned short* __restrict__ xtb)
{
    if (blockIdx.x < 160) {
        gemm_body<8, 3>(blockIdx.x, 160, hb, w2b, b2t, maskb, (void*)maskt, 2048, DD, 288, 288, 5);
    } else {
        gemm_body<7, 1>(blockIdx.x - 160, 160, itsel, delta, ex, xtb, nullptr, 2048, 320, 224, 288, 5);
    }
}

// ---------------- launch ----------------
extern "C" void kernel_launch(void* const* d_in, const int* in_sizes, int n_in,
                              void* d_out, int out_size, void* d_ws, size_t ws_size,
                              hipStream_t stream) {
    (void)in_sizes; (void)n_in; (void)out_size; (void)ws_size;
    const float* x      = (const float*)d_in[0];
    const float* W_emb  = (const float*)d_in[1];
    const float* b_emb  = (const float*)d_in[2];
    const float* ttok   = (const float*)d_in[3];
    const float* W1t    = (const float*)d_in[4];
    const float* b1t    = (const float*)d_in[5];
    const float* W2t    = (const float*)d_in[6];
    const float* b2t    = (const float*)d_in[7];
    const float* ftr    = (const float*)d_in[8];
    const float* fti    = (const float*)d_in[9];
    float* out = (float*)d_out;
    float* ws  = (float*)d_ws;

    float* ex     = ws + WS_EX;
    float* cxp    = ws + WS_CXP;
    float* tabc   = ws + WS_TABC;
    float* tabs   = ws + WS_TABS;
    double* score = (double*)(ws + WS_SCORE);
    double* magm  = (double*)(ws + WS_MAGM);
    int* maskt    = (int*)(ws + WS_MASKT);
    int* idxt     = (int*)(ws + WS_IDXT);
    int* idxf     = (int*)(ws + WS_IDXF);
    int* maskf    = (int*)(ws + WS_MASKF);
    unsigned short* w1b   = (unsigned short*)(ws + WS_W1BF);
    unsigned short* w2b   = (unsigned short*)(ws + WS_W2BF);
    unsigned short* wemT  = (unsigned short*)(ws + WS_WEMT);
    unsigned short* maskb = (unsigned short*)(ws + WS_MASKB);
    unsigned short* hb    = (unsigned short*)(ws + WS_HBF);
    unsigned short* xtb   = (unsigned short*)(ws + WS_XTBF);
    unsigned short* itsel = (unsigned short*)(ws + WS_ITSEL);
    unsigned short* delta = (unsigned short*)(ws + WS_DELTA);
    unsigned short* xhl   = (unsigned short*)(ws + WS_XHL);
    unsigned short* thl   = (unsigned short*)(ws + WS_THL);
    unsigned short* whl   = (unsigned short*)(ws + WS_WHL);
    unsigned short* exthl = (unsigned short*)(ws + WS_EXTHL);

    // 1: init (masks/tables) || all table-independent conversions
    initconv_k<<<3592, 256, 0, stream>>>(maskt, maskf, tabc, tabs,
                                         W1t, W2t, W_emb, x, w1b, w2b, wemT, xhl, whl);

    // 2: ex GEMM (KU=3, fused exT-hl scatter) || thl fill
    fused_ex_thl_k<<<1248, 256, 0, stream>>>(xhl, whl, b_emb, ex, exthl, tabc, tabs, thl);

    // 3: forward DFT (KU=4) || sliding score
    fused_dft_score_k<<<682, 256, 0, stream>>>(thl, exthl, cxp, ex, score);

    // 4: topk_t || mag
    fused_topkt_mag_k<<<131, 512, 0, stream>>>(score, out + OFF_IDXT, idxt, maskt, cxp, magm);

    // 5: topk_f || build_masked
    fused_topkf_bm_k<<<2050, 512, 0, stream>>>(magm, out + OFF_IDXF, idxf, maskf,
                                               ex, ttok, maskt, maskb);

    // 6: h GEMM (KU=3) || sel_delta
    fused_h_seldelta_k<<<2848, 256, 0, stream>>>(maskb, w1b, b1t, hb,
                                                 tabc, tabs, idxf, cxp, ftr, fti, itsel, delta);

    // 7: sigmoid+select GEMM (KU=3) || corr GEMM
    fused_sig_corr_k<<<320, 256, 0, stream>>>(hb, w2b, b2t, maskb, maskt,
                                              itsel, delta, ex, xtb);

    // 8: merged out_t / out_f (KU=3): [maskb ; xtb] (contiguous 4096x288) @ wemT
    gemm_k<9, 3><<<576, 256, 0, stream>>>(maskb, wemT, nullptr, out, nullptr, 4096, CC, 288, CC, 9);
}

// Round 20
// 113.837 us; speedup vs baseline: 2.2392x; 1.0052x over previous
//
#include <hip/hip_runtime.h>

#define TDIM 1024
#define DD   263
#define CC   526
#define NFREQ 513
#define PACK 1026
#define KTOP 102

// ---------------- ws layout (float offsets) ----------------
static const size_t WS_EX     = 0;          // 538624 f32
static const size_t WS_W1BF   = 538624;     // 320x288 bf16
static const size_t WS_W2BF   = 584704;
static const size_t WS_WEMT   = 630784;     // 576x288 bf16 (ends 713728)
static const size_t WS_MASKB  = 1615872;    // 2048x288 bf16 = 294912 f
static const size_t WS_XTBF   = 1910784;    // 2048x288 bf16 (contiguous after MASKB)
static const size_t WS_HBF    = 2693120;    // 2048x288 bf16
static const size_t WS_CXP    = 3770368;    // f32 2*1026*263
static const size_t WS_EXTHL  = 4310044;    // [640][3072] bf16
static const size_t WS_ITSEL  = 5360668;    // [2048][224] bf16
static const size_t WS_DELTA  = 5901340;    // [640][224] bf16
static const size_t WS_TABC   = 6411292;    // 1024
static const size_t WS_TABS   = 6412316;    // 1024
static const size_t WS_SCORE  = 6413340;    // double[2048]
static const size_t WS_MAGM   = 6417436;    // double[1026]
static const size_t WS_MASKT  = 6419488;    // int[2048]
static const size_t WS_IDXT   = 6421536;    // int[204]
static const size_t WS_IDXF   = 6421740;    // int[204]
static const size_t WS_MASKF  = 6421944;    // int[1026]
static const size_t WS_XHL    = 6422972;    // 2048x1632 bf16
static const size_t WS_THL    = 8094140;    // 1088x3072 bf16
static const size_t WS_WHL    = 9765308;    // 320x1632 bf16
static const size_t WS_TOTAL  = 10740380;   // floats

static const size_t OFF_OUTT = 0;
static const size_t OFF_IDXT = 1077248;
static const size_t OFF_OUTF = 1077452;
static const size_t OFF_IDXF = 2154700;

typedef __bf16 bf16x8_t __attribute__((ext_vector_type(8)));
typedef float  f32x4_t  __attribute__((ext_vector_type(4)));

__device__ __forceinline__ unsigned short f2bf(float f) {
    unsigned int u = __float_as_uint(f);
    unsigned int r = (u + 0x7fffu + ((u >> 16) & 1u)) >> 16;
    return (unsigned short)r;
}
__device__ __forceinline__ float bf2f(unsigned short h) {
    return __uint_as_float(((unsigned int)h) << 16);
}

__device__ __forceinline__ float pe_val(int t, int d) {
    const float sc = (float)(-9.210340371976184 / 263.0);  // -ln(10000)/D
    int j = d >> 1;
    float div = expf((float)(2 * j) * sc);
    float a = (float)t * div;
    return (d & 1) ? cosf(a) : sinf(a);
}

// raw workgroup barrier: no implicit vmcnt(0) drain (prefetch stays in flight)
#define WG_FENCE()   asm volatile("" ::: "memory")
#define WG_BARRIER() { WG_FENCE(); __builtin_amdgcn_s_barrier(); WG_FENCE(); }
// wave-local LDS sync: all this wave's LDS ops done; no cross-wave barrier (rule #18: pin with sched_barrier)
#define WAVE_LDS_SYNC() { asm volatile("s_waitcnt lgkmcnt(0)" ::: "memory"); __builtin_amdgcn_sched_barrier(0); }

// ---------------- bf16 MFMA GEMM body (device fn; hw/nwg are LOCAL grid id/size) ----------------
// C = A @ Bt^T. A [>=M x SA] bf16, Bt [64*gy x SA] bf16. Tile 64x64, 4 waves 2x2, 256 thr.
// KU: K-elems staged per iteration = 32*KU (SA must divide). Same MFMA order for any KU.
// EPI: 0 ->f32; 1 bias+gelu->bf16; 4 bias+pe->f32 + exthl scatter (aux); 5 DFT scatter ->cxp;
//      7 corr: xtb=bf16(ex+v); 8 sigmoid+select (aux=maskt); 9 dual-out
template<int EPI, int KU>
__device__ __forceinline__ void gemm_body(int hw, int nwg,
                                          const unsigned short* __restrict__ A,
                                          const unsigned short* __restrict__ Bt,
                                          const float* __restrict__ bias,
                                          void* __restrict__ Cv,
                                          void* __restrict__ aux,
                                          int M, int N, int SA, int NC, int gy)
{
    __shared__ unsigned short As[64][32 * KU + 8];
    __shared__ unsigned short Bs[64][32 * KU + 8];
    // XCD-bijective chunked swizzle (m204)
    const int q = nwg >> 3, r = nwg & 7, xcd = hw & 7;
    const int logical = (xcd < r ? xcd * (q + 1) : r * (q + 1) + (xcd - r) * q) + (hw >> 3);
    const int row0 = (logical / gy) * 64, col0 = (logical % gy) * 64;
    if (EPI == 7) Bt += (size_t)(row0 >> 10) * 320 * SA;   // per-batch delta panel

    const int tid  = threadIdx.x;
    const int wid = tid >> 6, lane = tid & 63;
    const int wr = wid >> 1, wc = wid & 1;
    const int srow = tid >> 2, skoff = (tid & 3) * 8;
    const int fl = lane & 15, fh = lane >> 4;
    f32x4_t acc[2][2];
#pragma unroll
    for (int i = 0; i < 2; i++)
#pragma unroll
        for (int j = 0; j < 2; j++) acc[i][j] = (f32x4_t){0.f, 0.f, 0.f, 0.f};

    const int nk = SA / (32 * KU);
    const unsigned short* pa = A  + (size_t)(row0 + srow) * SA + skoff;
    const unsigned short* pb = Bt + (size_t)(col0 + srow) * SA + skoff;

    bf16x8_t qa[4][KU], qb[4][KU];
#pragma unroll
    for (int j = 0; j < 4; ++j) {
        if (j < nk) {
#pragma unroll
            for (int u = 0; u < KU; ++u) {
                qa[j][u] = *(const bf16x8_t*)(pa + (size_t)j * (32 * KU) + u * 32);
                qb[j][u] = *(const bf16x8_t*)(pb + (size_t)j * (32 * KU) + u * 32);
            }
        }
    }

    for (int itb = 0; itb < nk; itb += 4) {
#pragma unroll
        for (int j = 0; j < 4; ++j) {
            const int it = itb + j;
            if (it < nk) {
                if (it > 0) WG_BARRIER();
#pragma unroll
                for (int u = 0; u < KU; ++u) {
                    *(bf16x8_t*)(&As[srow][u * 32 + skoff]) = qa[j][u];
                    *(bf16x8_t*)(&Bs[srow][u * 32 + skoff]) = qb[j][u];
                }
                asm volatile("s_waitcnt lgkmcnt(0)" ::: "memory");
                WG_BARRIER();
#pragma unroll
                for (int u = 0; u < KU; ++u) {
                    bf16x8_t fa0 = *(const bf16x8_t*)(&As[wr * 32 + fl][u * 32 + fh * 8]);
                    bf16x8_t fa1 = *(const bf16x8_t*)(&As[wr * 32 + 16 + fl][u * 32 + fh * 8]);
                    bf16x8_t fb0 = *(const bf16x8_t*)(&Bs[wc * 32 + fl][u * 32 + fh * 8]);
                    bf16x8_t fb1 = *(const bf16x8_t*)(&Bs[wc * 32 + 16 + fl][u * 32 + fh * 8]);
                    acc[0][0] = __builtin_amdgcn_mfma_f32_16x16x32_bf16(fa0, fb0, acc[0][0], 0, 0, 0);
                    acc[0][1] = __builtin_amdgcn_mfma_f32_16x16x32_bf16(fa0, fb1, acc[0][1], 0, 0, 0);
                    acc[1][0] = __builtin_amdgcn_mfma_f32_16x16x32_bf16(fa1, fb0, acc[1][0], 0, 0, 0);
                    acc[1][1] = __builtin_amdgcn_mfma_f32_16x16x32_bf16(fa1, fb1, acc[1][1], 0, 0, 0);
                }
                if (it + 4 < nk) {
#pragma unroll
                    for (int u = 0; u < KU; ++u) {
                        qa[j][u] = *(const bf16x8_t*)(pa + (size_t)(it + 4) * (32 * KU) + u * 32);
                        qb[j][u] = *(const bf16x8_t*)(pb + (size_t)(it + 4) * (32 * KU) + u * 32);
                    }
                }
            }
        }
    }

#pragma unroll
    for (int fi = 0; fi < 2; fi++)
#pragma unroll
        for (int fj = 0; fj < 2; fj++)
#pragma unroll
            for (int rr = 0; rr < 4; rr++) {
                int m = row0 + wr * 32 + fi * 16 + fh * 4 + rr;
                int n = col0 + wc * 32 + fj * 16 + fl;
                if (m >= M) continue;
                float v = acc[fi][fj][rr];
                if (EPI == 0) {
                    if (n < N) ((float*)Cv)[(size_t)m * NC + n] = v;
                } else if (EPI == 1) {
                    if (n < NC) {
                        float o = 0.0f;
                        if (n < N) { o = v + bias[n]; o = 0.5f * o * (1.0f + erff(o * 0.70710678118654752f)); }
                        ((unsigned short*)Cv)[(size_t)m * NC + n] = f2bf(o);
                    }
                } else if (EPI == 4) {
                    if (n < N) {
                        float o = v + bias[n] + pe_val(m & (TDIM - 1), n);
                        ((float*)Cv)[(size_t)m * NC + n] = o;
                        unsigned short hi = f2bf(o);
                        unsigned short lo = f2bf(o - bf2f(hi));
                        size_t b2 = ((size_t)(m >> 10) * 320 + n) * 3072 + (m & 1023);
                        unsigned short* xh = (unsigned short*)aux;
                        xh[b2] = hi; xh[b2 + 1024] = lo; xh[b2 + 2048] = hi;
                    }
                } else if (EPI == 5) {
                    int b = n / 320, col = n - b * 320;
                    if (col < DD) ((float*)Cv)[((size_t)b * PACK + m) * DD + col] = v;
                } else if (EPI == 7) {
                    if (n < 288) {
                        unsigned short o = 0;
                        if (n < DD) o = f2bf(bias[(size_t)m * DD + n] + v);
                        ((unsigned short*)Cv)[(size_t)m * 288 + n] = o;
                    }
                } else if (EPI == 8) {
                    const int* mt = (const int*)aux;
                    if (n < 288 && !mt[m]) {
                        unsigned short o = 0;
                        if (n < DD) {
                            float s = v + bias[n];
                            o = f2bf(1.0f / (1.0f + expf(-s)));
                        }
                        ((unsigned short*)Cv)[(size_t)m * 288 + n] = o;
                    }
                } else {  // EPI 9: dual output
                    if (n < CC) {
                        size_t off = (m < 2048) ? (size_t)m * CC + n
                                                : (size_t)OFF_OUTF + (size_t)(m - 2048) * CC + n;
                        ((float*)Cv)[off] = v;
                    }
                }
            }
}

template<int EPI, int KU>
__global__ __launch_bounds__(256) void gemm_k(const unsigned short* __restrict__ A,
                                              const unsigned short* __restrict__ Bt,
                                              const float* __restrict__ bias,
                                              void* __restrict__ Cv, void* __restrict__ aux,
                                              int M, int N, int SA, int NC, int gy)
{
    gemm_body<EPI, KU>(blockIdx.x, gridDim.x, A, Bt, bias, Cv, aux, M, N, SA, NC, gy);
}

// ---------------- wave bodies ----------------
__device__ __forceinline__ void score_wave(int ib, const float* __restrict__ ex,
                                           double* __restrict__ score) {
    const int t = ib & (TDIM - 1);
    const int lane = threadIdx.x & 63;
    double ms = 0.0, vs = 0.0;
    if (t >= 24) {
        const float* base = ex + (size_t)(ib - 24) * DD;
        for (int d = lane; d < DD; d += 64) {
            float s1 = 0.0f, s2 = 0.0f;
#pragma unroll
            for (int r = 0; r < 25; r++) {
                float v = base[(size_t)r * DD + d];
                s1 += v;
                s2 += v * v;
            }
            float m1 = s1 * (1.0f / 25.0f);
            float var = s2 * (1.0f / 25.0f) - m1 * m1;
            ms += (double)m1;
            vs += (double)var;
        }
    } else {
        const int nt = t + 1;
        const float cnt = (float)nt;
        const float* base = ex + (size_t)(ib - t) * DD;
        for (int d = lane; d < DD; d += 64) {
            float s1 = 0.0f, s2 = 0.0f;
            for (int r = 0; r < nt; r++) {
                float v = base[(size_t)r * DD + d];
                s1 += v;
                s2 += v * v;
            }
            float m1 = s1 / cnt;
            float var = s2 / cnt - m1 * m1;
            ms += (double)m1;
            vs += (double)var;
        }
    }
#pragma unroll
    for (int off = 32; off; off >>= 1) { ms += __shfl_xor(ms, off); vs += __shfl_xor(vs, off); }
    if (lane == 0) score[ib] = vs / (ms + (double)1e-6f);
}

__device__ __forceinline__ void mag_wave(int ib, const float* __restrict__ cxp,
                                         double* __restrict__ magm) {
    int b = ib / NFREQ, k = ib % NFREQ;
    int lane = threadIdx.x & 63;
    const float* re = cxp + ((size_t)b * PACK + k) * DD;
    const float* im = cxp + ((size_t)b * PACK + NFREQ + k) * DD;
    double acc = 0.0;
    for (int d = lane; d < DD; d += 64) {
        float r = re[d], i = im[d];
        acc += (double)sqrtf(r * r + i * i);
    }
#pragma unroll
    for (int off = 32; off; off >>= 1) acc += __shfl_xor(acc, off);
    if (lane == 0) magm[ib] = acc / (double)DD;
}

// topk body (512 threads; exact pair enumeration; wave-local stages skip s_barrier).
__device__ __forceinline__ void topk_body(int b, const double* __restrict__ score,
                                          int n, int kcount,
                                          float* __restrict__ out_f, int* __restrict__ out_i,
                                          int* __restrict__ mask) {
    __shared__ double sv[1024];
    __shared__ int    si[1024];
    const int tid = threadIdx.x;
    const double* s = score + (size_t)b * n;
    for (int i = tid; i < 1024; i += 512) {
        sv[i] = (i < n) ? s[i] : -1.0e300;
        si[i] = i;
    }
    __syncthreads();
    for (int k = 2; k <= 1024; k <<= 1) {
        for (int j = k >> 1; j > 0; j >>= 1) {
            int t = ((tid & ~(j - 1)) << 1) | (tid & (j - 1));
            int l = t | j;
            double v0 = sv[t], v1 = sv[l];
            int i0 = si[t], i1 = si[l];
            bool g = (v0 > v1) || (v0 == v1 && i0 < i1);
            bool wrong = ((t & k) == 0) ? !g : g;
            if (wrong) {
                sv[t] = v1; sv[l] = v0;
                si[t] = i1; si[l] = i0;
            }
            int next_j = (j > 1) ? (j >> 1) : k;   // next stage's j (first j of next k == k)
            if (j >= 128 || next_j >= 128) __syncthreads();
            else WAVE_LDS_SYNC();
        }
    }
    __syncthreads();   // final visibility for output read (crosses wave chunks)
    for (int t = tid; t < kcount; t += 512) {
        int bi = si[t];
        out_f[(size_t)b * kcount + t] = (float)bi;
        out_i[b * kcount + t] = bi;
        mask[b * n + bi] = 1;
    }
}

__device__ __forceinline__ void build_masked_body(int bt, const float* __restrict__ ex,
                                                  const float* __restrict__ ttok,
                                                  const int* __restrict__ maskt,
                                                  unsigned short* __restrict__ mb) {
    int d = threadIdx.x;
    if (d >= 288) return;
    float v = 0.0f;
    if (d < DD) v = maskt[bt] ? ttok[d] : ex[(size_t)bt * DD + d];
    mb[(size_t)bt * 288 + d] = f2bf(v);
}

__device__ __forceinline__ void sel_delta_body(int blk,
                                               const float* __restrict__ tabc, const float* __restrict__ tabs,
                                               const int* __restrict__ idxf, const float* __restrict__ cxp,
                                               const float* __restrict__ ftr, const float* __restrict__ fti,
                                               unsigned short* __restrict__ itsel,
                                               unsigned short* __restrict__ delta) {
    if (blk < 2048) {
        int b = blk >> 10, t = blk & 1023;
        unsigned short* dst = itsel + (size_t)blk * 224;
        for (int j = threadIdx.x; j < 224; j += 256) {
            float v = 0.0f;
            if (j < KTOP) {
                int k = idxf[b * KTOP + j];
                float w = (k == 0 || k == 512) ? 1.0f : 2.0f;
                v = (w * (1.0f / 1024.0f)) * tabc[(k * t) & 1023];
            } else if (j >= 112 && j < 112 + KTOP) {
                int k = idxf[b * KTOP + j - 112];
                v = (k == 0 || k == 512) ? 0.0f : (-2.0f / 1024.0f) * tabs[(k * t) & 1023];
            }
            dst[j] = f2bf(v);
        }
    } else {
        int idx = blk - 2048;
        int b = idx / 320, d = idx - (idx / 320) * 320;
        unsigned short* dst = delta + (size_t)idx * 224;
        for (int j = threadIdx.x; j < 224; j += 256) {
            float v = 0.0f;
            if (d < DD) {
                if (j < KTOP) {
                    int k = idxf[b * KTOP + j];
                    v = ftr[d] - cxp[((size_t)b * PACK + k) * DD + d];
                } else if (j >= 112 && j < 112 + KTOP) {
                    int k = idxf[b * KTOP + j - 112];
                    v = fti[d] - cxp[((size_t)b * PACK + NFREQ + k) * DD + d];
                }
            }
            dst[j] = f2bf(v);
        }
    }
}

__device__ __forceinline__ void thl_row_body(int row, const float* __restrict__ tabc,
                                             const float* __restrict__ tabs,
                                             unsigned short* __restrict__ thl) {
    unsigned short* dst = thl + (size_t)row * 3072;
    for (int c = threadIdx.x; c < 3072; c += 256) {
        int seg = c >> 10, t = c & 1023;
        float v = 0.0f;
        if (row < PACK) v = (row < NFREQ) ? tabc[(row * t) & 1023] : -tabs[((row - NFREQ) * t) & 1023];
        unsigned short hi = f2bf(v);
        dst[c] = (seg < 2) ? hi : f2bf(v - bf2f(hi));
    }
}

// ---------------- fused kernels (block-range dispatch; independent nodes overlap) ----------------
// launch A: init (masks+tables) || weight/x conversions (none need the tables)
__global__ __launch_bounds__(256) void initconv_k(int* maskt, int* maskf, float* tabc, float* tabs,
                                                  const float* __restrict__ W1t,
                                                  const float* __restrict__ W2t,
                                                  const float* __restrict__ W_emb,
                                                  const float* __restrict__ x,
                                                  unsigned short* __restrict__ w1b,
                                                  unsigned short* __restrict__ w2b,
                                                  unsigned short* __restrict__ wemT,
                                                  unsigned short* __restrict__ xhl,
                                                  unsigned short* __restrict__ whl)
{
    int blk = blockIdx.x;
    if (blk < 8) {
        int i = blk * 256 + threadIdx.x;
        if (i < 2 * TDIM) maskt[i] = 0;
        if (i < PACK) maskf[i] = 0;
        if (i < 1024) {
            double ang = (double)i * (3.14159265358979323846 * 2.0 / 1024.0);
            tabc[i] = (float)cos(ang);
            tabs[i] = (float)sin(ang);
        }
    } else if (blk < 1224) {
        int r = blk - 8;   // 0..1215
        if (r < 640) {
            int rr = r & 319;
            const float* src = (r < 320) ? W1t : W2t;
            unsigned short* dst = (r < 320) ? w1b : w2b;
            for (int c = threadIdx.x; c < 288; c += 256) {
                float v = (rr < DD && c < DD) ? src[(size_t)rr * DD + c] : 0.0f;
                dst[(size_t)rr * 288 + c] = f2bf(v);
            }
        } else {
            int rr = r - 640;  // 0..575
            for (int c = threadIdx.x; c < 288; c += 256) {
                float v = (rr < CC && c < DD) ? W_emb[(size_t)c * CC + rr] : 0.0f;
                wemT[(size_t)rr * 288 + c] = f2bf(v);
            }
        }
    } else if (blk < 3272) {
        int r = blk - 1224;  // 0..2047
        const float* src = x + (size_t)r * CC;
        unsigned short* dst = xhl + (size_t)r * 1632;
        for (int c = threadIdx.x; c < 1632; c += 256) {
            int seg = c / 544, cc = c - seg * 544;
            float v = (cc < CC) ? src[cc] : 0.0f;
            unsigned short hi = f2bf(v);
            dst[c] = (seg < 2) ? hi : f2bf(v - bf2f(hi));
        }
    } else {
        int n = blk - 3272;  // 0..319
        unsigned short* dst = whl + (size_t)n * 1632;
        for (int c = threadIdx.x; c < 1632; c += 256) {
            int seg = c / 544, cc = c - seg * 544;
            float v = (n < DD && cc < CC) ? W_emb[(size_t)n * CC + cc] : 0.0f;
            unsigned short hi = f2bf(v);
            dst[c] = (seg == 1) ? f2bf(v - bf2f(hi)) : hi;
        }
    }
}

// launch B: ex GEMM || thl fill (thl not needed until the DFT launch)
__global__ __launch_bounds__(256) void fused_ex_thl_k(const unsigned short* __restrict__ xhl,
                                                      const unsigned short* __restrict__ whl,
                                                      const float* __restrict__ b_emb,
                                                      float* __restrict__ ex,
                                                      unsigned short* __restrict__ exthl,
                                                      const float* __restrict__ tabc,
                                                      const float* __restrict__ tabs,
                                                      unsigned short* __restrict__ thl)
{
    if (blockIdx.x < 160) {
        gemm_body<4, 3>(blockIdx.x, 160, xhl, whl, b_emb, ex, exthl, 2048, DD, 1632, DD, 5);
    } else {
        thl_row_body(blockIdx.x - 160, tabc, tabs, thl);
    }
}

__global__ __launch_bounds__(256) void fused_dft_score_k(const unsigned short* __restrict__ thl,
                                                         const unsigned short* __restrict__ exthl,
                                                         float* __restrict__ cxp,
                                                         const float* __restrict__ ex,
                                                         double* __restrict__ score)
{
    if (blockIdx.x < 170) {
        gemm_body<5, 4>(blockIdx.x, 170, thl, exthl, nullptr, cxp, nullptr, PACK, 640, 3072, 0, 10);
    } else {
        int ib = (int)(blockIdx.x - 170) * 4 + (threadIdx.x >> 6);
        score_wave(ib, ex, score);
    }
}

__global__ __launch_bounds__(512) void fused_topkt_mag_k(const double* __restrict__ score,
                                                         float* __restrict__ outf, int* __restrict__ idxt,
                                                         int* __restrict__ maskt,
                                                         const float* __restrict__ cxp,
                                                         double* __restrict__ magm)
{
    if (blockIdx.x < 2) {
        topk_body(blockIdx.x, score, TDIM, KTOP, outf, idxt, maskt);
    } else {
        int ib = (int)(blockIdx.x - 2) * 8 + (threadIdx.x >> 6);
        if (ib < 2 * NFREQ) mag_wave(ib, cxp, magm);
    }
}

__global__ __launch_bounds__(512) void fused_topkf_bm_k(const double* __restrict__ magm,
                                                        float* __restrict__ outf, int* __restrict__ idxf,
                                                        int* __restrict__ maskf,
                                                        const float* __restrict__ ex,
                                                        const float* __restrict__ ttok,
                                                        const int* __restrict__ maskt,
                                                        unsigned short* __restrict__ mb)
{
    if (blockIdx.x < 2) {
        topk_body(blockIdx.x, magm, NFREQ, KTOP, outf, idxf, maskf);
    } else {
        build_masked_body(blockIdx.x - 2, ex, ttok, maskt, mb);
    }
}

__global__ __launch_bounds__(256) void fused_h_seldelta_k(const unsigned short* __restrict__ maskb,
                                                          const unsigned short* __restrict__ w1b,
                                                          const float* __restrict__ b1t,
                                                          unsigned short* __restrict__ hb,
                                                          const float* __restrict__ tabc,
                                                          const float* __restrict__ tabs,
                                                          const int* __restrict__ idxf,
                                                          const float* __restrict__ cxp,
                                                          const float* __restrict__ ftr,
                                                          const float* __restrict__ fti,
                                                          unsigned short* __restrict__ itsel,
                                                          unsigned short* __restrict__ delta)
{
    if (blockIdx.x < 160) {
        gemm_body<1, 3>(blockIdx.x, 160, maskb, w1b, b1t, hb, nullptr, 2048, DD, 288, 288, 5);
    } else {
        sel_delta_body(blockIdx.x - 160, tabc, tabs, idxf, cxp, ftr, fti, itsel, delta);
    }
}

__global__ __launch_bounds__(256) void fused_sig_corr_k(const unsigned short* __restrict__ hb,
                                                        const unsigned short* __restrict__ w2b,
                                                        const float* __restrict__ b2t,
                                                        unsigned short* __restrict__ maskb,
                                                        const int* __restrict__ maskt,
                                                        const unsigned short* __restrict__ itsel,
                                                        const unsigned short* __restrict__ delta,
                                                        const float* __restrict__ ex,
                                                        unsigned short* __restrict__ xtb)
{
    if (blockIdx.x < 160) {
        gemm_body<8, 3>(blockIdx.x, 160, hb, w2b, b2t, maskb, (void*)maskt, 2048, DD, 288, 288, 5);
    } else {
        gemm_body<7, 1>(blockIdx.x - 160, 160, itsel, delta, ex, xtb, nullptr, 2048, 320, 224, 288, 5);
    }
}

// ---------------- launch ----------------
extern "C" void kernel_launch(void* const* d_in, const int* in_sizes, int n_in,
                              void* d_out, int out_size, void* d_ws, size_t ws_size,
                              hipStream_t stream) {
    (void)in_sizes; (void)n_in; (void)out_size; (void)ws_size;
    const float* x      = (const float*)d_in[0];
    const float* W_emb  = (const float*)d_in[1];
    const float* b_emb  = (const float*)d_in[2];
    const float* ttok   = (const float*)d_in[3];
    const float* W1t    = (const float*)d_in[4];
    const float* b1t    = (const float*)d_in[5];
    const float* W2t    = (const float*)d_in[6];
    const float* b2t    = (const float*)d_in[7];
    const float* ftr    = (const float*)d_in[8];
    const float* fti    = (const float*)d_in[9];
    float* out = (float*)d_out;
    float* ws  = (float*)d_ws;

    float* ex     = ws + WS_EX;
    float* cxp    = ws + WS_CXP;
    float* tabc   = ws + WS_TABC;
    float* tabs   = ws + WS_TABS;
    double* score = (double*)(ws + WS_SCORE);
    double* magm  = (double*)(ws + WS_MAGM);
    int* maskt    = (int*)(ws + WS_MASKT);
    int* idxt     = (int*)(ws + WS_IDXT);
    int* idxf     = (int*)(ws + WS_IDXF);
    int* maskf    = (int*)(ws + WS_MASKF);
    unsigned short* w1b   = (unsigned short*)(ws + WS_W1BF);
    unsigned short* w2b   = (unsigned short*)(ws + WS_W2BF);
    unsigned short* wemT  = (unsigned short*)(ws + WS_WEMT);
    unsigned short* maskb = (unsigned short*)(ws + WS_MASKB);
    unsigned short* hb    = (unsigned short*)(ws + WS_HBF);
    unsigned short* xtb   = (unsigned short*)(ws + WS_XTBF);
    unsigned short* itsel = (unsigned short*)(ws + WS_ITSEL);
    unsigned short* delta = (unsigned short*)(ws + WS_DELTA);
    unsigned short* xhl   = (unsigned short*)(ws + WS_XHL);
    unsigned short* thl   = (unsigned short*)(ws + WS_THL);
    unsigned short* whl   = (unsigned short*)(ws + WS_WHL);
    unsigned short* exthl = (unsigned short*)(ws + WS_EXTHL);

    // 1: init (masks/tables) || all table-independent conversions
    initconv_k<<<3592, 256, 0, stream>>>(maskt, maskf, tabc, tabs,
                                         W1t, W2t, W_emb, x, w1b, w2b, wemT, xhl, whl);

    // 2: ex GEMM (KU=3, fused exT-hl scatter) || thl fill
    fused_ex_thl_k<<<1248, 256, 0, stream>>>(xhl, whl, b_emb, ex, exthl, tabc, tabs, thl);

    // 3: forward DFT (KU=4) || sliding score
    fused_dft_score_k<<<682, 256, 0, stream>>>(thl, exthl, cxp, ex, score);

    // 4: topk_t || mag
    fused_topkt_mag_k<<<131, 512, 0, stream>>>(score, out + OFF_IDXT, idxt, maskt, cxp, magm);

    // 5: topk_f || build_masked
    fused_topkf_bm_k<<<2050, 512, 0, stream>>>(magm, out + OFF_IDXF, idxf, maskf,
                                               ex, ttok, maskt, maskb);

    // 6: h GEMM (KU=3) || sel_delta
    fused_h_seldelta_k<<<2848, 256, 0, stream>>>(maskb, w1b, b1t, hb,
                                                 tabc, tabs, idxf, cxp, ftr, fti, itsel, delta);

    // 7: sigmoid+select GEMM (KU=3) || corr GEMM
    fused_sig_corr_k<<<320, 256, 0, stream>>>(hb, w2b, b2t, maskb, maskt,
                                              itsel, delta, ex, xtb);

    // 8: merged out_t / out_f (KU=3): [maskb ; xtb] (contiguous 4096x288) @ wemT
    gemm_k<9, 3><<<576, 256, 0, stream>>>(maskb, wemT, nullptr, out, nullptr, 4096, CC, 288, CC, 9);
}